// Round 13
// baseline (1815.648 us; speedup 1.0000x reference)
//
#include <hip/hip_runtime.h>
#include <stdint.h>

#define L_SEQ 4096
#define EDIM  1024
#define HDIM  4096
#define NLAY  8
#define WKV_C 128  // chunks
#define WKV_T 32   // tokens per chunk
#define SCAN_LANES 16
#define SCAN_CPT   (WKV_C / SCAN_LANES)  // 8

typedef unsigned short u16;
typedef __attribute__((ext_vector_type(8))) short short8;
typedef __attribute__((ext_vector_type(4))) float f32x4;
typedef __attribute__((ext_vector_type(4))) float f4v;
typedef __attribute__((ext_vector_type(4))) unsigned short us4;
typedef __attribute__((ext_vector_type(8))) unsigned short us8;

static __device__ __forceinline__ u16 f2b(float f) {
  union { float f; uint32_t u; } a; a.f = f;
  uint32_t u = a.u;
  return (u16)((u + 0x7FFFu + ((u >> 16) & 1u)) >> 16);  // RNE
}
static __device__ __forceinline__ float b2f(u16 b) {
  union { uint32_t u; float f; } a; a.u = ((uint32_t)b) << 16;
  return a.f;
}
static __device__ __forceinline__ float sigm(float v) {
  return 1.f / (1.f + __expf(-v));
}
static __device__ __forceinline__ float4 ld_bf4(const u16* __restrict__ p, size_t i) {
  us4 v = *reinterpret_cast<const us4*>(&p[i]);
  return make_float4(b2f(v.x), b2f(v.y), b2f(v.z), b2f(v.w));
}

static __device__ __forceinline__ void gld_lds16(const void* g, void* l) {
  __builtin_amdgcn_global_load_lds(
      (const __attribute__((address_space(1))) void*)g,
      (__attribute__((address_space(3))) void*)l, 16, 0, 0);
}

// ---------------- fused elementwise (x residual in bf16) ----------------

// F0: x = embed[tok], tm-mix3 (layer 0)
__global__ void k_f0(const int* __restrict__ s, const float* __restrict__ embed,
                     const float* __restrict__ mk, const float* __restrict__ mv,
                     const float* __restrict__ mr, u16* __restrict__ xA,
                     u16* __restrict__ kx, u16* __restrict__ vx, u16* __restrict__ rx) {
  int i = (blockIdx.x * blockDim.x + threadIdx.x) * 4;
  int t = i >> 10, e = i & 1023;
  int tok = (t == 0) ? 0 : s[t - 1];
  float4 xc = *reinterpret_cast<const float4*>(&embed[tok * EDIM + e]);
  float4 xs = make_float4(0.f, 0.f, 0.f, 0.f);
  if (t > 0) {
    int tokp = (t == 1) ? 0 : s[t - 2];
    xs = *reinterpret_cast<const float4*>(&embed[tokp * EDIM + e]);
  }
  us4 ox; ox.x = f2b(xc.x); ox.y = f2b(xc.y); ox.z = f2b(xc.z); ox.w = f2b(xc.w);
  *reinterpret_cast<us4*>(&xA[i]) = ox;
  float4 m; us4 o;
  m = *reinterpret_cast<const float4*>(&mk[e]);
  o.x = f2b(xc.x * m.x + xs.x * (1.f - m.x)); o.y = f2b(xc.y * m.y + xs.y * (1.f - m.y));
  o.z = f2b(xc.z * m.z + xs.z * (1.f - m.z)); o.w = f2b(xc.w * m.w + xs.w * (1.f - m.w));
  *reinterpret_cast<us4*>(&kx[i]) = o;
  m = *reinterpret_cast<const float4*>(&mv[e]);
  o.x = f2b(xc.x * m.x + xs.x * (1.f - m.x)); o.y = f2b(xc.y * m.y + xs.y * (1.f - m.y));
  o.z = f2b(xc.z * m.z + xs.z * (1.f - m.z)); o.w = f2b(xc.w * m.w + xs.w * (1.f - m.w));
  *reinterpret_cast<us4*>(&vx[i]) = o;
  m = *reinterpret_cast<const float4*>(&mr[e]);
  o.x = f2b(xc.x * m.x + xs.x * (1.f - m.x)); o.y = f2b(xc.y * m.y + xs.y * (1.f - m.y));
  o.z = f2b(xc.z * m.z + xs.z * (1.f - m.z)); o.w = f2b(xc.w * m.w + xs.w * (1.f - m.w));
  *reinterpret_cast<us4*>(&rx[i]) = o;
}

// cm-finish: x = xB + sig(PR0+PR1) * (PB0+PB1+PB2+PB3)  (all bf16)
static __device__ __forceinline__ float4 cm_finish(const u16* __restrict__ xB,
                                                   const u16* __restrict__ PR,
                                                   const u16* __restrict__ PB, int i) {
  const size_t LE = (size_t)L_SEQ * EDIM;
  float4 xm = ld_bf4(xB, i);
  float4 r0 = ld_bf4(PR, i), r1 = ld_bf4(PR, i + LE);
  float4 v0 = ld_bf4(PB, i), v1 = ld_bf4(PB, i + LE);
  float4 v2 = ld_bf4(PB, i + 2 * LE), v3 = ld_bf4(PB, i + 3 * LE);
  xm.x += sigm(r0.x + r1.x) * (v0.x + v1.x + v2.x + v3.x);
  xm.y += sigm(r0.y + r1.y) * (v0.y + v1.y + v2.y + v3.y);
  xm.z += sigm(r0.z + r1.z) * (v0.z + v1.z + v2.z + v3.z);
  xm.w += sigm(r0.w + r1.w) * (v0.w + v1.w + v2.w + v3.w);
  return xm;
}

// F1: x = cm_finish; tm-mix3 (layers 1..7)
__global__ void k_f1(const u16* __restrict__ xB, const u16* __restrict__ PR,
                     const u16* __restrict__ PB,
                     const float* __restrict__ mk, const float* __restrict__ mv,
                     const float* __restrict__ mr, u16* __restrict__ xA,
                     u16* __restrict__ kx, u16* __restrict__ vx, u16* __restrict__ rx) {
  int i = (blockIdx.x * blockDim.x + threadIdx.x) * 4;
  int e = i & 1023;
  float4 xc = cm_finish(xB, PR, PB, i);
  float4 xs = make_float4(0.f, 0.f, 0.f, 0.f);
  if (i >= EDIM) xs = cm_finish(xB, PR, PB, i - EDIM);
  us4 ox; ox.x = f2b(xc.x); ox.y = f2b(xc.y); ox.z = f2b(xc.z); ox.w = f2b(xc.w);
  *reinterpret_cast<us4*>(&xA[i]) = ox;
  float4 m; us4 o;
  m = *reinterpret_cast<const float4*>(&mk[e]);
  o.x = f2b(xc.x * m.x + xs.x * (1.f - m.x)); o.y = f2b(xc.y * m.y + xs.y * (1.f - m.y));
  o.z = f2b(xc.z * m.z + xs.z * (1.f - m.z)); o.w = f2b(xc.w * m.w + xs.w * (1.f - m.w));
  *reinterpret_cast<us4*>(&kx[i]) = o;
  m = *reinterpret_cast<const float4*>(&mv[e]);
  o.x = f2b(xc.x * m.x + xs.x * (1.f - m.x)); o.y = f2b(xc.y * m.y + xs.y * (1.f - m.y));
  o.z = f2b(xc.z * m.z + xs.z * (1.f - m.z)); o.w = f2b(xc.w * m.w + xs.w * (1.f - m.w));
  *reinterpret_cast<us4*>(&vx[i]) = o;
  m = *reinterpret_cast<const float4*>(&mr[e]);
  o.x = f2b(xc.x * m.x + xs.x * (1.f - m.x)); o.y = f2b(xc.y * m.y + xs.y * (1.f - m.y));
  o.z = f2b(xc.z * m.z + xs.z * (1.f - m.z)); o.w = f2b(xc.w * m.w + xs.w * (1.f - m.w));
  *reinterpret_cast<us4*>(&rx[i]) = o;
}

static __device__ __forceinline__ float4 tm_finish(const u16* __restrict__ xA,
                                                   const u16* __restrict__ PA, int i) {
  const size_t LE = (size_t)L_SEQ * EDIM;
  float4 xm = ld_bf4(xA, i);
  float4 a = ld_bf4(PA, i), b = ld_bf4(PA, i + LE);
  xm.x += a.x + b.x; xm.y += a.y + b.y; xm.z += a.z + b.z; xm.w += a.w + b.w;
  return xm;
}

// F2: x = xA + PA0 + PA1; cm-mix2
__global__ void k_f2(const u16* __restrict__ xA, const u16* __restrict__ PA,
                     const float* __restrict__ mk, const float* __restrict__ mr,
                     u16* __restrict__ xB, u16* __restrict__ kx, u16* __restrict__ rx) {
  int i = (blockIdx.x * blockDim.x + threadIdx.x) * 4;
  int e = i & 1023;
  float4 xc = tm_finish(xA, PA, i);
  float4 xs = make_float4(0.f, 0.f, 0.f, 0.f);
  if (i >= EDIM) xs = tm_finish(xA, PA, i - EDIM);
  us4 ox; ox.x = f2b(xc.x); ox.y = f2b(xc.y); ox.z = f2b(xc.z); ox.w = f2b(xc.w);
  *reinterpret_cast<us4*>(&xB[i]) = ox;
  float4 m; us4 o;
  m = *reinterpret_cast<const float4*>(&mk[e]);
  o.x = f2b(xc.x * m.x + xs.x * (1.f - m.x)); o.y = f2b(xc.y * m.y + xs.y * (1.f - m.y));
  o.z = f2b(xc.z * m.z + xs.z * (1.f - m.z)); o.w = f2b(xc.w * m.w + xs.w * (1.f - m.w));
  *reinterpret_cast<us4*>(&kx[i]) = o;
  m = *reinterpret_cast<const float4*>(&mr[e]);
  o.x = f2b(xc.x * m.x + xs.x * (1.f - m.x)); o.y = f2b(xc.y * m.y + xs.y * (1.f - m.y));
  o.z = f2b(xc.z * m.z + xs.z * (1.f - m.z)); o.w = f2b(xc.w * m.w + xs.w * (1.f - m.w));
  *reinterpret_cast<us4*>(&rx[i]) = o;
}

// F3: hb = bf16(cm_finish)
__global__ void k_f3(const u16* __restrict__ xB, const u16* __restrict__ PR,
                     const u16* __restrict__ PB, u16* __restrict__ hb) {
  int i = (blockIdx.x * blockDim.x + threadIdx.x) * 4;
  float4 xc = cm_finish(xB, PR, PB, i);
  us4 o;
  o.x = f2b(xc.x); o.y = f2b(xc.y); o.z = f2b(xc.z); o.w = f2b(xc.w);
  *reinterpret_cast<us4*>(&hb[i]) = o;
}

static __device__ __forceinline__ float gelu1(float v) {
  float c = 0.7978845608028654f * (v + 0.044715f * v * v * v);
  return 0.5f * v * (1.f + tanhf(c));
}

// ---------------- transpose + f32->bf16 (NT loads: weights read once) ----------------
static __device__ __forceinline__
void tconv2(const float* __restrict__ s, u16* __restrict__ d, int K, int N,
            int n0, int k0) {
  __shared__ float tile[64][65];
  int tid = threadIdx.x;
  int tx = tid & 15, ty = tid >> 4;
#pragma unroll
  for (int i = 0; i < 4; ++i) {
    int kr = ty + i * 16;
    f4v v = __builtin_nontemporal_load(
        reinterpret_cast<const f4v*>(&s[(size_t)(k0 + kr) * N + n0 + tx * 4]));
    tile[kr][tx * 4 + 0] = v.x; tile[kr][tx * 4 + 1] = v.y;
    tile[kr][tx * 4 + 2] = v.z; tile[kr][tx * 4 + 3] = v.w;
  }
  __syncthreads();
  int tx8 = tid & 7, ny = tid >> 3;
#pragma unroll
  for (int h = 0; h < 2; ++h) {
    int n = ny + h * 32;
    us8 o;
#pragma unroll
    for (int c = 0; c < 8; ++c) o[c] = f2b(tile[tx8 * 8 + c][n]);
    *reinterpret_cast<us8*>(&d[(size_t)(n0 + n) * K + k0 + tx8 * 8]) = o;
  }
}

__global__ __launch_bounds__(256)
void k_tconv(const float* __restrict__ src, u16* __restrict__ dst, int K, int N) {
  tconv2(src + (size_t)blockIdx.z * K * N, dst + (size_t)blockIdx.z * K * N,
         K, N, blockIdx.x * 64, blockIdx.y * 64);
}

// ALL weights in one flat launch: 41 ExE + 8 ExH (cm_Wk) + 8 HxE (cm_Wv)
#define TC_EE  (41 * 256)
#define TC_EH  8192
__global__ __launch_bounds__(256)
void k_tconv_all(const float* __restrict__ Wk, const float* __restrict__ Wv,
                 const float* __restrict__ Wr, const float* __restrict__ Wo,
                 const float* __restrict__ cWr, const float* __restrict__ nW,
                 const float* __restrict__ cWk, const float* __restrict__ cWv,
                 u16* __restrict__ oWk, u16* __restrict__ oWv, u16* __restrict__ oWr,
                 u16* __restrict__ oWo, u16* __restrict__ ocWr, u16* __restrict__ onW,
                 u16* __restrict__ ocWk, u16* __restrict__ ocWv) {
  const size_t EE = (size_t)EDIM * EDIM, EH = (size_t)EDIM * HDIM;
  int bid = blockIdx.x;
  if (bid < TC_EE) {
    int z = bid >> 8, rem = bid & 255;
    const float* src; u16* dst;
    if (z < 8)       { src = Wk  + (size_t)z * EE;        dst = oWk  + (size_t)z * EE; }
    else if (z < 16) { src = Wv  + (size_t)(z - 8) * EE;  dst = oWv  + (size_t)(z - 8) * EE; }
    else if (z < 24) { src = Wr  + (size_t)(z - 16) * EE; dst = oWr  + (size_t)(z - 16) * EE; }
    else if (z < 32) { src = Wo  + (size_t)(z - 24) * EE; dst = oWo  + (size_t)(z - 24) * EE; }
    else if (z < 40) { src = cWr + (size_t)(z - 32) * EE; dst = ocWr + (size_t)(z - 32) * EE; }
    else             { src = nW;                          dst = onW; }
    tconv2(src, dst, EDIM, EDIM, (rem & 15) * 64, (rem >> 4) * 64);
  } else if (bid < TC_EE + TC_EH) {
    int b = bid - TC_EE;
    int z = b >> 10, rem = b & 1023;
    tconv2(cWk + (size_t)z * EH, ocWk + (size_t)z * EH, EDIM, HDIM,
           (rem & 63) * 64, (rem >> 6) * 64);
  } else {
    int b = bid - TC_EE - TC_EH;
    int z = b >> 10, rem = b & 1023;
    tconv2(cWv + (size_t)z * EH, ocWv + (size_t)z * EH, HDIM, EDIM,
           (rem & 15) * 64, (rem >> 4) * 64);
  }
}

// ========== 256x256 8-wave pipelined GEMM (2 phases / K-tile of 32) ==========
// EPI: 0 = f32 store, 1 = bf16 store, 2 = bf16(relu^2)
template <int EPI>
__device__ __forceinline__
void g256_body(const u16* __restrict__ A, const u16* __restrict__ Bt,
               void* __restrict__ Cv, int N, int ldk, int klen,
               int bm, int bn) {
  extern __shared__ __align__(16) u16 lds[];
  const int tid = threadIdx.x, lane = tid & 63, w = tid >> 6;
  const int wr = w >> 2, wc = w & 3;
  const int l16 = lane & 15, lhi = lane >> 4;
  const int NT = klen >> 5;

  f32x4 acc[8][4];
#pragma unroll
  for (int i = 0; i < 8; ++i)
#pragma unroll
    for (int j = 0; j < 4; ++j)
#pragma unroll
      for (int r = 0; r < 4; ++r) acc[i][j][r] = 0.f;

  const int sd = tid * 16;
  const int sr = sd >> 6;
  const int sc = ((sd >> 4) & 3) ^ ((sr >> 1) & 3);
  const int sdst = w * 512;

  const int spn = lhi ^ ((l16 >> 1) & 3);
  const int aBase = wr * 4096 + l16 * 32 + spn * 8;
  const int bBase = 8192 + (wc >> 1) * 4096 + ((wc & 1) * 64 + l16) * 32 + spn * 8;

  auto stage_ht = [&](int kt, int ht) {
    const u16* src = (ht < 2) ? A : Bt;
    int rowbase = ((ht < 2) ? bm : bn) + (ht & 1) * 128;
    gld_lds16(src + (size_t)(rowbase + sr) * ldk + kt * 32 + sc * 8,
              &lds[(kt & 3) * 16384 + ht * 4096 + sdst]);
  };

#pragma unroll
  for (int t = 0; t < 3; ++t)
#pragma unroll
    for (int h = 0; h < 4; ++h) stage_ht(t, h);
  asm volatile("s_waitcnt vmcnt(8)" ::: "memory");
  __builtin_amdgcn_s_barrier();

  short8 a[4], b[4];
  for (int kt = 0; kt < NT; ++kt) {
    const int pb = (kt & 3) * 16384;
    __builtin_amdgcn_sched_barrier(0);
    // ---- phase 1 ----
#pragma unroll
    for (int mi = 0; mi < 4; ++mi)
      a[mi] = *reinterpret_cast<const short8*>(&lds[pb + aBase + mi * 512]);
#pragma unroll
    for (int ni = 0; ni < 4; ++ni)
      b[ni] = *reinterpret_cast<const short8*>(&lds[pb + bBase + ni * 512]);
    if (kt + 3 < NT) { stage_ht(kt + 3, 0); stage_ht(kt + 3, 1); }
    __builtin_amdgcn_s_barrier();
    asm volatile("s_waitcnt lgkmcnt(0)" ::: "memory");
    __builtin_amdgcn_sched_barrier(0);
    __builtin_amdgcn_s_setprio(1);
#pragma unroll
    for (int mi = 0; mi < 4; ++mi)
#pragma unroll
      for (int ni = 0; ni < 4; ++ni)
        acc[mi][ni] = __builtin_amdgcn_mfma_f32_16x16x32_bf16(a[mi], b[ni], acc[mi][ni], 0, 0, 0);
    __builtin_amdgcn_s_setprio(0);
    __builtin_amdgcn_s_barrier();
    __builtin_amdgcn_sched_barrier(0);
    // ---- phase 2 ----
#pragma unroll
    for (int mi = 0; mi < 4; ++mi)
      a[mi] = *reinterpret_cast<const short8*>(&lds[pb + aBase + 2048 + mi * 512]);
    if (kt + 3 < NT) { stage_ht(kt + 3, 2); stage_ht(kt + 3, 3); }
    __builtin_amdgcn_s_barrier();
    asm volatile("s_waitcnt lgkmcnt(0)" ::: "memory");
    __builtin_amdgcn_sched_barrier(0);
    __builtin_amdgcn_s_setprio(1);
#pragma unroll
    for (int mi = 0; mi < 4; ++mi)
#pragma unroll
      for (int ni = 0; ni < 4; ++ni)
        acc[4 + mi][ni] = __builtin_amdgcn_mfma_f32_16x16x32_bf16(a[mi], b[ni], acc[4 + mi][ni], 0, 0, 0);
    __builtin_amdgcn_s_setprio(0);
    if (kt + 4 <= NT)      asm volatile("s_waitcnt vmcnt(8)" ::: "memory");
    else if (kt + 3 == NT) asm volatile("s_waitcnt vmcnt(4)" ::: "memory");
    else if (kt + 2 == NT) asm volatile("s_waitcnt vmcnt(0)" ::: "memory");
    __builtin_amdgcn_s_barrier();
  }

#pragma unroll
  for (int q = 0; q < 8; ++q)
#pragma unroll
    for (int ni = 0; ni < 4; ++ni)
#pragma unroll
      for (int r = 0; r < 4; ++r) {
        int row = bm + wr * 128 + (q >> 2) * 64 + (q & 3) * 16 + lhi * 4 + r;
        int col = bn + wc * 64 + ni * 16 + l16;
        size_t o = (size_t)row * N + col;
        float v = acc[q][ni][r];
        if constexpr (EPI == 0) ((float*)Cv)[o] = v;
        else if constexpr (EPI == 1) ((u16*)Cv)[o] = f2b(v);
        else { v = fmaxf(v, 0.f); ((u16*)Cv)[o] = f2b(v * v); }
      }
}

// ========== 256x128 8-wave pipelined GEMM (wave tile 128x32) ==========
__device__ __forceinline__
void g128_body(const u16* __restrict__ A, const u16* __restrict__ Bt,
               u16* __restrict__ Cv, int N, int ldk, int klen,
               int bm, int bn) {
  extern __shared__ __align__(16) u16 lds[];
  const int tid = threadIdx.x, lane = tid & 63, w = tid >> 6;
  const int wr = w >> 2, wc = w & 3;
  const int l16 = lane & 15, lhi = lane >> 4;
  const int NT = klen >> 5;

  f32x4 acc[8][2];
#pragma unroll
  for (int i = 0; i < 8; ++i)
#pragma unroll
    for (int j = 0; j < 2; ++j)
#pragma unroll
      for (int r = 0; r < 4; ++r) acc[i][j][r] = 0.f;

  const int sd = tid * 16;
  const int sr = sd >> 6;
  const int sc = ((sd >> 4) & 3) ^ ((sr >> 1) & 3);
  const int sdst = w * 512;

  const int spn = lhi ^ ((l16 >> 1) & 3);
  const int aBase = wr * 4096 + l16 * 32 + spn * 8;
  const int bBase = 8192 + (wc * 32 + l16) * 32 + spn * 8;

  auto stage_ht = [&](int kt, int ht) {
    const u16* src = (ht < 2) ? A : Bt;
    int rowbase = (ht < 2) ? (bm + ht * 128) : bn;
    int dsto = (ht < 2) ? ht * 4096 : 8192;
    gld_lds16(src + (size_t)(rowbase + sr) * ldk + kt * 32 + sc * 8,
              &lds[(kt & 3) * 12288 + dsto + sdst]);
  };

#pragma unroll
  for (int t = 0; t < 3; ++t) {
    stage_ht(t, 0); stage_ht(t, 1); stage_ht(t, 2);
  }
  asm volatile("s_waitcnt vmcnt(6)" ::: "memory");
  __builtin_amdgcn_s_barrier();

  short8 a[4], b[2];
  for (int kt = 0; kt < NT; ++kt) {
    const int pb = (kt & 3) * 12288;
    __builtin_amdgcn_sched_barrier(0);
    // ---- phase 1: wave rows 0-63 ----
#pragma unroll
    for (int mi = 0; mi < 4; ++mi)
      a[mi] = *reinterpret_cast<const short8*>(&lds[pb + aBase + mi * 512]);
#pragma unroll
    for (int ni = 0; ni < 2; ++ni)
      b[ni] = *reinterpret_cast<const short8*>(&lds[pb + bBase + ni * 512]);
    if (kt + 3 < NT) { stage_ht(kt + 3, 0); stage_ht(kt + 3, 1); }
    __builtin_amdgcn_s_barrier();
    asm volatile("s_waitcnt lgkmcnt(0)" ::: "memory");
    __builtin_amdgcn_sched_barrier(0);
    __builtin_amdgcn_s_setprio(1);
#pragma unroll
    for (int mi = 0; mi < 4; ++mi)
#pragma unroll
      for (int ni = 0; ni < 2; ++ni)
        acc[mi][ni] = __builtin_amdgcn_mfma_f32_16x16x32_bf16(a[mi], b[ni], acc[mi][ni], 0, 0, 0);
    __builtin_amdgcn_s_setprio(0);
    __builtin_amdgcn_s_barrier();
    __builtin_amdgcn_sched_barrier(0);
    // ---- phase 2: wave rows 64-127 ----
#pragma unroll
    for (int mi = 0; mi < 4; ++mi)
      a[mi] = *reinterpret_cast<const short8*>(&lds[pb + aBase + 2048 + mi * 512]);
    if (kt + 3 < NT) stage_ht(kt + 3, 2);
    __builtin_amdgcn_s_barrier();
    asm volatile("s_waitcnt lgkmcnt(0)" ::: "memory");
    __builtin_amdgcn_sched_barrier(0);
    __builtin_amdgcn_s_setprio(1);
#pragma unroll
    for (int mi = 0; mi < 4; ++mi)
#pragma unroll
      for (int ni = 0; ni < 2; ++ni)
        acc[4 + mi][ni] = __builtin_amdgcn_mfma_f32_16x16x32_bf16(a[mi], b[ni], acc[4 + mi][ni], 0, 0, 0);
    __builtin_amdgcn_s_setprio(0);
    if (kt + 4 <= NT)      asm volatile("s_waitcnt vmcnt(6)" ::: "memory");
    else if (kt + 3 == NT) asm volatile("s_waitcnt vmcnt(3)" ::: "memory");
    else if (kt + 2 == NT) asm volatile("s_waitcnt vmcnt(0)" ::: "memory");
    __builtin_amdgcn_s_barrier();
  }

#pragma unroll
  for (int q = 0; q < 8; ++q)
#pragma unroll
    for (int ni = 0; ni < 2; ++ni)
#pragma unroll
      for (int r = 0; r < 4; ++r) {
        int row = bm + wr * 128 + (q >> 2) * 64 + (q & 3) * 16 + lhi * 4 + r;
        int col = bn + wc * 32 + ni * 16 + l16;
        Cv[(size_t)row * N + col] = f2b(acc[q][ni][r]);
      }
}

// ---------------- GEMM kernel wrappers ----------------

// cm_Wv: split-K x4 over H, bf16 partials; grid 256
__global__ __launch_bounds__(512)
void k_g256_wv(const u16* __restrict__ A, const u16* __restrict__ Bt,
               u16* __restrict__ P) {
  int bid = blockIdx.x;
  int wg = (bid & 7) * 32 + (bid >> 3);
  int z = wg >> 6, rem = wg & 63;
  int lb = rem & 3, sv = rem >> 2;
  int by = (sv >> 1) * 2 + (lb & 1);
  int bx = (sv & 1) * 2 + (lb >> 1);
  g256_body<1>(A + z * 1024, Bt + z * 1024, P + (size_t)z * L_SEQ * EDIM,
               EDIM, HDIM, 1024, by * 256, bx * 256);
}

// merged: cm_Wk (sqrelu, 256 blocks) + cm_Wr split-K x2 (256 blocks)
__global__ __launch_bounds__(512)
void k_g256_cm(const u16* __restrict__ kxb, const u16* __restrict__ Wk,
               u16* __restrict__ kkb,
               const u16* __restrict__ rxb, const u16* __restrict__ Wr,
               u16* __restrict__ PR) {
  int bid = blockIdx.x;
  if (bid < 256) {
    int wg = (bid & 7) * 32 + (bid >> 3);
    int lb = wg & 3, sv = wg >> 2;
    int by = (sv >> 3) * 2 + (lb & 1);
    int bx = (sv & 7) * 2 + (lb >> 1);
    g256_body<2>(kxb, Wk, kkb, HDIM, EDIM, EDIM, by * 256, bx * 256);
  } else {
    int b = bid - 256;
    int wg = (b & 7) * 32 + (b >> 3);
    int z = wg >> 7, rem = wg & 127;
    int by = rem >> 3, bx = rem & 7;
    g128_body(rxb + z * 512, Wr + z * 512, PR + (size_t)z * L_SEQ * EDIM,
              EDIM, EDIM, 512, by * 256, bx * 128);
  }
}

// k/v/r GEMMs on 256x128 tiles; grid 384 (1.5 blocks/CU)
__global__ __launch_bounds__(512)
void k_g128_3(const u16* __restrict__ A0, const u16* __restrict__ A1, const u16* __restrict__ A2,
              const u16* __restrict__ B0, const u16* __restrict__ B1, const u16* __restrict__ B2,
              u16* __restrict__ C0, u16* __restrict__ C1, u16* __restrict__ C2) {
  int bid = blockIdx.x;
  int wg = (bid & 7) * 48 + (bid >> 3);   // 384 = 8 * 48, bijective
  int z = wg >> 7, rem = wg & 127;
  int by = rem >> 3, bx = rem & 7;
  const u16* A = (z == 0) ? A0 : (z == 1) ? A1 : A2;
  const u16* B = (z == 0) ? B0 : (z == 1) ? B1 : B2;
  u16*       C = (z == 0) ? C0 : (z == 1) ? C1 : C2;
  g128_body(A, B, C, EDIM, EDIM, EDIM, by * 256, bx * 128);
}

// E^2 GEMM split-K x2 (Wo / neck), bf16 partials; grid 256
__global__ __launch_bounds__(512)
void k_gx128_sk2(const u16* __restrict__ A, const u16* __restrict__ Bt,
                 u16* __restrict__ P) {
  int bid = blockIdx.x;
  int wg = (bid & 7) * 32 + (bid >> 3);
  int z = wg >> 7, rem = wg & 127;
  int by = rem >> 3, bx = rem & 7;
  g128_body(A + z * 512, Bt + z * 512, P + (size_t)z * L_SEQ * EDIM,
            EDIM, EDIM, 512, by * 256, bx * 128);
}

// ---------------- chunk-parallel WKV (bf16 k/v/r) ----------------

__global__ void k_wkv_pass1(const u16* __restrict__ k, const u16* __restrict__ v,
                            const float* __restrict__ w_,
                            float* __restrict__ sa, float* __restrict__ sb,
                            float* __restrict__ sp) {
  int id = blockIdx.x * blockDim.x + threadIdx.x;
  int e = id & 1023, c = id >> 10;
  float D = __expf(w_[e]);
  float aa = 0.f, bb = 0.f, pp = -__builtin_inff();
  const u16* kp = k + (size_t)c * WKV_T * EDIM + e;
  const u16* vp = v + (size_t)c * WKV_T * EDIM + e;
#pragma unroll 4
  for (int i = 0; i < WKV_T; ++i) {
    float kk = b2f(kp[i * EDIM]), vv = b2f(vp[i * EDIM]);
    float ww = pp - D;
    float p2 = fmaxf(ww, kk);
    float e1 = __expf(ww - p2), e2 = __expf(kk - p2);
    aa = e1 * aa + e2 * vv;
    bb = e1 * bb + e2;
    pp = p2;
  }
  sa[id] = aa; sb[id] = bb; sp[id] = pp;
}

// parallel exclusive scan: 16 lanes/channel, 8 chunks/lane, shuffle combine
__global__ __launch_bounds__(256)
void k_wkv_scan16(const float* __restrict__ w_,
                  const float* __restrict__ sa, const float* __restrict__ sb,
                  const float* __restrict__ sp,
                  float* __restrict__ oa, float* __restrict__ ob,
                  float* __restrict__ op) {
  int t = blockIdx.x * blockDim.x + threadIdx.x;
  int e = t >> 4, j = t & (SCAN_LANES - 1);
  const float NEG = -1e30f;
  float DT = __expf(w_[e]) * (float)WKV_T;
  float Ea[SCAN_CPT], Eb[SCAN_CPT], Ep[SCAN_CPT];
  float A = 0.f, B = 0.f, P = NEG;
  int base = j * SCAN_CPT;
#pragma unroll
  for (int i = 0; i < SCAN_CPT; ++i) {
    int idx = (base + i) * EDIM + e;
    Ea[i] = A; Eb[i] = B; Ep[i] = P;
    float a = sa[idx], b = sb[idx], q = sp[idx];
    float shift = P - DT;
    float pn = fmaxf(shift, q);
    float w1 = __expf(shift - pn), w2 = __expf(q - pn);
    A = w1 * A + w2 * a; B = w1 * B + w2 * b; P = pn;
  }
  float tA = A, tB = B, tP = P; int tn = SCAN_CPT;
#pragma unroll
  for (int d = 1; d < SCAN_LANES; d <<= 1) {
    float fA = __shfl_up(tA, d, SCAN_LANES);
    float fB = __shfl_up(tB, d, SCAN_LANES);
    float fP = __shfl_up(tP, d, SCAN_LANES);
    int   fn = __shfl_up(tn, d, SCAN_LANES);
    if (j >= d) {
      float shift = fP - DT * (float)tn;
      float pn = fmaxf(shift, tP);
      float w1 = __expf(shift - pn), w2 = __expf(tP - pn);
      tA = w1 * fA + w2 * tA; tB = w1 * fB + w2 * tB; tP = pn; tn += fn;
    }
  }
  float pA = __shfl_up(tA, 1, SCAN_LANES);
  float pB = __shfl_up(tB, 1, SCAN_LANES);
  float pP = __shfl_up(tP, 1, SCAN_LANES);
  if (j == 0) { pA = 0.f; pB = 0.f; pP = NEG; }
#pragma unroll
  for (int i = 0; i < SCAN_CPT; ++i) {
    float shift = pP - DT * (float)i;
    float pn = fmaxf(shift, Ep[i]);
    float w1 = __expf(shift - pn), w2 = __expf(Ep[i] - pn);
    int idx = (base + i) * EDIM + e;
    oa[idx] = w1 * pA + w2 * Ea[i];
    ob[idx] = w1 * pB + w2 * Eb[i];
    op[idx] = pn;
  }
}

// pass2 with fused sigmoid gate: rwb = bf16(sig(rpre) * wkv)
__global__ void k_wkv_pass2(const u16* __restrict__ k, const u16* __restrict__ v,
                            const float* __restrict__ u_, const float* __restrict__ w_,
                            const float* __restrict__ sa, const float* __restrict__ sb,
                            const float* __restrict__ sp,
                            const u16* __restrict__ rpre, u16* __restrict__ rwb) {
  int id = blockIdx.x * blockDim.x + threadIdx.x;
  int e = id & 1023, c = id >> 10;
  float u = u_[e];
  float D = __expf(w_[e]);
  float aa = sa[id], bb = sb[id], pp = sp[id];
  const size_t base = (size_t)c * WKV_T * EDIM + e;
  const u16* kp = k + base;
  const u16* vp = v + base;
  const u16* rp = rpre + base;
  u16* op = rwb + base;
#pragma unroll 4
  for (int i = 0; i < WKV_T; ++i) {
    float kk = b2f(kp[i * EDIM]), vv = b2f(vp[i * EDIM]);
    float ww = u + kk;
    float p = fmaxf(pp, ww);
    float e1 = __expf(pp - p), e2 = __expf(ww - p);
    float out = (e1 * aa + e2 * vv) / (e1 * bb + e2);
    op[i * EDIM] = f2b(out * sigm(b2f(rp[i * EDIM])));
    float w2s = pp - D;
    float p2 = fmaxf(w2s, kk);
    float e1b = __expf(w2s - p2), e2b = __expf(kk - p2);
    aa = e1b * aa + e2b * vv;
    bb = e1b * bb + e2b;
    pp = p2;
  }
}

// ---------------- head (fused gelu, 2 neck partials) ----------------
__global__ __launch_bounds__(256)
void k_head(const u16* __restrict__ P, const float* __restrict__ nb,
            const float* __restrict__ W,
            const int* __restrict__ s, float* __restrict__ partial) {
  const size_t LE = (size_t)L_SEQ * EDIM;
  int t = blockIdx.x, tid = threadIdx.x;
  float a0 = 0.f, a1 = 0.f, a2 = 0.f, a3 = 0.f;
  for (int e = tid; e < EDIM; e += 256) {
    size_t i = (size_t)t * EDIM + e;
    float hv = gelu1(b2f(P[i]) + b2f(P[i + LE]) + nb[e]);
    const float4 wv = *reinterpret_cast<const float4*>(W + e * 4);
    a0 += hv * wv.x; a1 += hv * wv.y; a2 += hv * wv.z; a3 += hv * wv.w;
  }
#pragma unroll
  for (int off = 32; off > 0; off >>= 1) {
    a0 += __shfl_down(a0, off, 64);
    a1 += __shfl_down(a1, off, 64);
    a2 += __shfl_down(a2, off, 64);
    a3 += __shfl_down(a3, off, 64);
  }
  __shared__ float sm[4][4];
  int w = tid >> 6, lane = tid & 63;
  if (lane == 0) { sm[w][0] = a0; sm[w][1] = a1; sm[w][2] = a2; sm[w][3] = a3; }
  __syncthreads();
  if (tid == 0) {
    float lg[4];
#pragma unroll
    for (int j = 0; j < 4; ++j) lg[j] = sm[0][j] + sm[1][j] + sm[2][j] + sm[3][j];
    float m = fmaxf(fmaxf(lg[0], lg[1]), fmaxf(lg[2], lg[3]));
    float sum = expf(lg[0] - m) + expf(lg[1] - m) + expf(lg[2] - m) + expf(lg[3] - m);
    partial[t] = 0.5f * (lg[s[t]] - m - logf(sum));
  }
}

__global__ __launch_bounds__(256)
void k_reduce(const float* __restrict__ partial, float* __restrict__ out) {
  int tid = threadIdx.x;
  float a = 0.f;
  for (int j = tid; j < L_SEQ; j += 256) a += partial[j];
#pragma unroll
  for (int off = 32; off > 0; off >>= 1) a += __shfl_down(a, off, 64);
  __shared__ float sm[4];
  if ((tid & 63) == 0) sm[tid >> 6] = a;
  __syncthreads();
  if (tid == 0) out[0] = sm[0] + sm[1] + sm[2] + sm[3];
}

// ---------------- host ----------------

extern "C" void kernel_launch(void* const* d_in, const int* in_sizes, int n_in,
                              void* d_out, int out_size, void* d_ws, size_t ws_size,
                              hipStream_t stream) {
  const int*   s        = (const int*)d_in[0];
  const float* embed    = (const float*)d_in[1];
  const float* tm_first = (const float*)d_in[2];
  const float* tm_decay = (const float*)d_in[3];
  const float* tm_mk    = (const float*)d_in[4];
  const float* tm_mv    = (const float*)d_in[5];
  const float* tm_mr    = (const float*)d_in[6];
  const float* tm_Wk    = (const float*)d_in[7];
  const float* tm_Wv    = (const float*)d_in[8];
  const float* tm_Wr    = (const float*)d_in[9];
  const float* tm_Wo    = (const float*)d_in[10];
  const float* cm_mk    = (const float*)d_in[11];
  const float* cm_mr    = (const float*)d_in[12];
  const float* cm_Wk    = (const float*)d_in[13];
  const float* cm_Wr    = (const float*)d_in[14];
  const float* cm_Wv    = (const float*)d_in[15];
  const float* neck_W   = (const float*)d_in[16];
  const float* neck_b   = (const float*)d_in[17];
  const float* head_W   = (const float*)d_in[18];

  char* ws = (char*)d_ws;
  size_t off = 0;
  auto alloc = [&](size_t bytes) { char* p = ws + off; off += (bytes + 255) & ~(size_t)255; return p; };
  const size_t LE2 = (size_t)L_SEQ * EDIM * 2;
  const size_t EE  = (size_t)EDIM * EDIM, EH = (size_t)EDIM * HDIM;

  u16*   xA    = (u16*)alloc(LE2);
  u16*   xB    = (u16*)alloc(LE2);
  u16*   kxb   = (u16*)alloc(LE2);
  u16*   vxb   = (u16*)alloc(LE2);   // also rwb
  u16*   rxb   = (u16*)alloc(LE2);
  u16*   kf    = (u16*)alloc(LE2);
  u16*   vf    = (u16*)alloc(LE2);
  u16*   rpre  = (u16*)alloc(LE2);
  u16*   kkb   = (u16*)alloc((size_t)L_SEQ * HDIM * 2);
  u16*   PA    = (u16*)alloc(2 * LE2);   // Wo / neck partials (bf16 x2)
  u16*   PR    = (u16*)alloc(2 * LE2);   // cm_Wr partials (bf16 x2)
  u16*   PB    = (u16*)alloc(4 * LE2);   // cm_Wv partials (bf16 x4)
  float* partial = (float*)alloc((size_t)L_SEQ * 4);
  float* sa  = (float*)alloc((size_t)WKV_C * EDIM * 4);
  float* sb  = (float*)alloc((size_t)WKV_C * EDIM * 4);
  float* sp  = (float*)alloc((size_t)WKV_C * EDIM * 4);
  float* sa2 = (float*)alloc((size_t)WKV_C * EDIM * 4);
  float* sb2 = (float*)alloc((size_t)WKV_C * EDIM * 4);
  float* sp2 = (float*)alloc((size_t)WKV_C * EDIM * 4);

  size_t remain = (ws_size > off) ? ws_size - off : 0;
  const size_t bigNeed = (5 * EE * NLAY + 2 * EH * NLAY + EE) * 2 + 16 * 256;
  const bool big = remain >= bigNeed;
  const int NB = big ? NLAY : 1;
  u16* wWk   = (u16*)alloc(EE * NB * 2);
  u16* wWv   = (u16*)alloc(EE * NB * 2);
  u16* wWr   = (u16*)alloc(EE * NB * 2);
  u16* wWo   = (u16*)alloc(EE * NB * 2);
  u16* wcmWr = (u16*)alloc(EE * NB * 2);
  u16* wcmWk = (u16*)alloc(EH * NB * 2);
  u16* wcmWv = (u16*)alloc(EH * NB * 2);
  u16* wneck = big ? (u16*)alloc(EE * 2) : wWk;

  const dim3 blk(256);
  const dim3 blk512(512);
  const dim3 gE4((L_SEQ * EDIM) / 1024);
  const dim3 gWkv((WKV_C * EDIM) / 256);
  const dim3 gScan((EDIM * SCAN_LANES) / 256);
  const size_t DLDS  = 131072;  // 128KB for 256^2
  const size_t DLDS2 = 98304;   // 96KB for 256x128

  if (big) {
    k_tconv_all<<<dim3(TC_EE + 2 * TC_EH), blk, 0, stream>>>(
        tm_Wk, tm_Wv, tm_Wr, tm_Wo, cm_Wr, neck_W, cm_Wk, cm_Wv,
        wWk, wWv, wWr, wWo, wcmWr, wneck, wcmWk, wcmWv);
  }

  for (int l = 0; l < NLAY; ++l) {
    size_t oE  = (size_t)l * EDIM;
    size_t oEE = (size_t)l * EE;
    size_t oEH = (size_t)l * EH;
    size_t wE  = big ? oEE : 0;
    size_t wH  = big ? oEH : 0;
    if (!big) {
      k_tconv<<<dim3(EDIM / 64, EDIM / 64, 1), blk, 0, stream>>>(tm_Wk + oEE, wWk, EDIM, EDIM);
      k_tconv<<<dim3(EDIM / 64, EDIM / 64, 1), blk, 0, stream>>>(tm_Wv + oEE, wWv, EDIM, EDIM);
      k_tconv<<<dim3(EDIM / 64, EDIM / 64, 1), blk, 0, stream>>>(tm_Wr + oEE, wWr, EDIM, EDIM);
      k_tconv<<<dim3(EDIM / 64, EDIM / 64, 1), blk, 0, stream>>>(tm_Wo + oEE, wWo, EDIM, EDIM);
      k_tconv<<<dim3(EDIM / 64, EDIM / 64, 1), blk, 0, stream>>>(cm_Wr + oEE, wcmWr, EDIM, EDIM);
      k_tconv<<<dim3(HDIM / 64, EDIM / 64, 1), blk, 0, stream>>>(cm_Wk + oEH, wcmWk, EDIM, HDIM);
      k_tconv<<<dim3(EDIM / 64, HDIM / 64, 1), blk, 0, stream>>>(cm_Wv + oEH, wcmWv, HDIM, EDIM);
    }
    // --- TimeMixing ---
    if (l == 0)
      k_f0<<<gE4, blk, 0, stream>>>(s, embed, tm_mk + oE, tm_mv + oE, tm_mr + oE,
                                    xA, kxb, vxb, rxb);
    else
      k_f1<<<gE4, blk, 0, stream>>>(xB, PR, PB, tm_mk + oE, tm_mv + oE, tm_mr + oE,
                                    xA, kxb, vxb, rxb);
    k_g128_3<<<dim3(384), blk512, DLDS2, stream>>>(kxb, vxb, rxb,
                                                   wWk + wE, wWv + wE, wWr + wE,
                                                   kf, vf, rpre);
    k_wkv_pass1<<<gWkv, blk, 0, stream>>>(kf, vf, tm_decay + oE, sa, sb, sp);
    k_wkv_scan16<<<gScan, blk, 0, stream>>>(tm_decay + oE, sa, sb, sp, sa2, sb2, sp2);
    k_wkv_pass2<<<gWkv, blk, 0, stream>>>(kf, vf, tm_first + oE, tm_decay + oE,
                                          sa2, sb2, sp2, rpre, vxb);
    k_gx128_sk2<<<dim3(256), blk512, DLDS2, stream>>>(vxb, wWo + wE, PA);
    // --- ChannelMixing ---
    k_f2<<<gE4, blk, 0, stream>>>(xA, PA, cm_mk + oE, cm_mr + oE, xB, kxb, rxb);
    k_g256_cm<<<dim3(512), blk512, DLDS, stream>>>(kxb, wcmWk + wH, kkb,
                                                   rxb, wcmWr + wE, PR);
    k_g256_wv<<<dim3(256), blk512, DLDS, stream>>>(kkb, wcmWv + wH, PB);
  }
  // --- Neck + Head ---
  if (!big) k_tconv<<<dim3(EDIM / 64, EDIM / 64, 1), blk, 0, stream>>>(neck_W, wneck, EDIM, EDIM);
  k_f3<<<gE4, blk, 0, stream>>>(xB, PR, PB, kxb);
  k_gx128_sk2<<<dim3(256), blk512, DLDS2, stream>>>(kxb, wneck, PA);
  k_head<<<dim3(L_SEQ), blk, 0, stream>>>(PA, neck_b, head_W, s, partial);
  k_reduce<<<dim3(1), blk, 0, stream>>>(partial, (float*)d_out);

  (void)in_sizes; (void)n_in; (void)out_size;
}

// Round 14
// 1774.898 us; speedup vs baseline: 1.0230x; 1.0230x over previous
//
#include <hip/hip_runtime.h>
#include <stdint.h>

#define L_SEQ 4096
#define EDIM  1024
#define HDIM  4096
#define NLAY  8
#define WKV_C 128  // chunks
#define WKV_T 32   // tokens per chunk
#define SCAN_LANES 16
#define SCAN_CPT   (WKV_C / SCAN_LANES)  // 8

typedef unsigned short u16;
typedef __attribute__((ext_vector_type(8))) short short8;
typedef __attribute__((ext_vector_type(4))) float f32x4;
typedef __attribute__((ext_vector_type(4))) float f4v;
typedef __attribute__((ext_vector_type(4))) unsigned short us4;
typedef __attribute__((ext_vector_type(8))) unsigned short us8;

static __device__ __forceinline__ u16 f2b(float f) {
  union { float f; uint32_t u; } a; a.f = f;
  uint32_t u = a.u;
  return (u16)((u + 0x7FFFu + ((u >> 16) & 1u)) >> 16);  // RNE
}
static __device__ __forceinline__ float b2f(u16 b) {
  union { uint32_t u; float f; } a; a.u = ((uint32_t)b) << 16;
  return a.f;
}
static __device__ __forceinline__ float sigm(float v) {
  return 1.f / (1.f + __expf(-v));
}
static __device__ __forceinline__ float4 ld_bf4(const u16* __restrict__ p, size_t i) {
  us4 v = *reinterpret_cast<const us4*>(&p[i]);
  return make_float4(b2f(v.x), b2f(v.y), b2f(v.z), b2f(v.w));
}

static __device__ __forceinline__ void gld_lds16(const void* g, void* l) {
  __builtin_amdgcn_global_load_lds(
      (const __attribute__((address_space(1))) void*)g,
      (__attribute__((address_space(3))) void*)l, 16, 0, 0);
}

// ---------------- fused elementwise (x residual in bf16) ----------------

// F0: x = embed[tok], tm-mix3 (layer 0)
__global__ void k_f0(const int* __restrict__ s, const float* __restrict__ embed,
                     const float* __restrict__ mk, const float* __restrict__ mv,
                     const float* __restrict__ mr, u16* __restrict__ xA,
                     u16* __restrict__ kx, u16* __restrict__ vx, u16* __restrict__ rx) {
  int i = (blockIdx.x * blockDim.x + threadIdx.x) * 4;
  int t = i >> 10, e = i & 1023;
  int tok = (t == 0) ? 0 : s[t - 1];
  float4 xc = *reinterpret_cast<const float4*>(&embed[tok * EDIM + e]);
  float4 xs = make_float4(0.f, 0.f, 0.f, 0.f);
  if (t > 0) {
    int tokp = (t == 1) ? 0 : s[t - 2];
    xs = *reinterpret_cast<const float4*>(&embed[tokp * EDIM + e]);
  }
  us4 ox; ox.x = f2b(xc.x); ox.y = f2b(xc.y); ox.z = f2b(xc.z); ox.w = f2b(xc.w);
  *reinterpret_cast<us4*>(&xA[i]) = ox;
  float4 m; us4 o;
  m = *reinterpret_cast<const float4*>(&mk[e]);
  o.x = f2b(xc.x * m.x + xs.x * (1.f - m.x)); o.y = f2b(xc.y * m.y + xs.y * (1.f - m.y));
  o.z = f2b(xc.z * m.z + xs.z * (1.f - m.z)); o.w = f2b(xc.w * m.w + xs.w * (1.f - m.w));
  *reinterpret_cast<us4*>(&kx[i]) = o;
  m = *reinterpret_cast<const float4*>(&mv[e]);
  o.x = f2b(xc.x * m.x + xs.x * (1.f - m.x)); o.y = f2b(xc.y * m.y + xs.y * (1.f - m.y));
  o.z = f2b(xc.z * m.z + xs.z * (1.f - m.z)); o.w = f2b(xc.w * m.w + xs.w * (1.f - m.w));
  *reinterpret_cast<us4*>(&vx[i]) = o;
  m = *reinterpret_cast<const float4*>(&mr[e]);
  o.x = f2b(xc.x * m.x + xs.x * (1.f - m.x)); o.y = f2b(xc.y * m.y + xs.y * (1.f - m.y));
  o.z = f2b(xc.z * m.z + xs.z * (1.f - m.z)); o.w = f2b(xc.w * m.w + xs.w * (1.f - m.w));
  *reinterpret_cast<us4*>(&rx[i]) = o;
}

// cm-finish: x = xB + sig(PR0+PR1) * (PB0+PB1+PB2+PB3)  (all bf16)
static __device__ __forceinline__ float4 cm_finish(const u16* __restrict__ xB,
                                                   const u16* __restrict__ PR,
                                                   const u16* __restrict__ PB, int i) {
  const size_t LE = (size_t)L_SEQ * EDIM;
  float4 xm = ld_bf4(xB, i);
  float4 r0 = ld_bf4(PR, i), r1 = ld_bf4(PR, i + LE);
  float4 v0 = ld_bf4(PB, i), v1 = ld_bf4(PB, i + LE);
  float4 v2 = ld_bf4(PB, i + 2 * LE), v3 = ld_bf4(PB, i + 3 * LE);
  xm.x += sigm(r0.x + r1.x) * (v0.x + v1.x + v2.x + v3.x);
  xm.y += sigm(r0.y + r1.y) * (v0.y + v1.y + v2.y + v3.y);
  xm.z += sigm(r0.z + r1.z) * (v0.z + v1.z + v2.z + v3.z);
  xm.w += sigm(r0.w + r1.w) * (v0.w + v1.w + v2.w + v3.w);
  return xm;
}

// F1: x = cm_finish; tm-mix3 (layers 1..7)
__global__ void k_f1(const u16* __restrict__ xB, const u16* __restrict__ PR,
                     const u16* __restrict__ PB,
                     const float* __restrict__ mk, const float* __restrict__ mv,
                     const float* __restrict__ mr, u16* __restrict__ xA,
                     u16* __restrict__ kx, u16* __restrict__ vx, u16* __restrict__ rx) {
  int i = (blockIdx.x * blockDim.x + threadIdx.x) * 4;
  int e = i & 1023;
  float4 xc = cm_finish(xB, PR, PB, i);
  float4 xs = make_float4(0.f, 0.f, 0.f, 0.f);
  if (i >= EDIM) xs = cm_finish(xB, PR, PB, i - EDIM);
  us4 ox; ox.x = f2b(xc.x); ox.y = f2b(xc.y); ox.z = f2b(xc.z); ox.w = f2b(xc.w);
  *reinterpret_cast<us4*>(&xA[i]) = ox;
  float4 m; us4 o;
  m = *reinterpret_cast<const float4*>(&mk[e]);
  o.x = f2b(xc.x * m.x + xs.x * (1.f - m.x)); o.y = f2b(xc.y * m.y + xs.y * (1.f - m.y));
  o.z = f2b(xc.z * m.z + xs.z * (1.f - m.z)); o.w = f2b(xc.w * m.w + xs.w * (1.f - m.w));
  *reinterpret_cast<us4*>(&kx[i]) = o;
  m = *reinterpret_cast<const float4*>(&mv[e]);
  o.x = f2b(xc.x * m.x + xs.x * (1.f - m.x)); o.y = f2b(xc.y * m.y + xs.y * (1.f - m.y));
  o.z = f2b(xc.z * m.z + xs.z * (1.f - m.z)); o.w = f2b(xc.w * m.w + xs.w * (1.f - m.w));
  *reinterpret_cast<us4*>(&vx[i]) = o;
  m = *reinterpret_cast<const float4*>(&mr[e]);
  o.x = f2b(xc.x * m.x + xs.x * (1.f - m.x)); o.y = f2b(xc.y * m.y + xs.y * (1.f - m.y));
  o.z = f2b(xc.z * m.z + xs.z * (1.f - m.z)); o.w = f2b(xc.w * m.w + xs.w * (1.f - m.w));
  *reinterpret_cast<us4*>(&rx[i]) = o;
}

static __device__ __forceinline__ float4 tm_finish(const u16* __restrict__ xA,
                                                   const u16* __restrict__ PA, int i) {
  const size_t LE = (size_t)L_SEQ * EDIM;
  float4 xm = ld_bf4(xA, i);
  float4 a = ld_bf4(PA, i), b = ld_bf4(PA, i + LE);
  xm.x += a.x + b.x; xm.y += a.y + b.y; xm.z += a.z + b.z; xm.w += a.w + b.w;
  return xm;
}

// F2: x = xA + PA0 + PA1; cm-mix2
__global__ void k_f2(const u16* __restrict__ xA, const u16* __restrict__ PA,
                     const float* __restrict__ mk, const float* __restrict__ mr,
                     u16* __restrict__ xB, u16* __restrict__ kx, u16* __restrict__ rx) {
  int i = (blockIdx.x * blockDim.x + threadIdx.x) * 4;
  int e = i & 1023;
  float4 xc = tm_finish(xA, PA, i);
  float4 xs = make_float4(0.f, 0.f, 0.f, 0.f);
  if (i >= EDIM) xs = tm_finish(xA, PA, i - EDIM);
  us4 ox; ox.x = f2b(xc.x); ox.y = f2b(xc.y); ox.z = f2b(xc.z); ox.w = f2b(xc.w);
  *reinterpret_cast<us4*>(&xB[i]) = ox;
  float4 m; us4 o;
  m = *reinterpret_cast<const float4*>(&mk[e]);
  o.x = f2b(xc.x * m.x + xs.x * (1.f - m.x)); o.y = f2b(xc.y * m.y + xs.y * (1.f - m.y));
  o.z = f2b(xc.z * m.z + xs.z * (1.f - m.z)); o.w = f2b(xc.w * m.w + xs.w * (1.f - m.w));
  *reinterpret_cast<us4*>(&kx[i]) = o;
  m = *reinterpret_cast<const float4*>(&mr[e]);
  o.x = f2b(xc.x * m.x + xs.x * (1.f - m.x)); o.y = f2b(xc.y * m.y + xs.y * (1.f - m.y));
  o.z = f2b(xc.z * m.z + xs.z * (1.f - m.z)); o.w = f2b(xc.w * m.w + xs.w * (1.f - m.w));
  *reinterpret_cast<us4*>(&rx[i]) = o;
}

// F3: hb = bf16(cm_finish)
__global__ void k_f3(const u16* __restrict__ xB, const u16* __restrict__ PR,
                     const u16* __restrict__ PB, u16* __restrict__ hb) {
  int i = (blockIdx.x * blockDim.x + threadIdx.x) * 4;
  float4 xc = cm_finish(xB, PR, PB, i);
  us4 o;
  o.x = f2b(xc.x); o.y = f2b(xc.y); o.z = f2b(xc.z); o.w = f2b(xc.w);
  *reinterpret_cast<us4*>(&hb[i]) = o;
}

static __device__ __forceinline__ float gelu1(float v) {
  float c = 0.7978845608028654f * (v + 0.044715f * v * v * v);
  return 0.5f * v * (1.f + tanhf(c));
}

// ---------------- transpose + f32->bf16 (NT loads: weights read once) ----------------
static __device__ __forceinline__
void tconv2(const float* __restrict__ s, u16* __restrict__ d, int K, int N,
            int n0, int k0) {
  __shared__ float tile[64][65];
  int tid = threadIdx.x;
  int tx = tid & 15, ty = tid >> 4;
#pragma unroll
  for (int i = 0; i < 4; ++i) {
    int kr = ty + i * 16;
    f4v v = __builtin_nontemporal_load(
        reinterpret_cast<const f4v*>(&s[(size_t)(k0 + kr) * N + n0 + tx * 4]));
    tile[kr][tx * 4 + 0] = v.x; tile[kr][tx * 4 + 1] = v.y;
    tile[kr][tx * 4 + 2] = v.z; tile[kr][tx * 4 + 3] = v.w;
  }
  __syncthreads();
  int tx8 = tid & 7, ny = tid >> 3;
#pragma unroll
  for (int h = 0; h < 2; ++h) {
    int n = ny + h * 32;
    us8 o;
#pragma unroll
    for (int c = 0; c < 8; ++c) o[c] = f2b(tile[tx8 * 8 + c][n]);
    *reinterpret_cast<us8*>(&d[(size_t)(n0 + n) * K + k0 + tx8 * 8]) = o;
  }
}

__global__ __launch_bounds__(256)
void k_tconv(const float* __restrict__ src, u16* __restrict__ dst, int K, int N) {
  tconv2(src + (size_t)blockIdx.z * K * N, dst + (size_t)blockIdx.z * K * N,
         K, N, blockIdx.x * 64, blockIdx.y * 64);
}

// ALL weights in one flat launch: 41 ExE + 8 ExH (cm_Wk) + 8 HxE (cm_Wv)
#define TC_EE  (41 * 256)
#define TC_EH  8192
__global__ __launch_bounds__(256)
void k_tconv_all(const float* __restrict__ Wk, const float* __restrict__ Wv,
                 const float* __restrict__ Wr, const float* __restrict__ Wo,
                 const float* __restrict__ cWr, const float* __restrict__ nW,
                 const float* __restrict__ cWk, const float* __restrict__ cWv,
                 u16* __restrict__ oWk, u16* __restrict__ oWv, u16* __restrict__ oWr,
                 u16* __restrict__ oWo, u16* __restrict__ ocWr, u16* __restrict__ onW,
                 u16* __restrict__ ocWk, u16* __restrict__ ocWv) {
  const size_t EE = (size_t)EDIM * EDIM, EH = (size_t)EDIM * HDIM;
  int bid = blockIdx.x;
  if (bid < TC_EE) {
    int z = bid >> 8, rem = bid & 255;
    const float* src; u16* dst;
    if (z < 8)       { src = Wk  + (size_t)z * EE;        dst = oWk  + (size_t)z * EE; }
    else if (z < 16) { src = Wv  + (size_t)(z - 8) * EE;  dst = oWv  + (size_t)(z - 8) * EE; }
    else if (z < 24) { src = Wr  + (size_t)(z - 16) * EE; dst = oWr  + (size_t)(z - 16) * EE; }
    else if (z < 32) { src = Wo  + (size_t)(z - 24) * EE; dst = oWo  + (size_t)(z - 24) * EE; }
    else if (z < 40) { src = cWr + (size_t)(z - 32) * EE; dst = ocWr + (size_t)(z - 32) * EE; }
    else             { src = nW;                          dst = onW; }
    tconv2(src, dst, EDIM, EDIM, (rem & 15) * 64, (rem >> 4) * 64);
  } else if (bid < TC_EE + TC_EH) {
    int b = bid - TC_EE;
    int z = b >> 10, rem = b & 1023;
    tconv2(cWk + (size_t)z * EH, ocWk + (size_t)z * EH, EDIM, HDIM,
           (rem & 63) * 64, (rem >> 6) * 64);
  } else {
    int b = bid - TC_EE - TC_EH;
    int z = b >> 10, rem = b & 1023;
    tconv2(cWv + (size_t)z * EH, ocWv + (size_t)z * EH, HDIM, EDIM,
           (rem & 15) * 64, (rem >> 4) * 64);
  }
}

// ========== 256x256 8-wave pipelined GEMM (2 phases / K-tile of 32) ==========
// EPI: 0 = f32 store, 1 = bf16 store, 2 = bf16(relu^2)
template <int EPI>
__device__ __forceinline__
void g256_body(const u16* __restrict__ A, const u16* __restrict__ Bt,
               void* __restrict__ Cv, int N, int ldk, int klen,
               int bm, int bn) {
  extern __shared__ __align__(16) u16 lds[];
  const int tid = threadIdx.x, lane = tid & 63, w = tid >> 6;
  const int wr = w >> 2, wc = w & 3;
  const int l16 = lane & 15, lhi = lane >> 4;
  const int NT = klen >> 5;

  f32x4 acc[8][4];
#pragma unroll
  for (int i = 0; i < 8; ++i)
#pragma unroll
    for (int j = 0; j < 4; ++j)
#pragma unroll
      for (int r = 0; r < 4; ++r) acc[i][j][r] = 0.f;

  const int sd = tid * 16;
  const int sr = sd >> 6;
  const int sc = ((sd >> 4) & 3) ^ ((sr >> 1) & 3);
  const int sdst = w * 512;

  const int spn = lhi ^ ((l16 >> 1) & 3);
  const int aBase = wr * 4096 + l16 * 32 + spn * 8;
  const int bBase = 8192 + (wc >> 1) * 4096 + ((wc & 1) * 64 + l16) * 32 + spn * 8;

  auto stage_ht = [&](int kt, int ht) {
    const u16* src = (ht < 2) ? A : Bt;
    int rowbase = ((ht < 2) ? bm : bn) + (ht & 1) * 128;
    gld_lds16(src + (size_t)(rowbase + sr) * ldk + kt * 32 + sc * 8,
              &lds[(kt & 3) * 16384 + ht * 4096 + sdst]);
  };

#pragma unroll
  for (int t = 0; t < 3; ++t)
#pragma unroll
    for (int h = 0; h < 4; ++h) stage_ht(t, h);
  asm volatile("s_waitcnt vmcnt(8)" ::: "memory");
  __builtin_amdgcn_s_barrier();

  short8 a[4], b[4];
  for (int kt = 0; kt < NT; ++kt) {
    const int pb = (kt & 3) * 16384;
    __builtin_amdgcn_sched_barrier(0);
    // ---- phase 1 ----
#pragma unroll
    for (int mi = 0; mi < 4; ++mi)
      a[mi] = *reinterpret_cast<const short8*>(&lds[pb + aBase + mi * 512]);
#pragma unroll
    for (int ni = 0; ni < 4; ++ni)
      b[ni] = *reinterpret_cast<const short8*>(&lds[pb + bBase + ni * 512]);
    if (kt + 3 < NT) { stage_ht(kt + 3, 0); stage_ht(kt + 3, 1); }
    __builtin_amdgcn_s_barrier();
    asm volatile("s_waitcnt lgkmcnt(0)" ::: "memory");
    __builtin_amdgcn_sched_barrier(0);
    __builtin_amdgcn_s_setprio(1);
#pragma unroll
    for (int mi = 0; mi < 4; ++mi)
#pragma unroll
      for (int ni = 0; ni < 4; ++ni)
        acc[mi][ni] = __builtin_amdgcn_mfma_f32_16x16x32_bf16(a[mi], b[ni], acc[mi][ni], 0, 0, 0);
    __builtin_amdgcn_s_setprio(0);
    __builtin_amdgcn_s_barrier();
    __builtin_amdgcn_sched_barrier(0);
    // ---- phase 2 ----
#pragma unroll
    for (int mi = 0; mi < 4; ++mi)
      a[mi] = *reinterpret_cast<const short8*>(&lds[pb + aBase + 2048 + mi * 512]);
    if (kt + 3 < NT) { stage_ht(kt + 3, 2); stage_ht(kt + 3, 3); }
    __builtin_amdgcn_s_barrier();
    asm volatile("s_waitcnt lgkmcnt(0)" ::: "memory");
    __builtin_amdgcn_sched_barrier(0);
    __builtin_amdgcn_s_setprio(1);
#pragma unroll
    for (int mi = 0; mi < 4; ++mi)
#pragma unroll
      for (int ni = 0; ni < 4; ++ni)
        acc[4 + mi][ni] = __builtin_amdgcn_mfma_f32_16x16x32_bf16(a[mi], b[ni], acc[4 + mi][ni], 0, 0, 0);
    __builtin_amdgcn_s_setprio(0);
    if (kt + 4 <= NT)      asm volatile("s_waitcnt vmcnt(8)" ::: "memory");
    else if (kt + 3 == NT) asm volatile("s_waitcnt vmcnt(4)" ::: "memory");
    else if (kt + 2 == NT) asm volatile("s_waitcnt vmcnt(0)" ::: "memory");
    __builtin_amdgcn_s_barrier();
  }

#pragma unroll
  for (int q = 0; q < 8; ++q)
#pragma unroll
    for (int ni = 0; ni < 4; ++ni)
#pragma unroll
      for (int r = 0; r < 4; ++r) {
        int row = bm + wr * 128 + (q >> 2) * 64 + (q & 3) * 16 + lhi * 4 + r;
        int col = bn + wc * 64 + ni * 16 + l16;
        size_t o = (size_t)row * N + col;
        float v = acc[q][ni][r];
        if constexpr (EPI == 0) ((float*)Cv)[o] = v;
        else if constexpr (EPI == 1) ((u16*)Cv)[o] = f2b(v);
        else { v = fmaxf(v, 0.f); ((u16*)Cv)[o] = f2b(v * v); }
      }
}

// ========== 256x128 8-wave pipelined GEMM (wave tile 128x32) ==========
__device__ __forceinline__
void g128_body(const u16* __restrict__ A, const u16* __restrict__ Bt,
               u16* __restrict__ Cv, int N, int ldk, int klen,
               int bm, int bn) {
  extern __shared__ __align__(16) u16 lds[];
  const int tid = threadIdx.x, lane = tid & 63, w = tid >> 6;
  const int wr = w >> 2, wc = w & 3;
  const int l16 = lane & 15, lhi = lane >> 4;
  const int NT = klen >> 5;

  f32x4 acc[8][2];
#pragma unroll
  for (int i = 0; i < 8; ++i)
#pragma unroll
    for (int j = 0; j < 2; ++j)
#pragma unroll
      for (int r = 0; r < 4; ++r) acc[i][j][r] = 0.f;

  const int sd = tid * 16;
  const int sr = sd >> 6;
  const int sc = ((sd >> 4) & 3) ^ ((sr >> 1) & 3);
  const int sdst = w * 512;

  const int spn = lhi ^ ((l16 >> 1) & 3);
  const int aBase = wr * 4096 + l16 * 32 + spn * 8;
  const int bBase = 8192 + (wc * 32 + l16) * 32 + spn * 8;

  auto stage_ht = [&](int kt, int ht) {
    const u16* src = (ht < 2) ? A : Bt;
    int rowbase = (ht < 2) ? (bm + ht * 128) : bn;
    int dsto = (ht < 2) ? ht * 4096 : 8192;
    gld_lds16(src + (size_t)(rowbase + sr) * ldk + kt * 32 + sc * 8,
              &lds[(kt & 3) * 12288 + dsto + sdst]);
  };

#pragma unroll
  for (int t = 0; t < 3; ++t) {
    stage_ht(t, 0); stage_ht(t, 1); stage_ht(t, 2);
  }
  asm volatile("s_waitcnt vmcnt(6)" ::: "memory");
  __builtin_amdgcn_s_barrier();

  short8 a[4], b[2];
  for (int kt = 0; kt < NT; ++kt) {
    const int pb = (kt & 3) * 12288;
    __builtin_amdgcn_sched_barrier(0);
    // ---- phase 1: wave rows 0-63 ----
#pragma unroll
    for (int mi = 0; mi < 4; ++mi)
      a[mi] = *reinterpret_cast<const short8*>(&lds[pb + aBase + mi * 512]);
#pragma unroll
    for (int ni = 0; ni < 2; ++ni)
      b[ni] = *reinterpret_cast<const short8*>(&lds[pb + bBase + ni * 512]);
    if (kt + 3 < NT) { stage_ht(kt + 3, 0); stage_ht(kt + 3, 1); }
    __builtin_amdgcn_s_barrier();
    asm volatile("s_waitcnt lgkmcnt(0)" ::: "memory");
    __builtin_amdgcn_sched_barrier(0);
    __builtin_amdgcn_s_setprio(1);
#pragma unroll
    for (int mi = 0; mi < 4; ++mi)
#pragma unroll
      for (int ni = 0; ni < 2; ++ni)
        acc[mi][ni] = __builtin_amdgcn_mfma_f32_16x16x32_bf16(a[mi], b[ni], acc[mi][ni], 0, 0, 0);
    __builtin_amdgcn_s_setprio(0);
    __builtin_amdgcn_s_barrier();
    __builtin_amdgcn_sched_barrier(0);
    // ---- phase 2: wave rows 64-127 ----
#pragma unroll
    for (int mi = 0; mi < 4; ++mi)
      a[mi] = *reinterpret_cast<const short8*>(&lds[pb + aBase + 2048 + mi * 512]);
    if (kt + 3 < NT) stage_ht(kt + 3, 2);
    __builtin_amdgcn_s_barrier();
    asm volatile("s_waitcnt lgkmcnt(0)" ::: "memory");
    __builtin_amdgcn_sched_barrier(0);
    __builtin_amdgcn_s_setprio(1);
#pragma unroll
    for (int mi = 0; mi < 4; ++mi)
#pragma unroll
      for (int ni = 0; ni < 2; ++ni)
        acc[4 + mi][ni] = __builtin_amdgcn_mfma_f32_16x16x32_bf16(a[mi], b[ni], acc[4 + mi][ni], 0, 0, 0);
    __builtin_amdgcn_s_setprio(0);
    if (kt + 4 <= NT)      asm volatile("s_waitcnt vmcnt(6)" ::: "memory");
    else if (kt + 3 == NT) asm volatile("s_waitcnt vmcnt(3)" ::: "memory");
    else if (kt + 2 == NT) asm volatile("s_waitcnt vmcnt(0)" ::: "memory");
    __builtin_amdgcn_s_barrier();
  }

#pragma unroll
  for (int q = 0; q < 8; ++q)
#pragma unroll
    for (int ni = 0; ni < 2; ++ni)
#pragma unroll
      for (int r = 0; r < 4; ++r) {
        int row = bm + wr * 128 + (q >> 2) * 64 + (q & 3) * 16 + lhi * 4 + r;
        int col = bn + wc * 32 + ni * 16 + l16;
        Cv[(size_t)row * N + col] = f2b(acc[q][ni][r]);
      }
}

// ---------------- GEMM kernel wrappers ----------------

// cm_Wk: sqrelu bf16; grid 256
__global__ __launch_bounds__(512)
void k_g256_cmk(const u16* __restrict__ A, const u16* __restrict__ Bt,
                u16* __restrict__ C) {
  int bid = blockIdx.x;
  int wg = (bid & 7) * 32 + (bid >> 3);
  int lb = wg & 3, sv = wg >> 2;
  int by = (sv >> 3) * 2 + (lb & 1);
  int bx = (sv & 7) * 2 + (lb >> 1);
  g256_body<2>(A, Bt, C, HDIM, EDIM, EDIM, by * 256, bx * 256);
}

// cm_Wv: split-K x4 over H, bf16 partials; grid 256
__global__ __launch_bounds__(512)
void k_g256_wv(const u16* __restrict__ A, const u16* __restrict__ Bt,
               u16* __restrict__ P) {
  int bid = blockIdx.x;
  int wg = (bid & 7) * 32 + (bid >> 3);
  int z = wg >> 6, rem = wg & 63;
  int lb = rem & 3, sv = rem >> 2;
  int by = (sv >> 1) * 2 + (lb & 1);
  int bx = (sv & 1) * 2 + (lb >> 1);
  g256_body<1>(A + z * 1024, Bt + z * 1024, P + (size_t)z * L_SEQ * EDIM,
               EDIM, HDIM, 1024, by * 256, bx * 256);
}

// batched k/v/r GEMMs, bf16 out; grid 192
__global__ __launch_bounds__(512)
void k_g256_3(const u16* __restrict__ A0, const u16* __restrict__ A1, const u16* __restrict__ A2,
              const u16* __restrict__ B0, const u16* __restrict__ B1, const u16* __restrict__ B2,
              u16* __restrict__ C0, u16* __restrict__ C1, u16* __restrict__ C2) {
  int bid = blockIdx.x;
  int wg = (bid & 7) * 24 + (bid >> 3);
  int z = wg >> 6, rem = wg & 63;
  int lb = rem & 3, sv = rem >> 2;
  int by = (sv >> 1) * 2 + (lb & 1);
  int bx = (sv & 1) * 2 + (lb >> 1);
  const u16* A = (z == 0) ? A0 : (z == 1) ? A1 : A2;
  const u16* B = (z == 0) ? B0 : (z == 1) ? B1 : B2;
  u16*       C = (z == 0) ? C0 : (z == 1) ? C1 : C2;
  g256_body<1>(A, B, C, EDIM, EDIM, EDIM, by * 256, bx * 256);
}

// E^2 GEMM split-K x2 (Wo / cm_Wr / neck), bf16 partials; grid 256
__global__ __launch_bounds__(512)
void k_gx128_sk2(const u16* __restrict__ A, const u16* __restrict__ Bt,
                 u16* __restrict__ P) {
  int bid = blockIdx.x;
  int wg = (bid & 7) * 32 + (bid >> 3);
  int z = wg >> 7, rem = wg & 127;
  int by = rem >> 3, bx = rem & 7;
  g128_body(A + z * 512, Bt + z * 512, P + (size_t)z * L_SEQ * EDIM,
            EDIM, EDIM, 512, by * 256, bx * 128);
}

// ---------------- chunk-parallel WKV (bf16 k/v/r) ----------------

__global__ void k_wkv_pass1(const u16* __restrict__ k, const u16* __restrict__ v,
                            const float* __restrict__ w_,
                            float* __restrict__ sa, float* __restrict__ sb,
                            float* __restrict__ sp) {
  int id = blockIdx.x * blockDim.x + threadIdx.x;
  int e = id & 1023, c = id >> 10;
  float D = __expf(w_[e]);
  float aa = 0.f, bb = 0.f, pp = -__builtin_inff();
  const u16* kp = k + (size_t)c * WKV_T * EDIM + e;
  const u16* vp = v + (size_t)c * WKV_T * EDIM + e;
#pragma unroll 4
  for (int i = 0; i < WKV_T; ++i) {
    float kk = b2f(kp[i * EDIM]), vv = b2f(vp[i * EDIM]);
    float ww = pp - D;
    float p2 = fmaxf(ww, kk);
    float e1 = __expf(ww - p2), e2 = __expf(kk - p2);
    aa = e1 * aa + e2 * vv;
    bb = e1 * bb + e2;
    pp = p2;
  }
  sa[id] = aa; sb[id] = bb; sp[id] = pp;
}

// parallel exclusive scan: 16 lanes/channel, 8 chunks/lane, shuffle combine
__global__ __launch_bounds__(256)
void k_wkv_scan16(const float* __restrict__ w_,
                  const float* __restrict__ sa, const float* __restrict__ sb,
                  const float* __restrict__ sp,
                  float* __restrict__ oa, float* __restrict__ ob,
                  float* __restrict__ op) {
  int t = blockIdx.x * blockDim.x + threadIdx.x;
  int e = t >> 4, j = t & (SCAN_LANES - 1);
  const float NEG = -1e30f;
  float DT = __expf(w_[e]) * (float)WKV_T;
  float Ea[SCAN_CPT], Eb[SCAN_CPT], Ep[SCAN_CPT];
  float A = 0.f, B = 0.f, P = NEG;
  int base = j * SCAN_CPT;
#pragma unroll
  for (int i = 0; i < SCAN_CPT; ++i) {
    int idx = (base + i) * EDIM + e;
    Ea[i] = A; Eb[i] = B; Ep[i] = P;
    float a = sa[idx], b = sb[idx], q = sp[idx];
    float shift = P - DT;
    float pn = fmaxf(shift, q);
    float w1 = __expf(shift - pn), w2 = __expf(q - pn);
    A = w1 * A + w2 * a; B = w1 * B + w2 * b; P = pn;
  }
  float tA = A, tB = B, tP = P; int tn = SCAN_CPT;
#pragma unroll
  for (int d = 1; d < SCAN_LANES; d <<= 1) {
    float fA = __shfl_up(tA, d, SCAN_LANES);
    float fB = __shfl_up(tB, d, SCAN_LANES);
    float fP = __shfl_up(tP, d, SCAN_LANES);
    int   fn = __shfl_up(tn, d, SCAN_LANES);
    if (j >= d) {
      float shift = fP - DT * (float)tn;
      float pn = fmaxf(shift, tP);
      float w1 = __expf(shift - pn), w2 = __expf(tP - pn);
      tA = w1 * fA + w2 * tA; tB = w1 * fB + w2 * tB; tP = pn; tn += fn;
    }
  }
  float pA = __shfl_up(tA, 1, SCAN_LANES);
  float pB = __shfl_up(tB, 1, SCAN_LANES);
  float pP = __shfl_up(tP, 1, SCAN_LANES);
  if (j == 0) { pA = 0.f; pB = 0.f; pP = NEG; }
#pragma unroll
  for (int i = 0; i < SCAN_CPT; ++i) {
    float shift = pP - DT * (float)i;
    float pn = fmaxf(shift, Ep[i]);
    float w1 = __expf(shift - pn), w2 = __expf(Ep[i] - pn);
    int idx = (base + i) * EDIM + e;
    oa[idx] = w1 * pA + w2 * Ea[i];
    ob[idx] = w1 * pB + w2 * Eb[i];
    op[idx] = pn;
  }
}

// pass2 with fused sigmoid gate: rwb = bf16(sig(rpre) * wkv)
__global__ void k_wkv_pass2(const u16* __restrict__ k, const u16* __restrict__ v,
                            const float* __restrict__ u_, const float* __restrict__ w_,
                            const float* __restrict__ sa, const float* __restrict__ sb,
                            const float* __restrict__ sp,
                            const u16* __restrict__ rpre, u16* __restrict__ rwb) {
  int id = blockIdx.x * blockDim.x + threadIdx.x;
  int e = id & 1023, c = id >> 10;
  float u = u_[e];
  float D = __expf(w_[e]);
  float aa = sa[id], bb = sb[id], pp = sp[id];
  const size_t base = (size_t)c * WKV_T * EDIM + e;
  const u16* kp = k + base;
  const u16* vp = v + base;
  const u16* rp = rpre + base;
  u16* op = rwb + base;
#pragma unroll 4
  for (int i = 0; i < WKV_T; ++i) {
    float kk = b2f(kp[i * EDIM]), vv = b2f(vp[i * EDIM]);
    float ww = u + kk;
    float p = fmaxf(pp, ww);
    float e1 = __expf(pp - p), e2 = __expf(ww - p);
    float out = (e1 * aa + e2 * vv) / (e1 * bb + e2);
    op[i * EDIM] = f2b(out * sigm(b2f(rp[i * EDIM])));
    float w2s = pp - D;
    float p2 = fmaxf(w2s, kk);
    float e1b = __expf(w2s - p2), e2b = __expf(kk - p2);
    aa = e1b * aa + e2b * vv;
    bb = e1b * bb + e2b;
    pp = p2;
  }
}

// ---------------- head (fused gelu, 2 neck partials) ----------------
__global__ __launch_bounds__(256)
void k_head(const u16* __restrict__ P, const float* __restrict__ nb,
            const float* __restrict__ W,
            const int* __restrict__ s, float* __restrict__ partial) {
  const size_t LE = (size_t)L_SEQ * EDIM;
  int t = blockIdx.x, tid = threadIdx.x;
  float a0 = 0.f, a1 = 0.f, a2 = 0.f, a3 = 0.f;
  for (int e = tid; e < EDIM; e += 256) {
    size_t i = (size_t)t * EDIM + e;
    float hv = gelu1(b2f(P[i]) + b2f(P[i + LE]) + nb[e]);
    const float4 wv = *reinterpret_cast<const float4*>(W + e * 4);
    a0 += hv * wv.x; a1 += hv * wv.y; a2 += hv * wv.z; a3 += hv * wv.w;
  }
#pragma unroll
  for (int off = 32; off > 0; off >>= 1) {
    a0 += __shfl_down(a0, off, 64);
    a1 += __shfl_down(a1, off, 64);
    a2 += __shfl_down(a2, off, 64);
    a3 += __shfl_down(a3, off, 64);
  }
  __shared__ float sm[4][4];
  int w = tid >> 6, lane = tid & 63;
  if (lane == 0) { sm[w][0] = a0; sm[w][1] = a1; sm[w][2] = a2; sm[w][3] = a3; }
  __syncthreads();
  if (tid == 0) {
    float lg[4];
#pragma unroll
    for (int j = 0; j < 4; ++j) lg[j] = sm[0][j] + sm[1][j] + sm[2][j] + sm[3][j];
    float m = fmaxf(fmaxf(lg[0], lg[1]), fmaxf(lg[2], lg[3]));
    float sum = expf(lg[0] - m) + expf(lg[1] - m) + expf(lg[2] - m) + expf(lg[3] - m);
    partial[t] = 0.5f * (lg[s[t]] - m - logf(sum));
  }
}

__global__ __launch_bounds__(256)
void k_reduce(const float* __restrict__ partial, float* __restrict__ out) {
  int tid = threadIdx.x;
  float a = 0.f;
  for (int j = tid; j < L_SEQ; j += 256) a += partial[j];
#pragma unroll
  for (int off = 32; off > 0; off >>= 1) a += __shfl_down(a, off, 64);
  __shared__ float sm[4];
  if ((tid & 63) == 0) sm[tid >> 6] = a;
  __syncthreads();
  if (tid == 0) out[0] = sm[0] + sm[1] + sm[2] + sm[3];
}

// ---------------- host ----------------

extern "C" void kernel_launch(void* const* d_in, const int* in_sizes, int n_in,
                              void* d_out, int out_size, void* d_ws, size_t ws_size,
                              hipStream_t stream) {
  const int*   s        = (const int*)d_in[0];
  const float* embed    = (const float*)d_in[1];
  const float* tm_first = (const float*)d_in[2];
  const float* tm_decay = (const float*)d_in[3];
  const float* tm_mk    = (const float*)d_in[4];
  const float* tm_mv    = (const float*)d_in[5];
  const float* tm_mr    = (const float*)d_in[6];
  const float* tm_Wk    = (const float*)d_in[7];
  const float* tm_Wv    = (const float*)d_in[8];
  const float* tm_Wr    = (const float*)d_in[9];
  const float* tm_Wo    = (const float*)d_in[10];
  const float* cm_mk    = (const float*)d_in[11];
  const float* cm_mr    = (const float*)d_in[12];
  const float* cm_Wk    = (const float*)d_in[13];
  const float* cm_Wr    = (const float*)d_in[14];
  const float* cm_Wv    = (const float*)d_in[15];
  const float* neck_W   = (const float*)d_in[16];
  const float* neck_b   = (const float*)d_in[17];
  const float* head_W   = (const float*)d_in[18];

  char* ws = (char*)d_ws;
  size_t off = 0;
  auto alloc = [&](size_t bytes) { char* p = ws + off; off += (bytes + 255) & ~(size_t)255; return p; };
  const size_t LE2 = (size_t)L_SEQ * EDIM * 2;
  const size_t EE  = (size_t)EDIM * EDIM, EH = (size_t)EDIM * HDIM;

  u16*   xA    = (u16*)alloc(LE2);
  u16*   xB    = (u16*)alloc(LE2);
  u16*   kxb   = (u16*)alloc(LE2);
  u16*   vxb   = (u16*)alloc(LE2);   // also rwb
  u16*   rxb   = (u16*)alloc(LE2);
  u16*   kf    = (u16*)alloc(LE2);
  u16*   vf    = (u16*)alloc(LE2);
  u16*   rpre  = (u16*)alloc(LE2);
  u16*   kkb   = (u16*)alloc((size_t)L_SEQ * HDIM * 2);
  u16*   PA    = (u16*)alloc(2 * LE2);   // Wo / neck partials (bf16 x2)
  u16*   PR    = (u16*)alloc(2 * LE2);   // cm_Wr partials (bf16 x2)
  u16*   PB    = (u16*)alloc(4 * LE2);   // cm_Wv partials (bf16 x4)
  float* partial = (float*)alloc((size_t)L_SEQ * 4);
  float* sa  = (float*)alloc((size_t)WKV_C * EDIM * 4);
  float* sb  = (float*)alloc((size_t)WKV_C * EDIM * 4);
  float* sp  = (float*)alloc((size_t)WKV_C * EDIM * 4);
  float* sa2 = (float*)alloc((size_t)WKV_C * EDIM * 4);
  float* sb2 = (float*)alloc((size_t)WKV_C * EDIM * 4);
  float* sp2 = (float*)alloc((size_t)WKV_C * EDIM * 4);

  size_t remain = (ws_size > off) ? ws_size - off : 0;
  const size_t bigNeed = (5 * EE * NLAY + 2 * EH * NLAY + EE) * 2 + 16 * 256;
  const bool big = remain >= bigNeed;
  const int NB = big ? NLAY : 1;
  u16* wWk   = (u16*)alloc(EE * NB * 2);
  u16* wWv   = (u16*)alloc(EE * NB * 2);
  u16* wWr   = (u16*)alloc(EE * NB * 2);
  u16* wWo   = (u16*)alloc(EE * NB * 2);
  u16* wcmWr = (u16*)alloc(EE * NB * 2);
  u16* wcmWk = (u16*)alloc(EH * NB * 2);
  u16* wcmWv = (u16*)alloc(EH * NB * 2);
  u16* wneck = big ? (u16*)alloc(EE * 2) : wWk;

  const dim3 blk(256);
  const dim3 blk512(512);
  const dim3 gE4((L_SEQ * EDIM) / 1024);
  const dim3 gWkv((WKV_C * EDIM) / 256);
  const dim3 gScan((EDIM * SCAN_LANES) / 256);
  const size_t DLDS  = 131072;  // 128KB for 256^2
  const size_t DLDS2 = 98304;   // 96KB for 256x128

  if (big) {
    k_tconv_all<<<dim3(TC_EE + 2 * TC_EH), blk, 0, stream>>>(
        tm_Wk, tm_Wv, tm_Wr, tm_Wo, cm_Wr, neck_W, cm_Wk, cm_Wv,
        wWk, wWv, wWr, wWo, wcmWr, wneck, wcmWk, wcmWv);
  }

  for (int l = 0; l < NLAY; ++l) {
    size_t oE  = (size_t)l * EDIM;
    size_t oEE = (size_t)l * EE;
    size_t oEH = (size_t)l * EH;
    size_t wE  = big ? oEE : 0;
    size_t wH  = big ? oEH : 0;
    if (!big) {
      k_tconv<<<dim3(EDIM / 64, EDIM / 64, 1), blk, 0, stream>>>(tm_Wk + oEE, wWk, EDIM, EDIM);
      k_tconv<<<dim3(EDIM / 64, EDIM / 64, 1), blk, 0, stream>>>(tm_Wv + oEE, wWv, EDIM, EDIM);
      k_tconv<<<dim3(EDIM / 64, EDIM / 64, 1), blk, 0, stream>>>(tm_Wr + oEE, wWr, EDIM, EDIM);
      k_tconv<<<dim3(EDIM / 64, EDIM / 64, 1), blk, 0, stream>>>(tm_Wo + oEE, wWo, EDIM, EDIM);
      k_tconv<<<dim3(EDIM / 64, EDIM / 64, 1), blk, 0, stream>>>(cm_Wr + oEE, wcmWr, EDIM, EDIM);
      k_tconv<<<dim3(HDIM / 64, EDIM / 64, 1), blk, 0, stream>>>(cm_Wk + oEH, wcmWk, EDIM, HDIM);
      k_tconv<<<dim3(EDIM / 64, HDIM / 64, 1), blk, 0, stream>>>(cm_Wv + oEH, wcmWv, HDIM, EDIM);
    }
    // --- TimeMixing ---
    if (l == 0)
      k_f0<<<gE4, blk, 0, stream>>>(s, embed, tm_mk + oE, tm_mv + oE, tm_mr + oE,
                                    xA, kxb, vxb, rxb);
    else
      k_f1<<<gE4, blk, 0, stream>>>(xB, PR, PB, tm_mk + oE, tm_mv + oE, tm_mr + oE,
                                    xA, kxb, vxb, rxb);
    k_g256_3<<<dim3(192), blk512, DLDS, stream>>>(kxb, vxb, rxb,
                                                  wWk + wE, wWv + wE, wWr + wE,
                                                  kf, vf, rpre);
    k_wkv_pass1<<<gWkv, blk, 0, stream>>>(kf, vf, tm_decay + oE, sa, sb, sp);
    k_wkv_scan16<<<gScan, blk, 0, stream>>>(tm_decay + oE, sa, sb, sp, sa2, sb2, sp2);
    k_wkv_pass2<<<gWkv, blk, 0, stream>>>(kf, vf, tm_first + oE, tm_decay + oE,
                                          sa2, sb2, sp2, rpre, vxb);
    k_gx128_sk2<<<dim3(256), blk512, DLDS2, stream>>>(vxb, wWo + wE, PA);
    // --- ChannelMixing ---
    k_f2<<<gE4, blk, 0, stream>>>(xA, PA, cm_mk + oE, cm_mr + oE, xB, kxb, rxb);
    k_gx128_sk2<<<dim3(256), blk512, DLDS2, stream>>>(rxb, wcmWr + wE, PR);
    k_g256_cmk<<<dim3(256), blk512, DLDS, stream>>>(kxb, wcmWk + wH, kkb);
    k_g256_wv<<<dim3(256), blk512, DLDS, stream>>>(kkb, wcmWv + wH, PB);
  }
  // --- Neck + Head ---
  if (!big) k_tconv<<<dim3(EDIM / 64, EDIM / 64, 1), blk, 0, stream>>>(neck_W, wneck, EDIM, EDIM);
  k_f3<<<gE4, blk, 0, stream>>>(xB, PR, PB, kxb);
  k_gx128_sk2<<<dim3(256), blk512, DLDS2, stream>>>(kxb, wneck, PA);
  k_head<<<dim3(L_SEQ), blk, 0, stream>>>(PA, neck_b, head_W, s, partial);
  k_reduce<<<dim3(1), blk, 0, stream>>>(partial, (float*)d_out);

  (void)in_sizes; (void)n_in; (void)out_size;
}

// Round 15
// 1743.007 us; speedup vs baseline: 1.0417x; 1.0183x over previous
//
#include <hip/hip_runtime.h>
#include <stdint.h>

#define L_SEQ 4096
#define EDIM  1024
#define HDIM  4096
#define NLAY  8
#define WKV_C 128  // chunks
#define WKV_T 32   // tokens per chunk
#define SCAN_LANES 16
#define SCAN_CPT   (WKV_C / SCAN_LANES)  // 8

typedef unsigned short u16;
typedef __attribute__((ext_vector_type(8))) short short8;
typedef __attribute__((ext_vector_type(4))) float f32x4;
typedef __attribute__((ext_vector_type(4))) float f4v;
typedef __attribute__((ext_vector_type(4))) unsigned short us4;
typedef __attribute__((ext_vector_type(8))) unsigned short us8;

static __device__ __forceinline__ u16 f2b(float f) {
  union { float f; uint32_t u; } a; a.f = f;
  uint32_t u = a.u;
  return (u16)((u + 0x7FFFu + ((u >> 16) & 1u)) >> 16);  // RNE
}
static __device__ __forceinline__ float b2f(u16 b) {
  union { uint32_t u; float f; } a; a.u = ((uint32_t)b) << 16;
  return a.f;
}
static __device__ __forceinline__ float sigm(float v) {
  return 1.f / (1.f + __expf(-v));
}
static __device__ __forceinline__ float4 ld_bf4(const u16* __restrict__ p, size_t i) {
  us4 v = *reinterpret_cast<const us4*>(&p[i]);
  return make_float4(b2f(v.x), b2f(v.y), b2f(v.z), b2f(v.w));
}

static __device__ __forceinline__ void gld_lds16(const void* g, void* l) {
  __builtin_amdgcn_global_load_lds(
      (const __attribute__((address_space(1))) void*)g,
      (__attribute__((address_space(3))) void*)l, 16, 0, 0);
}

// ---------------- fused elementwise (x residual in bf16) ----------------

// F0: x = embed[tok], tm-mix3 (layer 0)
__global__ void k_f0(const int* __restrict__ s, const float* __restrict__ embed,
                     const float* __restrict__ mk, const float* __restrict__ mv,
                     const float* __restrict__ mr, u16* __restrict__ xA,
                     u16* __restrict__ kx, u16* __restrict__ vx, u16* __restrict__ rx) {
  int i = (blockIdx.x * blockDim.x + threadIdx.x) * 4;
  int t = i >> 10, e = i & 1023;
  int tok = (t == 0) ? 0 : s[t - 1];
  float4 xc = *reinterpret_cast<const float4*>(&embed[tok * EDIM + e]);
  float4 xs = make_float4(0.f, 0.f, 0.f, 0.f);
  if (t > 0) {
    int tokp = (t == 1) ? 0 : s[t - 2];
    xs = *reinterpret_cast<const float4*>(&embed[tokp * EDIM + e]);
  }
  us4 ox; ox.x = f2b(xc.x); ox.y = f2b(xc.y); ox.z = f2b(xc.z); ox.w = f2b(xc.w);
  *reinterpret_cast<us4*>(&xA[i]) = ox;
  float4 m; us4 o;
  m = *reinterpret_cast<const float4*>(&mk[e]);
  o.x = f2b(xc.x * m.x + xs.x * (1.f - m.x)); o.y = f2b(xc.y * m.y + xs.y * (1.f - m.y));
  o.z = f2b(xc.z * m.z + xs.z * (1.f - m.z)); o.w = f2b(xc.w * m.w + xs.w * (1.f - m.w));
  *reinterpret_cast<us4*>(&kx[i]) = o;
  m = *reinterpret_cast<const float4*>(&mv[e]);
  o.x = f2b(xc.x * m.x + xs.x * (1.f - m.x)); o.y = f2b(xc.y * m.y + xs.y * (1.f - m.y));
  o.z = f2b(xc.z * m.z + xs.z * (1.f - m.z)); o.w = f2b(xc.w * m.w + xs.w * (1.f - m.w));
  *reinterpret_cast<us4*>(&vx[i]) = o;
  m = *reinterpret_cast<const float4*>(&mr[e]);
  o.x = f2b(xc.x * m.x + xs.x * (1.f - m.x)); o.y = f2b(xc.y * m.y + xs.y * (1.f - m.y));
  o.z = f2b(xc.z * m.z + xs.z * (1.f - m.z)); o.w = f2b(xc.w * m.w + xs.w * (1.f - m.w));
  *reinterpret_cast<us4*>(&rx[i]) = o;
}

// cm-finish: x = xB + sig(PR0+PR1) * (PB0+PB1+PB2+PB3)  (all bf16)
static __device__ __forceinline__ float4 cm_finish(const u16* __restrict__ xB,
                                                   const u16* __restrict__ PR,
                                                   const u16* __restrict__ PB, int i) {
  const size_t LE = (size_t)L_SEQ * EDIM;
  float4 xm = ld_bf4(xB, i);
  float4 r0 = ld_bf4(PR, i), r1 = ld_bf4(PR, i + LE);
  float4 v0 = ld_bf4(PB, i), v1 = ld_bf4(PB, i + LE);
  float4 v2 = ld_bf4(PB, i + 2 * LE), v3 = ld_bf4(PB, i + 3 * LE);
  xm.x += sigm(r0.x + r1.x) * (v0.x + v1.x + v2.x + v3.x);
  xm.y += sigm(r0.y + r1.y) * (v0.y + v1.y + v2.y + v3.y);
  xm.z += sigm(r0.z + r1.z) * (v0.z + v1.z + v2.z + v3.z);
  xm.w += sigm(r0.w + r1.w) * (v0.w + v1.w + v2.w + v3.w);
  return xm;
}

// F1: x = cm_finish; tm-mix3 (layers 1..7)
__global__ void k_f1(const u16* __restrict__ xB, const u16* __restrict__ PR,
                     const u16* __restrict__ PB,
                     const float* __restrict__ mk, const float* __restrict__ mv,
                     const float* __restrict__ mr, u16* __restrict__ xA,
                     u16* __restrict__ kx, u16* __restrict__ vx, u16* __restrict__ rx) {
  int i = (blockIdx.x * blockDim.x + threadIdx.x) * 4;
  int e = i & 1023;
  float4 xc = cm_finish(xB, PR, PB, i);
  float4 xs = make_float4(0.f, 0.f, 0.f, 0.f);
  if (i >= EDIM) xs = cm_finish(xB, PR, PB, i - EDIM);
  us4 ox; ox.x = f2b(xc.x); ox.y = f2b(xc.y); ox.z = f2b(xc.z); ox.w = f2b(xc.w);
  *reinterpret_cast<us4*>(&xA[i]) = ox;
  float4 m; us4 o;
  m = *reinterpret_cast<const float4*>(&mk[e]);
  o.x = f2b(xc.x * m.x + xs.x * (1.f - m.x)); o.y = f2b(xc.y * m.y + xs.y * (1.f - m.y));
  o.z = f2b(xc.z * m.z + xs.z * (1.f - m.z)); o.w = f2b(xc.w * m.w + xs.w * (1.f - m.w));
  *reinterpret_cast<us4*>(&kx[i]) = o;
  m = *reinterpret_cast<const float4*>(&mv[e]);
  o.x = f2b(xc.x * m.x + xs.x * (1.f - m.x)); o.y = f2b(xc.y * m.y + xs.y * (1.f - m.y));
  o.z = f2b(xc.z * m.z + xs.z * (1.f - m.z)); o.w = f2b(xc.w * m.w + xs.w * (1.f - m.w));
  *reinterpret_cast<us4*>(&vx[i]) = o;
  m = *reinterpret_cast<const float4*>(&mr[e]);
  o.x = f2b(xc.x * m.x + xs.x * (1.f - m.x)); o.y = f2b(xc.y * m.y + xs.y * (1.f - m.y));
  o.z = f2b(xc.z * m.z + xs.z * (1.f - m.z)); o.w = f2b(xc.w * m.w + xs.w * (1.f - m.w));
  *reinterpret_cast<us4*>(&rx[i]) = o;
}

static __device__ __forceinline__ float4 tm_finish(const u16* __restrict__ xA,
                                                   const u16* __restrict__ PA, int i) {
  const size_t LE = (size_t)L_SEQ * EDIM;
  float4 xm = ld_bf4(xA, i);
  float4 a = ld_bf4(PA, i), b = ld_bf4(PA, i + LE);
  xm.x += a.x + b.x; xm.y += a.y + b.y; xm.z += a.z + b.z; xm.w += a.w + b.w;
  return xm;
}

// F2: x = xA + PA0 + PA1; cm-mix2
__global__ void k_f2(const u16* __restrict__ xA, const u16* __restrict__ PA,
                     const float* __restrict__ mk, const float* __restrict__ mr,
                     u16* __restrict__ xB, u16* __restrict__ kx, u16* __restrict__ rx) {
  int i = (blockIdx.x * blockDim.x + threadIdx.x) * 4;
  int e = i & 1023;
  float4 xc = tm_finish(xA, PA, i);
  float4 xs = make_float4(0.f, 0.f, 0.f, 0.f);
  if (i >= EDIM) xs = tm_finish(xA, PA, i - EDIM);
  us4 ox; ox.x = f2b(xc.x); ox.y = f2b(xc.y); ox.z = f2b(xc.z); ox.w = f2b(xc.w);
  *reinterpret_cast<us4*>(&xB[i]) = ox;
  float4 m; us4 o;
  m = *reinterpret_cast<const float4*>(&mk[e]);
  o.x = f2b(xc.x * m.x + xs.x * (1.f - m.x)); o.y = f2b(xc.y * m.y + xs.y * (1.f - m.y));
  o.z = f2b(xc.z * m.z + xs.z * (1.f - m.z)); o.w = f2b(xc.w * m.w + xs.w * (1.f - m.w));
  *reinterpret_cast<us4*>(&kx[i]) = o;
  m = *reinterpret_cast<const float4*>(&mr[e]);
  o.x = f2b(xc.x * m.x + xs.x * (1.f - m.x)); o.y = f2b(xc.y * m.y + xs.y * (1.f - m.y));
  o.z = f2b(xc.z * m.z + xs.z * (1.f - m.z)); o.w = f2b(xc.w * m.w + xs.w * (1.f - m.w));
  *reinterpret_cast<us4*>(&rx[i]) = o;
}

// F3: hb = bf16(cm_finish)
__global__ void k_f3(const u16* __restrict__ xB, const u16* __restrict__ PR,
                     const u16* __restrict__ PB, u16* __restrict__ hb) {
  int i = (blockIdx.x * blockDim.x + threadIdx.x) * 4;
  float4 xc = cm_finish(xB, PR, PB, i);
  us4 o;
  o.x = f2b(xc.x); o.y = f2b(xc.y); o.z = f2b(xc.z); o.w = f2b(xc.w);
  *reinterpret_cast<us4*>(&hb[i]) = o;
}

static __device__ __forceinline__ float gelu1(float v) {
  float c = 0.7978845608028654f * (v + 0.044715f * v * v * v);
  return 0.5f * v * (1.f + tanhf(c));
}

// ---------------- transpose + f32->bf16 (NT loads) ----------------
static __device__ __forceinline__
void tconv2(const float* __restrict__ s, u16* __restrict__ d, int K, int N,
            int n0, int k0) {
  __shared__ float tile[64][65];
  int tid = threadIdx.x;
  int tx = tid & 15, ty = tid >> 4;
#pragma unroll
  for (int i = 0; i < 4; ++i) {
    int kr = ty + i * 16;
    f4v v = __builtin_nontemporal_load(
        reinterpret_cast<const f4v*>(&s[(size_t)(k0 + kr) * N + n0 + tx * 4]));
    tile[kr][tx * 4 + 0] = v.x; tile[kr][tx * 4 + 1] = v.y;
    tile[kr][tx * 4 + 2] = v.z; tile[kr][tx * 4 + 3] = v.w;
  }
  __syncthreads();
  int tx8 = tid & 7, ny = tid >> 3;
#pragma unroll
  for (int h = 0; h < 2; ++h) {
    int n = ny + h * 32;
    us8 o;
#pragma unroll
    for (int c = 0; c < 8; ++c) o[c] = f2b(tile[tx8 * 8 + c][n]);
    *reinterpret_cast<us8*>(&d[(size_t)(n0 + n) * K + k0 + tx8 * 8]) = o;
  }
}

__global__ __launch_bounds__(256)
void k_tconv(const float* __restrict__ src, u16* __restrict__ dst, int K, int N) {
  tconv2(src + (size_t)blockIdx.z * K * N, dst + (size_t)blockIdx.z * K * N,
         K, N, blockIdx.x * 64, blockIdx.y * 64);
}

// ALL weights in one flat launch: 41 ExE + 8 ExH (cm_Wk) + 8 HxE (cm_Wv)
#define TC_EE  (41 * 256)
#define TC_EH  8192
__global__ __launch_bounds__(256)
void k_tconv_all(const float* __restrict__ Wk, const float* __restrict__ Wv,
                 const float* __restrict__ Wr, const float* __restrict__ Wo,
                 const float* __restrict__ cWr, const float* __restrict__ nW,
                 const float* __restrict__ cWk, const float* __restrict__ cWv,
                 u16* __restrict__ oWk, u16* __restrict__ oWv, u16* __restrict__ oWr,
                 u16* __restrict__ oWo, u16* __restrict__ ocWr, u16* __restrict__ onW,
                 u16* __restrict__ ocWk, u16* __restrict__ ocWv) {
  const size_t EE = (size_t)EDIM * EDIM, EH = (size_t)EDIM * HDIM;
  int bid = blockIdx.x;
  if (bid < TC_EE) {
    int z = bid >> 8, rem = bid & 255;
    const float* src; u16* dst;
    if (z < 8)       { src = Wk  + (size_t)z * EE;        dst = oWk  + (size_t)z * EE; }
    else if (z < 16) { src = Wv  + (size_t)(z - 8) * EE;  dst = oWv  + (size_t)(z - 8) * EE; }
    else if (z < 24) { src = Wr  + (size_t)(z - 16) * EE; dst = oWr  + (size_t)(z - 16) * EE; }
    else if (z < 32) { src = Wo  + (size_t)(z - 24) * EE; dst = oWo  + (size_t)(z - 24) * EE; }
    else if (z < 40) { src = cWr + (size_t)(z - 32) * EE; dst = ocWr + (size_t)(z - 32) * EE; }
    else             { src = nW;                          dst = onW; }
    tconv2(src, dst, EDIM, EDIM, (rem & 15) * 64, (rem >> 4) * 64);
  } else if (bid < TC_EE + TC_EH) {
    int b = bid - TC_EE;
    int z = b >> 10, rem = b & 1023;
    tconv2(cWk + (size_t)z * EH, ocWk + (size_t)z * EH, EDIM, HDIM,
           (rem & 63) * 64, (rem >> 6) * 64);
  } else {
    int b = bid - TC_EE - TC_EH;
    int z = b >> 10, rem = b & 1023;
    tconv2(cWv + (size_t)z * EH, ocWv + (size_t)z * EH, HDIM, EDIM,
           (rem & 15) * 64, (rem >> 4) * 64);
  }
}

// ========== 256x256 8-wave pipelined GEMM (ONE barrier per K-tile) ==========
// EPI: 0 = f32 store, 1 = bf16 store, 2 = bf16(relu^2)
template <int EPI>
__device__ __forceinline__
void g256_body(const u16* __restrict__ A, const u16* __restrict__ Bt,
               void* __restrict__ Cv, int N, int ldk, int klen,
               int bm, int bn) {
  extern __shared__ __align__(16) u16 lds[];
  const int tid = threadIdx.x, lane = tid & 63, w = tid >> 6;
  const int wr = w >> 2, wc = w & 3;
  const int l16 = lane & 15, lhi = lane >> 4;
  const int NT = klen >> 5;

  f32x4 acc[8][4];
#pragma unroll
  for (int i = 0; i < 8; ++i)
#pragma unroll
    for (int j = 0; j < 4; ++j)
#pragma unroll
      for (int r = 0; r < 4; ++r) acc[i][j][r] = 0.f;

  const int sd = tid * 16;
  const int sr = sd >> 6;
  const int sc = ((sd >> 4) & 3) ^ ((sr >> 1) & 3);
  const int sdst = w * 512;

  const int spn = lhi ^ ((l16 >> 1) & 3);
  const int aBase = wr * 4096 + l16 * 32 + spn * 8;
  const int bBase = 8192 + (wc >> 1) * 4096 + ((wc & 1) * 64 + l16) * 32 + spn * 8;

  auto stage_ht = [&](int kt, int ht) {
    const u16* src = (ht < 2) ? A : Bt;
    int rowbase = ((ht < 2) ? bm : bn) + (ht & 1) * 128;
    gld_lds16(src + (size_t)(rowbase + sr) * ldk + kt * 32 + sc * 8,
              &lds[(kt & 3) * 16384 + ht * 4096 + sdst]);
  };

#pragma unroll
  for (int t = 0; t < 3; ++t)
#pragma unroll
    for (int h = 0; h < 4; ++h) stage_ht(t, h);
  asm volatile("s_waitcnt vmcnt(8)" ::: "memory");
  __builtin_amdgcn_s_barrier();

  short8 a[4], b[4];
  for (int kt = 0; kt < NT; ++kt) {
    const int pb = (kt & 3) * 16384;
    __builtin_amdgcn_sched_barrier(0);
    // ---- phase 1: rows 0-63 ----
#pragma unroll
    for (int mi = 0; mi < 4; ++mi)
      a[mi] = *reinterpret_cast<const short8*>(&lds[pb + aBase + mi * 512]);
#pragma unroll
    for (int ni = 0; ni < 4; ++ni)
      b[ni] = *reinterpret_cast<const short8*>(&lds[pb + bBase + ni * 512]);
    if (kt + 3 < NT) { stage_ht(kt + 3, 0); stage_ht(kt + 3, 1); }
    asm volatile("s_waitcnt lgkmcnt(0)" ::: "memory");
    __builtin_amdgcn_sched_barrier(0);
    __builtin_amdgcn_s_setprio(1);
#pragma unroll
    for (int mi = 0; mi < 4; ++mi)
#pragma unroll
      for (int ni = 0; ni < 4; ++ni)
        acc[mi][ni] = __builtin_amdgcn_mfma_f32_16x16x32_bf16(a[mi], b[ni], acc[mi][ni], 0, 0, 0);
    __builtin_amdgcn_s_setprio(0);
    __builtin_amdgcn_sched_barrier(0);
    // ---- phase 2: rows 64-127 ----
#pragma unroll
    for (int mi = 0; mi < 4; ++mi)
      a[mi] = *reinterpret_cast<const short8*>(&lds[pb + aBase + 2048 + mi * 512]);
    if (kt + 3 < NT) { stage_ht(kt + 3, 2); stage_ht(kt + 3, 3); }
    asm volatile("s_waitcnt lgkmcnt(0)" ::: "memory");
    __builtin_amdgcn_sched_barrier(0);
    __builtin_amdgcn_s_setprio(1);
#pragma unroll
    for (int mi = 0; mi < 4; ++mi)
#pragma unroll
      for (int ni = 0; ni < 4; ++ni)
        acc[4 + mi][ni] = __builtin_amdgcn_mfma_f32_16x16x32_bf16(a[mi], b[ni], acc[4 + mi][ni], 0, 0, 0);
    __builtin_amdgcn_s_setprio(0);
    if (kt + 4 <= NT)      asm volatile("s_waitcnt vmcnt(8)" ::: "memory");
    else if (kt + 3 == NT) asm volatile("s_waitcnt vmcnt(4)" ::: "memory");
    else if (kt + 2 == NT) asm volatile("s_waitcnt vmcnt(0)" ::: "memory");
    __builtin_amdgcn_s_barrier();   // single rendezvous per K-tile
  }

#pragma unroll
  for (int q = 0; q < 8; ++q)
#pragma unroll
    for (int ni = 0; ni < 4; ++ni)
#pragma unroll
      for (int r = 0; r < 4; ++r) {
        int row = bm + wr * 128 + (q >> 2) * 64 + (q & 3) * 16 + lhi * 4 + r;
        int col = bn + wc * 64 + ni * 16 + l16;
        size_t o = (size_t)row * N + col;
        float v = acc[q][ni][r];
        if constexpr (EPI == 0) ((float*)Cv)[o] = v;
        else if constexpr (EPI == 1) ((u16*)Cv)[o] = f2b(v);
        else { v = fmaxf(v, 0.f); ((u16*)Cv)[o] = f2b(v * v); }
      }
}

// ========== 256x128 8-wave pipelined GEMM (ONE barrier per K-tile) ==========
__device__ __forceinline__
void g128_body(const u16* __restrict__ A, const u16* __restrict__ Bt,
               u16* __restrict__ Cv, int N, int ldk, int klen,
               int bm, int bn) {
  extern __shared__ __align__(16) u16 lds[];
  const int tid = threadIdx.x, lane = tid & 63, w = tid >> 6;
  const int wr = w >> 2, wc = w & 3;
  const int l16 = lane & 15, lhi = lane >> 4;
  const int NT = klen >> 5;

  f32x4 acc[8][2];
#pragma unroll
  for (int i = 0; i < 8; ++i)
#pragma unroll
    for (int j = 0; j < 2; ++j)
#pragma unroll
      for (int r = 0; r < 4; ++r) acc[i][j][r] = 0.f;

  const int sd = tid * 16;
  const int sr = sd >> 6;
  const int sc = ((sd >> 4) & 3) ^ ((sr >> 1) & 3);
  const int sdst = w * 512;

  const int spn = lhi ^ ((l16 >> 1) & 3);
  const int aBase = wr * 4096 + l16 * 32 + spn * 8;
  const int bBase = 8192 + (wc * 32 + l16) * 32 + spn * 8;

  auto stage_ht = [&](int kt, int ht) {
    const u16* src = (ht < 2) ? A : Bt;
    int rowbase = (ht < 2) ? (bm + ht * 128) : bn;
    int dsto = (ht < 2) ? ht * 4096 : 8192;
    gld_lds16(src + (size_t)(rowbase + sr) * ldk + kt * 32 + sc * 8,
              &lds[(kt & 3) * 12288 + dsto + sdst]);
  };

#pragma unroll
  for (int t = 0; t < 3; ++t) {
    stage_ht(t, 0); stage_ht(t, 1); stage_ht(t, 2);
  }
  asm volatile("s_waitcnt vmcnt(6)" ::: "memory");
  __builtin_amdgcn_s_barrier();

  short8 a[4], b[2];
  for (int kt = 0; kt < NT; ++kt) {
    const int pb = (kt & 3) * 12288;
    __builtin_amdgcn_sched_barrier(0);
    // ---- phase 1: rows 0-63 ----
#pragma unroll
    for (int mi = 0; mi < 4; ++mi)
      a[mi] = *reinterpret_cast<const short8*>(&lds[pb + aBase + mi * 512]);
#pragma unroll
    for (int ni = 0; ni < 2; ++ni)
      b[ni] = *reinterpret_cast<const short8*>(&lds[pb + bBase + ni * 512]);
    if (kt + 3 < NT) { stage_ht(kt + 3, 0); stage_ht(kt + 3, 1); }
    asm volatile("s_waitcnt lgkmcnt(0)" ::: "memory");
    __builtin_amdgcn_sched_barrier(0);
    __builtin_amdgcn_s_setprio(1);
#pragma unroll
    for (int mi = 0; mi < 4; ++mi)
#pragma unroll
      for (int ni = 0; ni < 2; ++ni)
        acc[mi][ni] = __builtin_amdgcn_mfma_f32_16x16x32_bf16(a[mi], b[ni], acc[mi][ni], 0, 0, 0);
    __builtin_amdgcn_s_setprio(0);
    __builtin_amdgcn_sched_barrier(0);
    // ---- phase 2: rows 64-127 ----
#pragma unroll
    for (int mi = 0; mi < 4; ++mi)
      a[mi] = *reinterpret_cast<const short8*>(&lds[pb + aBase + 2048 + mi * 512]);
    if (kt + 3 < NT) stage_ht(kt + 3, 2);
    asm volatile("s_waitcnt lgkmcnt(0)" ::: "memory");
    __builtin_amdgcn_sched_barrier(0);
    __builtin_amdgcn_s_setprio(1);
#pragma unroll
    for (int mi = 0; mi < 4; ++mi)
#pragma unroll
      for (int ni = 0; ni < 2; ++ni)
        acc[4 + mi][ni] = __builtin_amdgcn_mfma_f32_16x16x32_bf16(a[mi], b[ni], acc[4 + mi][ni], 0, 0, 0);
    __builtin_amdgcn_s_setprio(0);
    if (kt + 4 <= NT)      asm volatile("s_waitcnt vmcnt(6)" ::: "memory");
    else if (kt + 3 == NT) asm volatile("s_waitcnt vmcnt(3)" ::: "memory");
    else if (kt + 2 == NT) asm volatile("s_waitcnt vmcnt(0)" ::: "memory");
    __builtin_amdgcn_s_barrier();   // single rendezvous per K-tile
  }

#pragma unroll
  for (int q = 0; q < 8; ++q)
#pragma unroll
    for (int ni = 0; ni < 2; ++ni)
#pragma unroll
      for (int r = 0; r < 4; ++r) {
        int row = bm + wr * 128 + (q >> 2) * 64 + (q & 3) * 16 + lhi * 4 + r;
        int col = bn + wc * 32 + ni * 16 + l16;
        Cv[(size_t)row * N + col] = f2b(acc[q][ni][r]);
      }
}

// ---------------- GEMM kernel wrappers ----------------

// cm_Wk: sqrelu bf16; grid 256
__global__ __launch_bounds__(512)
void k_g256_cmk(const u16* __restrict__ A, const u16* __restrict__ Bt,
                u16* __restrict__ C) {
  int bid = blockIdx.x;
  int wg = (bid & 7) * 32 + (bid >> 3);
  int lb = wg & 3, sv = wg >> 2;
  int by = (sv >> 3) * 2 + (lb & 1);
  int bx = (sv & 7) * 2 + (lb >> 1);
  g256_body<2>(A, Bt, C, HDIM, EDIM, EDIM, by * 256, bx * 256);
}

// cm_Wv: split-K x4 over H, bf16 partials; grid 256
__global__ __launch_bounds__(512)
void k_g256_wv(const u16* __restrict__ A, const u16* __restrict__ Bt,
               u16* __restrict__ P) {
  int bid = blockIdx.x;
  int wg = (bid & 7) * 32 + (bid >> 3);
  int z = wg >> 6, rem = wg & 63;
  int lb = rem & 3, sv = rem >> 2;
  int by = (sv >> 1) * 2 + (lb & 1);
  int bx = (sv & 1) * 2 + (lb >> 1);
  g256_body<1>(A + z * 1024, Bt + z * 1024, P + (size_t)z * L_SEQ * EDIM,
               EDIM, HDIM, 1024, by * 256, bx * 256);
}

// batched k/v/r GEMMs, bf16 out; grid 192
__global__ __launch_bounds__(512)
void k_g256_3(const u16* __restrict__ A0, const u16* __restrict__ A1, const u16* __restrict__ A2,
              const u16* __restrict__ B0, const u16* __restrict__ B1, const u16* __restrict__ B2,
              u16* __restrict__ C0, u16* __restrict__ C1, u16* __restrict__ C2) {
  int bid = blockIdx.x;
  int wg = (bid & 7) * 24 + (bid >> 3);
  int z = wg >> 6, rem = wg & 63;
  int lb = rem & 3, sv = rem >> 2;
  int by = (sv >> 1) * 2 + (lb & 1);
  int bx = (sv & 1) * 2 + (lb >> 1);
  const u16* A = (z == 0) ? A0 : (z == 1) ? A1 : A2;
  const u16* B = (z == 0) ? B0 : (z == 1) ? B1 : B2;
  u16*       C = (z == 0) ? C0 : (z == 1) ? C1 : C2;
  g256_body<1>(A, B, C, EDIM, EDIM, EDIM, by * 256, bx * 256);
}

// E^2 GEMM split-K x2 (Wo / cm_Wr / neck), bf16 partials; grid 256
__global__ __launch_bounds__(512)
void k_gx128_sk2(const u16* __restrict__ A, const u16* __restrict__ Bt,
                 u16* __restrict__ P) {
  int bid = blockIdx.x;
  int wg = (bid & 7) * 32 + (bid >> 3);
  int z = wg >> 7, rem = wg & 127;
  int by = rem >> 3, bx = rem & 7;
  g128_body(A + z * 512, Bt + z * 512, P + (size_t)z * L_SEQ * EDIM,
            EDIM, EDIM, 512, by * 256, bx * 128);
}

// ---------------- chunk-parallel WKV (bf16 k/v/r) ----------------

__global__ void k_wkv_pass1(const u16* __restrict__ k, const u16* __restrict__ v,
                            const float* __restrict__ w_,
                            float* __restrict__ sa, float* __restrict__ sb,
                            float* __restrict__ sp) {
  int id = blockIdx.x * blockDim.x + threadIdx.x;
  int e = id & 1023, c = id >> 10;
  float D = __expf(w_[e]);
  float aa = 0.f, bb = 0.f, pp = -__builtin_inff();
  const u16* kp = k + (size_t)c * WKV_T * EDIM + e;
  const u16* vp = v + (size_t)c * WKV_T * EDIM + e;
#pragma unroll 4
  for (int i = 0; i < WKV_T; ++i) {
    float kk = b2f(kp[i * EDIM]), vv = b2f(vp[i * EDIM]);
    float ww = pp - D;
    float p2 = fmaxf(ww, kk);
    float e1 = __expf(ww - p2), e2 = __expf(kk - p2);
    aa = e1 * aa + e2 * vv;
    bb = e1 * bb + e2;
    pp = p2;
  }
  sa[id] = aa; sb[id] = bb; sp[id] = pp;
}

// parallel exclusive scan: 16 lanes/channel, 8 chunks/lane, shuffle combine
__global__ __launch_bounds__(256)
void k_wkv_scan16(const float* __restrict__ w_,
                  const float* __restrict__ sa, const float* __restrict__ sb,
                  const float* __restrict__ sp,
                  float* __restrict__ oa, float* __restrict__ ob,
                  float* __restrict__ op) {
  int t = blockIdx.x * blockDim.x + threadIdx.x;
  int e = t >> 4, j = t & (SCAN_LANES - 1);
  const float NEG = -1e30f;
  float DT = __expf(w_[e]) * (float)WKV_T;
  float Ea[SCAN_CPT], Eb[SCAN_CPT], Ep[SCAN_CPT];
  float A = 0.f, B = 0.f, P = NEG;
  int base = j * SCAN_CPT;
#pragma unroll
  for (int i = 0; i < SCAN_CPT; ++i) {
    int idx = (base + i) * EDIM + e;
    Ea[i] = A; Eb[i] = B; Ep[i] = P;
    float a = sa[idx], b = sb[idx], q = sp[idx];
    float shift = P - DT;
    float pn = fmaxf(shift, q);
    float w1 = __expf(shift - pn), w2 = __expf(q - pn);
    A = w1 * A + w2 * a; B = w1 * B + w2 * b; P = pn;
  }
  float tA = A, tB = B, tP = P; int tn = SCAN_CPT;
#pragma unroll
  for (int d = 1; d < SCAN_LANES; d <<= 1) {
    float fA = __shfl_up(tA, d, SCAN_LANES);
    float fB = __shfl_up(tB, d, SCAN_LANES);
    float fP = __shfl_up(tP, d, SCAN_LANES);
    int   fn = __shfl_up(tn, d, SCAN_LANES);
    if (j >= d) {
      float shift = fP - DT * (float)tn;
      float pn = fmaxf(shift, tP);
      float w1 = __expf(shift - pn), w2 = __expf(tP - pn);
      tA = w1 * fA + w2 * tA; tB = w1 * fB + w2 * tB; tP = pn; tn += fn;
    }
  }
  float pA = __shfl_up(tA, 1, SCAN_LANES);
  float pB = __shfl_up(tB, 1, SCAN_LANES);
  float pP = __shfl_up(tP, 1, SCAN_LANES);
  if (j == 0) { pA = 0.f; pB = 0.f; pP = NEG; }
#pragma unroll
  for (int i = 0; i < SCAN_CPT; ++i) {
    float shift = pP - DT * (float)i;
    float pn = fmaxf(shift, Ep[i]);
    float w1 = __expf(shift - pn), w2 = __expf(Ep[i] - pn);
    int idx = (base + i) * EDIM + e;
    oa[idx] = w1 * pA + w2 * Ea[i];
    ob[idx] = w1 * pB + w2 * Eb[i];
    op[idx] = pn;
  }
}

// pass2 with fused sigmoid gate: rwb = bf16(sig(rpre) * wkv)
__global__ void k_wkv_pass2(const u16* __restrict__ k, const u16* __restrict__ v,
                            const float* __restrict__ u_, const float* __restrict__ w_,
                            const float* __restrict__ sa, const float* __restrict__ sb,
                            const float* __restrict__ sp,
                            const u16* __restrict__ rpre, u16* __restrict__ rwb) {
  int id = blockIdx.x * blockDim.x + threadIdx.x;
  int e = id & 1023, c = id >> 10;
  float u = u_[e];
  float D = __expf(w_[e]);
  float aa = sa[id], bb = sb[id], pp = sp[id];
  const size_t base = (size_t)c * WKV_T * EDIM + e;
  const u16* kp = k + base;
  const u16* vp = v + base;
  const u16* rp = rpre + base;
  u16* op = rwb + base;
#pragma unroll 4
  for (int i = 0; i < WKV_T; ++i) {
    float kk = b2f(kp[i * EDIM]), vv = b2f(vp[i * EDIM]);
    float ww = u + kk;
    float p = fmaxf(pp, ww);
    float e1 = __expf(pp - p), e2 = __expf(ww - p);
    float out = (e1 * aa + e2 * vv) / (e1 * bb + e2);
    op[i * EDIM] = f2b(out * sigm(b2f(rp[i * EDIM])));
    float w2s = pp - D;
    float p2 = fmaxf(w2s, kk);
    float e1b = __expf(w2s - p2), e2b = __expf(kk - p2);
    aa = e1b * aa + e2b * vv;
    bb = e1b * bb + e2b;
    pp = p2;
  }
}

// ---------------- head (fused gelu, 2 neck partials) ----------------
__global__ __launch_bounds__(256)
void k_head(const u16* __restrict__ P, const float* __restrict__ nb,
            const float* __restrict__ W,
            const int* __restrict__ s, float* __restrict__ partial) {
  const size_t LE = (size_t)L_SEQ * EDIM;
  int t = blockIdx.x, tid = threadIdx.x;
  float a0 = 0.f, a1 = 0.f, a2 = 0.f, a3 = 0.f;
  for (int e = tid; e < EDIM; e += 256) {
    size_t i = (size_t)t * EDIM + e;
    float hv = gelu1(b2f(P[i]) + b2f(P[i + LE]) + nb[e]);
    const float4 wv = *reinterpret_cast<const float4*>(W + e * 4);
    a0 += hv * wv.x; a1 += hv * wv.y; a2 += hv * wv.z; a3 += hv * wv.w;
  }
#pragma unroll
  for (int off = 32; off > 0; off >>= 1) {
    a0 += __shfl_down(a0, off, 64);
    a1 += __shfl_down(a1, off, 64);
    a2 += __shfl_down(a2, off, 64);
    a3 += __shfl_down(a3, off, 64);
  }
  __shared__ float sm[4][4];
  int w = tid >> 6, lane = tid & 63;
  if (lane == 0) { sm[w][0] = a0; sm[w][1] = a1; sm[w][2] = a2; sm[w][3] = a3; }
  __syncthreads();
  if (tid == 0) {
    float lg[4];
#pragma unroll
    for (int j = 0; j < 4; ++j) lg[j] = sm[0][j] + sm[1][j] + sm[2][j] + sm[3][j];
    float m = fmaxf(fmaxf(lg[0], lg[1]), fmaxf(lg[2], lg[3]));
    float sum = expf(lg[0] - m) + expf(lg[1] - m) + expf(lg[2] - m) + expf(lg[3] - m);
    partial[t] = 0.5f * (lg[s[t]] - m - logf(sum));
  }
}

__global__ __launch_bounds__(256)
void k_reduce(const float* __restrict__ partial, float* __restrict__ out) {
  int tid = threadIdx.x;
  float a = 0.f;
  for (int j = tid; j < L_SEQ; j += 256) a += partial[j];
#pragma unroll
  for (int off = 32; off > 0; off >>= 1) a += __shfl_down(a, off, 64);
  __shared__ float sm[4];
  if ((tid & 63) == 0) sm[tid >> 6] = a;
  __syncthreads();
  if (tid == 0) out[0] = sm[0] + sm[1] + sm[2] + sm[3];
}

// ---------------- host ----------------

extern "C" void kernel_launch(void* const* d_in, const int* in_sizes, int n_in,
                              void* d_out, int out_size, void* d_ws, size_t ws_size,
                              hipStream_t stream) {
  const int*   s        = (const int*)d_in[0];
  const float* embed    = (const float*)d_in[1];
  const float* tm_first = (const float*)d_in[2];
  const float* tm_decay = (const float*)d_in[3];
  const float* tm_mk    = (const float*)d_in[4];
  const float* tm_mv    = (const float*)d_in[5];
  const float* tm_mr    = (const float*)d_in[6];
  const float* tm_Wk    = (const float*)d_in[7];
  const float* tm_Wv    = (const float*)d_in[8];
  const float* tm_Wr    = (const float*)d_in[9];
  const float* tm_Wo    = (const float*)d_in[10];
  const float* cm_mk    = (const float*)d_in[11];
  const float* cm_mr    = (const float*)d_in[12];
  const float* cm_Wk    = (const float*)d_in[13];
  const float* cm_Wr    = (const float*)d_in[14];
  const float* cm_Wv    = (const float*)d_in[15];
  const float* neck_W   = (const float*)d_in[16];
  const float* neck_b   = (const float*)d_in[17];
  const float* head_W   = (const float*)d_in[18];

  char* ws = (char*)d_ws;
  size_t off = 0;
  auto alloc = [&](size_t bytes) { char* p = ws + off; off += (bytes + 255) & ~(size_t)255; return p; };
  const size_t LE2 = (size_t)L_SEQ * EDIM * 2;
  const size_t EE  = (size_t)EDIM * EDIM, EH = (size_t)EDIM * HDIM;

  u16*   xA    = (u16*)alloc(LE2);
  u16*   xB    = (u16*)alloc(LE2);
  u16*   kxb   = (u16*)alloc(LE2);
  u16*   vxb   = (u16*)alloc(LE2);   // also rwb
  u16*   rxb   = (u16*)alloc(LE2);
  u16*   kf    = (u16*)alloc(LE2);
  u16*   vf    = (u16*)alloc(LE2);
  u16*   rpre  = (u16*)alloc(LE2);
  u16*   kkb   = (u16*)alloc((size_t)L_SEQ * HDIM * 2);
  u16*   PA    = (u16*)alloc(2 * LE2);   // Wo / neck partials (bf16 x2)
  u16*   PR    = (u16*)alloc(2 * LE2);   // cm_Wr partials (bf16 x2)
  u16*   PB    = (u16*)alloc(4 * LE2);   // cm_Wv partials (bf16 x4)
  float* partial = (float*)alloc((size_t)L_SEQ * 4);
  float* sa  = (float*)alloc((size_t)WKV_C * EDIM * 4);
  float* sb  = (float*)alloc((size_t)WKV_C * EDIM * 4);
  float* sp  = (float*)alloc((size_t)WKV_C * EDIM * 4);
  float* sa2 = (float*)alloc((size_t)WKV_C * EDIM * 4);
  float* sb2 = (float*)alloc((size_t)WKV_C * EDIM * 4);
  float* sp2 = (float*)alloc((size_t)WKV_C * EDIM * 4);

  size_t remain = (ws_size > off) ? ws_size - off : 0;
  const size_t bigNeed = (5 * EE * NLAY + 2 * EH * NLAY + EE) * 2 + 16 * 256;
  const bool big = remain >= bigNeed;
  const int NB = big ? NLAY : 1;
  u16* wWk   = (u16*)alloc(EE * NB * 2);
  u16* wWv   = (u16*)alloc(EE * NB * 2);
  u16* wWr   = (u16*)alloc(EE * NB * 2);
  u16* wWo   = (u16*)alloc(EE * NB * 2);
  u16* wcmWr = (u16*)alloc(EE * NB * 2);
  u16* wcmWk = (u16*)alloc(EH * NB * 2);
  u16* wcmWv = (u16*)alloc(EH * NB * 2);
  u16* wneck = big ? (u16*)alloc(EE * 2) : wWk;

  const dim3 blk(256);
  const dim3 blk512(512);
  const dim3 gE4((L_SEQ * EDIM) / 1024);
  const dim3 gWkv((WKV_C * EDIM) / 256);
  const dim3 gScan((EDIM * SCAN_LANES) / 256);
  const size_t DLDS  = 131072;  // 128KB for 256^2
  const size_t DLDS2 = 98304;   // 96KB for 256x128

  if (big) {
    k_tconv_all<<<dim3(TC_EE + 2 * TC_EH), blk, 0, stream>>>(
        tm_Wk, tm_Wv, tm_Wr, tm_Wo, cm_Wr, neck_W, cm_Wk, cm_Wv,
        wWk, wWv, wWr, wWo, wcmWr, wneck, wcmWk, wcmWv);
  }

  for (int l = 0; l < NLAY; ++l) {
    size_t oE  = (size_t)l * EDIM;
    size_t oEE = (size_t)l * EE;
    size_t oEH = (size_t)l * EH;
    size_t wE  = big ? oEE : 0;
    size_t wH  = big ? oEH : 0;
    if (!big) {
      k_tconv<<<dim3(EDIM / 64, EDIM / 64, 1), blk, 0, stream>>>(tm_Wk + oEE, wWk, EDIM, EDIM);
      k_tconv<<<dim3(EDIM / 64, EDIM / 64, 1), blk, 0, stream>>>(tm_Wv + oEE, wWv, EDIM, EDIM);
      k_tconv<<<dim3(EDIM / 64, EDIM / 64, 1), blk, 0, stream>>>(tm_Wr + oEE, wWr, EDIM, EDIM);
      k_tconv<<<dim3(EDIM / 64, EDIM / 64, 1), blk, 0, stream>>>(tm_Wo + oEE, wWo, EDIM, EDIM);
      k_tconv<<<dim3(EDIM / 64, EDIM / 64, 1), blk, 0, stream>>>(cm_Wr + oEE, wcmWr, EDIM, EDIM);
      k_tconv<<<dim3(HDIM / 64, EDIM / 64, 1), blk, 0, stream>>>(cm_Wk + oEH, wcmWk, EDIM, HDIM);
      k_tconv<<<dim3(EDIM / 64, HDIM / 64, 1), blk, 0, stream>>>(cm_Wv + oEH, wcmWv, HDIM, EDIM);
    }
    // --- TimeMixing ---
    if (l == 0)
      k_f0<<<gE4, blk, 0, stream>>>(s, embed, tm_mk + oE, tm_mv + oE, tm_mr + oE,
                                    xA, kxb, vxb, rxb);
    else
      k_f1<<<gE4, blk, 0, stream>>>(xB, PR, PB, tm_mk + oE, tm_mv + oE, tm_mr + oE,
                                    xA, kxb, vxb, rxb);
    k_g256_3<<<dim3(192), blk512, DLDS, stream>>>(kxb, vxb, rxb,
                                                  wWk + wE, wWv + wE, wWr + wE,
                                                  kf, vf, rpre);
    k_wkv_pass1<<<gWkv, blk, 0, stream>>>(kf, vf, tm_decay + oE, sa, sb, sp);
    k_wkv_scan16<<<gScan, blk, 0, stream>>>(tm_decay + oE, sa, sb, sp, sa2, sb2, sp2);
    k_wkv_pass2<<<gWkv, blk, 0, stream>>>(kf, vf, tm_first + oE, tm_decay + oE,
                                          sa2, sb2, sp2, rpre, vxb);
    k_gx128_sk2<<<dim3(256), blk512, DLDS2, stream>>>(vxb, wWo + wE, PA);
    // --- ChannelMixing ---
    k_f2<<<gE4, blk, 0, stream>>>(xA, PA, cm_mk + oE, cm_mr + oE, xB, kxb, rxb);
    k_gx128_sk2<<<dim3(256), blk512, DLDS2, stream>>>(rxb, wcmWr + wE, PR);
    k_g256_cmk<<<dim3(256), blk512, DLDS, stream>>>(kxb, wcmWk + wH, kkb);
    k_g256_wv<<<dim3(256), blk512, DLDS, stream>>>(kkb, wcmWv + wH, PB);
  }
  // --- Neck + Head ---
  if (!big) k_tconv<<<dim3(EDIM / 64, EDIM / 64, 1), blk, 0, stream>>>(neck_W, wneck, EDIM, EDIM);
  k_f3<<<gE4, blk, 0, stream>>>(xB, PR, PB, kxb);
  k_gx128_sk2<<<dim3(256), blk512, DLDS2, stream>>>(kxb, wneck, PA);
  k_head<<<dim3(L_SEQ), blk, 0, stream>>>(PA, neck_b, head_W, s, partial);
  k_reduce<<<dim3(1), blk, 0, stream>>>(partial, (float*)d_out);

  (void)in_sizes; (void)n_in; (void)out_size;
}

// Round 16
// 1632.391 us; speedup vs baseline: 1.1123x; 1.0678x over previous
//
#include <hip/hip_runtime.h>
#include <stdint.h>

#define L_SEQ 4096
#define EDIM  1024
#define HDIM  4096
#define NLAY  8
#define WKV_C 128  // chunks
#define WKV_T 32   // tokens per chunk
#define SCAN_LANES 16
#define SCAN_CPT   (WKV_C / SCAN_LANES)  // 8

typedef unsigned short u16;
typedef __attribute__((ext_vector_type(8))) short short8;
typedef __attribute__((ext_vector_type(4))) float f32x4;
typedef __attribute__((ext_vector_type(4))) float f4v;
typedef __attribute__((ext_vector_type(4))) unsigned short us4;
typedef __attribute__((ext_vector_type(8))) unsigned short us8;

static __device__ __forceinline__ u16 f2b(float f) {
  union { float f; uint32_t u; } a; a.f = f;
  uint32_t u = a.u;
  return (u16)((u + 0x7FFFu + ((u >> 16) & 1u)) >> 16);  // RNE
}
static __device__ __forceinline__ float b2f(u16 b) {
  union { uint32_t u; float f; } a; a.u = ((uint32_t)b) << 16;
  return a.f;
}
static __device__ __forceinline__ float sigm(float v) {
  return 1.f / (1.f + __expf(-v));
}
static __device__ __forceinline__ float4 ld_bf4(const u16* __restrict__ p, size_t i) {
  us4 v = *reinterpret_cast<const us4*>(&p[i]);
  return make_float4(b2f(v.x), b2f(v.y), b2f(v.z), b2f(v.w));
}

static __device__ __forceinline__ void gld_lds16(const void* g, void* l) {
  __builtin_amdgcn_global_load_lds(
      (const __attribute__((address_space(1))) void*)g,
      (__attribute__((address_space(3))) void*)l, 16, 0, 0);
}

// ---------------- fused elementwise (x residual in bf16) ----------------

// F0: x = embed[tok], tm-mix3 (layer 0)
__global__ void k_f0(const int* __restrict__ s, const float* __restrict__ embed,
                     const float* __restrict__ mk, const float* __restrict__ mv,
                     const float* __restrict__ mr, u16* __restrict__ xA,
                     u16* __restrict__ kx, u16* __restrict__ vx, u16* __restrict__ rx) {
  int i = (blockIdx.x * blockDim.x + threadIdx.x) * 4;
  int t = i >> 10, e = i & 1023;
  int tok = (t == 0) ? 0 : s[t - 1];
  float4 xc = *reinterpret_cast<const float4*>(&embed[tok * EDIM + e]);
  float4 xs = make_float4(0.f, 0.f, 0.f, 0.f);
  if (t > 0) {
    int tokp = (t == 1) ? 0 : s[t - 2];
    xs = *reinterpret_cast<const float4*>(&embed[tokp * EDIM + e]);
  }
  us4 ox; ox.x = f2b(xc.x); ox.y = f2b(xc.y); ox.z = f2b(xc.z); ox.w = f2b(xc.w);
  *reinterpret_cast<us4*>(&xA[i]) = ox;
  float4 m; us4 o;
  m = *reinterpret_cast<const float4*>(&mk[e]);
  o.x = f2b(xc.x * m.x + xs.x * (1.f - m.x)); o.y = f2b(xc.y * m.y + xs.y * (1.f - m.y));
  o.z = f2b(xc.z * m.z + xs.z * (1.f - m.z)); o.w = f2b(xc.w * m.w + xs.w * (1.f - m.w));
  *reinterpret_cast<us4*>(&kx[i]) = o;
  m = *reinterpret_cast<const float4*>(&mv[e]);
  o.x = f2b(xc.x * m.x + xs.x * (1.f - m.x)); o.y = f2b(xc.y * m.y + xs.y * (1.f - m.y));
  o.z = f2b(xc.z * m.z + xs.z * (1.f - m.z)); o.w = f2b(xc.w * m.w + xs.w * (1.f - m.w));
  *reinterpret_cast<us4*>(&vx[i]) = o;
  m = *reinterpret_cast<const float4*>(&mr[e]);
  o.x = f2b(xc.x * m.x + xs.x * (1.f - m.x)); o.y = f2b(xc.y * m.y + xs.y * (1.f - m.y));
  o.z = f2b(xc.z * m.z + xs.z * (1.f - m.z)); o.w = f2b(xc.w * m.w + xs.w * (1.f - m.w));
  *reinterpret_cast<us4*>(&rx[i]) = o;
}

// cm-finish: x = xB + sig(PR0+PR1) * (PB0+PB1+PB2+PB3)  (all bf16)
static __device__ __forceinline__ float4 cm_finish(const u16* __restrict__ xB,
                                                   const u16* __restrict__ PR,
                                                   const u16* __restrict__ PB, int i) {
  const size_t LE = (size_t)L_SEQ * EDIM;
  float4 xm = ld_bf4(xB, i);
  float4 r0 = ld_bf4(PR, i), r1 = ld_bf4(PR, i + LE);
  float4 v0 = ld_bf4(PB, i), v1 = ld_bf4(PB, i + LE);
  float4 v2 = ld_bf4(PB, i + 2 * LE), v3 = ld_bf4(PB, i + 3 * LE);
  xm.x += sigm(r0.x + r1.x) * (v0.x + v1.x + v2.x + v3.x);
  xm.y += sigm(r0.y + r1.y) * (v0.y + v1.y + v2.y + v3.y);
  xm.z += sigm(r0.z + r1.z) * (v0.z + v1.z + v2.z + v3.z);
  xm.w += sigm(r0.w + r1.w) * (v0.w + v1.w + v2.w + v3.w);
  return xm;
}

static __device__ __forceinline__ us4 mix4(float4 xc, float4 xs, float4 m) {
  us4 o;
  o.x = f2b(xc.x * m.x + xs.x * (1.f - m.x));
  o.y = f2b(xc.y * m.y + xs.y * (1.f - m.y));
  o.z = f2b(xc.z * m.z + xs.z * (1.f - m.z));
  o.w = f2b(xc.w * m.w + xs.w * (1.f - m.w));
  return o;
}

// F1 row-block: block b owns rows 4b..4b+3; thread col = 4*tid.
// Computes cm_finish once per row (incl. boundary row) into registers.
__global__ __launch_bounds__(256)
void k_f1(const u16* __restrict__ xB, const u16* __restrict__ PR,
          const u16* __restrict__ PB,
          const float* __restrict__ mk, const float* __restrict__ mv,
          const float* __restrict__ mr, u16* __restrict__ xA,
          u16* __restrict__ kx, u16* __restrict__ vx, u16* __restrict__ rx) {
  int b = blockIdx.x, col = threadIdx.x * 4;
  float4 cf[5];
#pragma unroll
  for (int r = 0; r < 5; ++r) {
    int t = 4 * b + r - 1;
    cf[r] = (t < 0) ? make_float4(0.f, 0.f, 0.f, 0.f)
                    : cm_finish(xB, PR, PB, t * EDIM + col);
  }
  float4 m_k = *reinterpret_cast<const float4*>(&mk[col]);
  float4 m_v = *reinterpret_cast<const float4*>(&mv[col]);
  float4 m_r = *reinterpret_cast<const float4*>(&mr[col]);
#pragma unroll
  for (int q = 0; q < 4; ++q) {
    int i = (4 * b + q) * EDIM + col;
    float4 xc = cf[q + 1], xs = cf[q];
    us4 ox; ox.x = f2b(xc.x); ox.y = f2b(xc.y); ox.z = f2b(xc.z); ox.w = f2b(xc.w);
    *reinterpret_cast<us4*>(&xA[i]) = ox;
    *reinterpret_cast<us4*>(&kx[i]) = mix4(xc, xs, m_k);
    *reinterpret_cast<us4*>(&vx[i]) = mix4(xc, xs, m_v);
    *reinterpret_cast<us4*>(&rx[i]) = mix4(xc, xs, m_r);
  }
}

static __device__ __forceinline__ float4 tm_finish(const u16* __restrict__ xA,
                                                   const u16* __restrict__ PA, int i) {
  const size_t LE = (size_t)L_SEQ * EDIM;
  float4 xm = ld_bf4(xA, i);
  float4 a = ld_bf4(PA, i), b = ld_bf4(PA, i + LE);
  xm.x += a.x + b.x; xm.y += a.y + b.y; xm.z += a.z + b.z; xm.w += a.w + b.w;
  return xm;
}

// F2 row-block: x = xA + PA0 + PA1; cm-mix2
__global__ __launch_bounds__(256)
void k_f2(const u16* __restrict__ xA, const u16* __restrict__ PA,
          const float* __restrict__ mk, const float* __restrict__ mr,
          u16* __restrict__ xB, u16* __restrict__ kx, u16* __restrict__ rx) {
  int b = blockIdx.x, col = threadIdx.x * 4;
  float4 cf[5];
#pragma unroll
  for (int r = 0; r < 5; ++r) {
    int t = 4 * b + r - 1;
    cf[r] = (t < 0) ? make_float4(0.f, 0.f, 0.f, 0.f)
                    : tm_finish(xA, PA, t * EDIM + col);
  }
  float4 m_k = *reinterpret_cast<const float4*>(&mk[col]);
  float4 m_r = *reinterpret_cast<const float4*>(&mr[col]);
#pragma unroll
  for (int q = 0; q < 4; ++q) {
    int i = (4 * b + q) * EDIM + col;
    float4 xc = cf[q + 1], xs = cf[q];
    us4 ox; ox.x = f2b(xc.x); ox.y = f2b(xc.y); ox.z = f2b(xc.z); ox.w = f2b(xc.w);
    *reinterpret_cast<us4*>(&xB[i]) = ox;
    *reinterpret_cast<us4*>(&kx[i]) = mix4(xc, xs, m_k);
    *reinterpret_cast<us4*>(&rx[i]) = mix4(xc, xs, m_r);
  }
}

// F3: hb = bf16(cm_finish)
__global__ void k_f3(const u16* __restrict__ xB, const u16* __restrict__ PR,
                     const u16* __restrict__ PB, u16* __restrict__ hb) {
  int i = (blockIdx.x * blockDim.x + threadIdx.x) * 4;
  float4 xc = cm_finish(xB, PR, PB, i);
  us4 o;
  o.x = f2b(xc.x); o.y = f2b(xc.y); o.z = f2b(xc.z); o.w = f2b(xc.w);
  *reinterpret_cast<us4*>(&hb[i]) = o;
}

static __device__ __forceinline__ float gelu1(float v) {
  float c = 0.7978845608028654f * (v + 0.044715f * v * v * v);
  return 0.5f * v * (1.f + tanhf(c));
}

// ---------------- transpose + f32->bf16 (NT loads) ----------------
static __device__ __forceinline__
void tconv2(const float* __restrict__ s, u16* __restrict__ d, int K, int N,
            int n0, int k0) {
  __shared__ float tile[64][65];
  int tid = threadIdx.x;
  int tx = tid & 15, ty = tid >> 4;
#pragma unroll
  for (int i = 0; i < 4; ++i) {
    int kr = ty + i * 16;
    f4v v = __builtin_nontemporal_load(
        reinterpret_cast<const f4v*>(&s[(size_t)(k0 + kr) * N + n0 + tx * 4]));
    tile[kr][tx * 4 + 0] = v.x; tile[kr][tx * 4 + 1] = v.y;
    tile[kr][tx * 4 + 2] = v.z; tile[kr][tx * 4 + 3] = v.w;
  }
  __syncthreads();
  int tx8 = tid & 7, ny = tid >> 3;
#pragma unroll
  for (int h = 0; h < 2; ++h) {
    int n = ny + h * 32;
    us8 o;
#pragma unroll
    for (int c = 0; c < 8; ++c) o[c] = f2b(tile[tx8 * 8 + c][n]);
    *reinterpret_cast<us8*>(&d[(size_t)(n0 + n) * K + k0 + tx8 * 8]) = o;
  }
}

__global__ __launch_bounds__(256)
void k_tconv(const float* __restrict__ src, u16* __restrict__ dst, int K, int N) {
  tconv2(src + (size_t)blockIdx.z * K * N, dst + (size_t)blockIdx.z * K * N,
         K, N, blockIdx.x * 64, blockIdx.y * 64);
}

// ALL weights in one flat launch: 41 ExE + 8 ExH (cm_Wk) + 8 HxE (cm_Wv)
#define TC_EE  (41 * 256)
#define TC_EH  8192
__global__ __launch_bounds__(256)
void k_tconv_all(const float* __restrict__ Wk, const float* __restrict__ Wv,
                 const float* __restrict__ Wr, const float* __restrict__ Wo,
                 const float* __restrict__ cWr, const float* __restrict__ nW,
                 const float* __restrict__ cWk, const float* __restrict__ cWv,
                 u16* __restrict__ oWk, u16* __restrict__ oWv, u16* __restrict__ oWr,
                 u16* __restrict__ oWo, u16* __restrict__ ocWr, u16* __restrict__ onW,
                 u16* __restrict__ ocWk, u16* __restrict__ ocWv) {
  const size_t EE = (size_t)EDIM * EDIM, EH = (size_t)EDIM * HDIM;
  int bid = blockIdx.x;
  if (bid < TC_EE) {
    int z = bid >> 8, rem = bid & 255;
    const float* src; u16* dst;
    if (z < 8)       { src = Wk  + (size_t)z * EE;        dst = oWk  + (size_t)z * EE; }
    else if (z < 16) { src = Wv  + (size_t)(z - 8) * EE;  dst = oWv  + (size_t)(z - 8) * EE; }
    else if (z < 24) { src = Wr  + (size_t)(z - 16) * EE; dst = oWr  + (size_t)(z - 16) * EE; }
    else if (z < 32) { src = Wo  + (size_t)(z - 24) * EE; dst = oWo  + (size_t)(z - 24) * EE; }
    else if (z < 40) { src = cWr + (size_t)(z - 32) * EE; dst = ocWr + (size_t)(z - 32) * EE; }
    else             { src = nW;                          dst = onW; }
    tconv2(src, dst, EDIM, EDIM, (rem & 15) * 64, (rem >> 4) * 64);
  } else if (bid < TC_EE + TC_EH) {
    int b = bid - TC_EE;
    int z = b >> 10, rem = b & 1023;
    tconv2(cWk + (size_t)z * EH, ocWk + (size_t)z * EH, EDIM, HDIM,
           (rem & 63) * 64, (rem >> 6) * 64);
  } else {
    int b = bid - TC_EE - TC_EH;
    int z = b >> 10, rem = b & 1023;
    tconv2(cWv + (size_t)z * EH, ocWv + (size_t)z * EH, HDIM, EDIM,
           (rem & 15) * 64, (rem >> 4) * 64);
  }
}

// ========== 256x256 8-wave pipelined GEMM (ONE barrier per K-tile) ==========
// EPI: 0 = f32 store, 1 = bf16 store, 2 = bf16(relu^2)
template <int EPI>
__device__ __forceinline__
void g256_body(const u16* __restrict__ A, const u16* __restrict__ Bt,
               void* __restrict__ Cv, int N, int ldk, int klen,
               int bm, int bn) {
  extern __shared__ __align__(16) u16 lds[];
  const int tid = threadIdx.x, lane = tid & 63, w = tid >> 6;
  const int wr = w >> 2, wc = w & 3;
  const int l16 = lane & 15, lhi = lane >> 4;
  const int NT = klen >> 5;

  f32x4 acc[8][4];
#pragma unroll
  for (int i = 0; i < 8; ++i)
#pragma unroll
    for (int j = 0; j < 4; ++j)
#pragma unroll
      for (int r = 0; r < 4; ++r) acc[i][j][r] = 0.f;

  const int sd = tid * 16;
  const int sr = sd >> 6;
  const int sc = ((sd >> 4) & 3) ^ ((sr >> 1) & 3);
  const int sdst = w * 512;

  const int spn = lhi ^ ((l16 >> 1) & 3);
  const int aBase = wr * 4096 + l16 * 32 + spn * 8;
  const int bBase = 8192 + (wc >> 1) * 4096 + ((wc & 1) * 64 + l16) * 32 + spn * 8;

  auto stage_ht = [&](int kt, int ht) {
    const u16* src = (ht < 2) ? A : Bt;
    int rowbase = ((ht < 2) ? bm : bn) + (ht & 1) * 128;
    gld_lds16(src + (size_t)(rowbase + sr) * ldk + kt * 32 + sc * 8,
              &lds[(kt & 3) * 16384 + ht * 4096 + sdst]);
  };

#pragma unroll
  for (int t = 0; t < 3; ++t)
#pragma unroll
    for (int h = 0; h < 4; ++h) stage_ht(t, h);
  asm volatile("s_waitcnt vmcnt(8)" ::: "memory");
  __builtin_amdgcn_s_barrier();

  short8 a[4], b[4];
  for (int kt = 0; kt < NT; ++kt) {
    const int pb = (kt & 3) * 16384;
    __builtin_amdgcn_sched_barrier(0);
    // ---- phase 1: rows 0-63 ----
#pragma unroll
    for (int mi = 0; mi < 4; ++mi)
      a[mi] = *reinterpret_cast<const short8*>(&lds[pb + aBase + mi * 512]);
#pragma unroll
    for (int ni = 0; ni < 4; ++ni)
      b[ni] = *reinterpret_cast<const short8*>(&lds[pb + bBase + ni * 512]);
    if (kt + 3 < NT) { stage_ht(kt + 3, 0); stage_ht(kt + 3, 1); }
    asm volatile("s_waitcnt lgkmcnt(0)" ::: "memory");
    __builtin_amdgcn_sched_barrier(0);
    __builtin_amdgcn_s_setprio(1);
#pragma unroll
    for (int mi = 0; mi < 4; ++mi)
#pragma unroll
      for (int ni = 0; ni < 4; ++ni)
        acc[mi][ni] = __builtin_amdgcn_mfma_f32_16x16x32_bf16(a[mi], b[ni], acc[mi][ni], 0, 0, 0);
    __builtin_amdgcn_s_setprio(0);
    __builtin_amdgcn_sched_barrier(0);
    // ---- phase 2: rows 64-127 ----
#pragma unroll
    for (int mi = 0; mi < 4; ++mi)
      a[mi] = *reinterpret_cast<const short8*>(&lds[pb + aBase + 2048 + mi * 512]);
    if (kt + 3 < NT) { stage_ht(kt + 3, 2); stage_ht(kt + 3, 3); }
    asm volatile("s_waitcnt lgkmcnt(0)" ::: "memory");
    __builtin_amdgcn_sched_barrier(0);
    __builtin_amdgcn_s_setprio(1);
#pragma unroll
    for (int mi = 0; mi < 4; ++mi)
#pragma unroll
      for (int ni = 0; ni < 4; ++ni)
        acc[4 + mi][ni] = __builtin_amdgcn_mfma_f32_16x16x32_bf16(a[mi], b[ni], acc[4 + mi][ni], 0, 0, 0);
    __builtin_amdgcn_s_setprio(0);
    if (kt + 4 <= NT)      asm volatile("s_waitcnt vmcnt(8)" ::: "memory");
    else if (kt + 3 == NT) asm volatile("s_waitcnt vmcnt(4)" ::: "memory");
    else if (kt + 2 == NT) asm volatile("s_waitcnt vmcnt(0)" ::: "memory");
    __builtin_amdgcn_s_barrier();   // single rendezvous per K-tile
  }

#pragma unroll
  for (int q = 0; q < 8; ++q)
#pragma unroll
    for (int ni = 0; ni < 4; ++ni)
#pragma unroll
      for (int r = 0; r < 4; ++r) {
        int row = bm + wr * 128 + (q >> 2) * 64 + (q & 3) * 16 + lhi * 4 + r;
        int col = bn + wc * 64 + ni * 16 + l16;
        size_t o = (size_t)row * N + col;
        float v = acc[q][ni][r];
        if constexpr (EPI == 0) ((float*)Cv)[o] = v;
        else if constexpr (EPI == 1) ((u16*)Cv)[o] = f2b(v);
        else { v = fmaxf(v, 0.f); ((u16*)Cv)[o] = f2b(v * v); }
      }
}

// ========== 256x128 8-wave pipelined GEMM (ONE barrier per K-tile) ==========
__device__ __forceinline__
void g128_body(const u16* __restrict__ A, const u16* __restrict__ Bt,
               u16* __restrict__ Cv, int N, int ldk, int klen,
               int bm, int bn) {
  extern __shared__ __align__(16) u16 lds[];
  const int tid = threadIdx.x, lane = tid & 63, w = tid >> 6;
  const int wr = w >> 2, wc = w & 3;
  const int l16 = lane & 15, lhi = lane >> 4;
  const int NT = klen >> 5;

  f32x4 acc[8][2];
#pragma unroll
  for (int i = 0; i < 8; ++i)
#pragma unroll
    for (int j = 0; j < 2; ++j)
#pragma unroll
      for (int r = 0; r < 4; ++r) acc[i][j][r] = 0.f;

  const int sd = tid * 16;
  const int sr = sd >> 6;
  const int sc = ((sd >> 4) & 3) ^ ((sr >> 1) & 3);
  const int sdst = w * 512;

  const int spn = lhi ^ ((l16 >> 1) & 3);
  const int aBase = wr * 4096 + l16 * 32 + spn * 8;
  const int bBase = 8192 + (wc * 32 + l16) * 32 + spn * 8;

  auto stage_ht = [&](int kt, int ht) {
    const u16* src = (ht < 2) ? A : Bt;
    int rowbase = (ht < 2) ? (bm + ht * 128) : bn;
    int dsto = (ht < 2) ? ht * 4096 : 8192;
    gld_lds16(src + (size_t)(rowbase + sr) * ldk + kt * 32 + sc * 8,
              &lds[(kt & 3) * 12288 + dsto + sdst]);
  };

#pragma unroll
  for (int t = 0; t < 3; ++t) {
    stage_ht(t, 0); stage_ht(t, 1); stage_ht(t, 2);
  }
  asm volatile("s_waitcnt vmcnt(6)" ::: "memory");
  __builtin_amdgcn_s_barrier();

  short8 a[4], b[2];
  for (int kt = 0; kt < NT; ++kt) {
    const int pb = (kt & 3) * 12288;
    __builtin_amdgcn_sched_barrier(0);
    // ---- phase 1: rows 0-63 ----
#pragma unroll
    for (int mi = 0; mi < 4; ++mi)
      a[mi] = *reinterpret_cast<const short8*>(&lds[pb + aBase + mi * 512]);
#pragma unroll
    for (int ni = 0; ni < 2; ++ni)
      b[ni] = *reinterpret_cast<const short8*>(&lds[pb + bBase + ni * 512]);
    if (kt + 3 < NT) { stage_ht(kt + 3, 0); stage_ht(kt + 3, 1); }
    asm volatile("s_waitcnt lgkmcnt(0)" ::: "memory");
    __builtin_amdgcn_sched_barrier(0);
    __builtin_amdgcn_s_setprio(1);
#pragma unroll
    for (int mi = 0; mi < 4; ++mi)
#pragma unroll
      for (int ni = 0; ni < 2; ++ni)
        acc[mi][ni] = __builtin_amdgcn_mfma_f32_16x16x32_bf16(a[mi], b[ni], acc[mi][ni], 0, 0, 0);
    __builtin_amdgcn_s_setprio(0);
    __builtin_amdgcn_sched_barrier(0);
    // ---- phase 2: rows 64-127 ----
#pragma unroll
    for (int mi = 0; mi < 4; ++mi)
      a[mi] = *reinterpret_cast<const short8*>(&lds[pb + aBase + 2048 + mi * 512]);
    if (kt + 3 < NT) stage_ht(kt + 3, 2);
    asm volatile("s_waitcnt lgkmcnt(0)" ::: "memory");
    __builtin_amdgcn_sched_barrier(0);
    __builtin_amdgcn_s_setprio(1);
#pragma unroll
    for (int mi = 0; mi < 4; ++mi)
#pragma unroll
      for (int ni = 0; ni < 2; ++ni)
        acc[4 + mi][ni] = __builtin_amdgcn_mfma_f32_16x16x32_bf16(a[mi], b[ni], acc[4 + mi][ni], 0, 0, 0);
    __builtin_amdgcn_s_setprio(0);
    if (kt + 4 <= NT)      asm volatile("s_waitcnt vmcnt(6)" ::: "memory");
    else if (kt + 3 == NT) asm volatile("s_waitcnt vmcnt(3)" ::: "memory");
    else if (kt + 2 == NT) asm volatile("s_waitcnt vmcnt(0)" ::: "memory");
    __builtin_amdgcn_s_barrier();   // single rendezvous per K-tile
  }

#pragma unroll
  for (int q = 0; q < 8; ++q)
#pragma unroll
    for (int ni = 0; ni < 2; ++ni)
#pragma unroll
      for (int r = 0; r < 4; ++r) {
        int row = bm + wr * 128 + (q >> 2) * 64 + (q & 3) * 16 + lhi * 4 + r;
        int col = bn + wc * 32 + ni * 16 + l16;
        Cv[(size_t)row * N + col] = f2b(acc[q][ni][r]);
      }
}

// ---------------- GEMM kernel wrappers ----------------

// cm_Wk: sqrelu bf16; grid 256
__global__ __launch_bounds__(512)
void k_g256_cmk(const u16* __restrict__ A, const u16* __restrict__ Bt,
                u16* __restrict__ C) {
  int bid = blockIdx.x;
  int wg = (bid & 7) * 32 + (bid >> 3);
  int lb = wg & 3, sv = wg >> 2;
  int by = (sv >> 3) * 2 + (lb & 1);
  int bx = (sv & 7) * 2 + (lb >> 1);
  g256_body<2>(A, Bt, C, HDIM, EDIM, EDIM, by * 256, bx * 256);
}

// cm_Wv: split-K x4 over H, bf16 partials; grid 256
__global__ __launch_bounds__(512)
void k_g256_wv(const u16* __restrict__ A, const u16* __restrict__ Bt,
               u16* __restrict__ P) {
  int bid = blockIdx.x;
  int wg = (bid & 7) * 32 + (bid >> 3);
  int z = wg >> 6, rem = wg & 63;
  int lb = rem & 3, sv = rem >> 2;
  int by = (sv >> 1) * 2 + (lb & 1);
  int bx = (sv & 1) * 2 + (lb >> 1);
  g256_body<1>(A + z * 1024, Bt + z * 1024, P + (size_t)z * L_SEQ * EDIM,
               EDIM, HDIM, 1024, by * 256, bx * 256);
}

// batched k/v/r GEMMs, bf16 out; grid 192
__global__ __launch_bounds__(512)
void k_g256_3(const u16* __restrict__ A0, const u16* __restrict__ A1, const u16* __restrict__ A2,
              const u16* __restrict__ B0, const u16* __restrict__ B1, const u16* __restrict__ B2,
              u16* __restrict__ C0, u16* __restrict__ C1, u16* __restrict__ C2) {
  int bid = blockIdx.x;
  int wg = (bid & 7) * 24 + (bid >> 3);
  int z = wg >> 6, rem = wg & 63;
  int lb = rem & 3, sv = rem >> 2;
  int by = (sv >> 1) * 2 + (lb & 1);
  int bx = (sv & 1) * 2 + (lb >> 1);
  const u16* A = (z == 0) ? A0 : (z == 1) ? A1 : A2;
  const u16* B = (z == 0) ? B0 : (z == 1) ? B1 : B2;
  u16*       C = (z == 0) ? C0 : (z == 1) ? C1 : C2;
  g256_body<1>(A, B, C, EDIM, EDIM, EDIM, by * 256, bx * 256);
}

// E^2 GEMM split-K x2 (Wo / cm_Wr / neck), bf16 partials; grid 256
__global__ __launch_bounds__(512)
void k_gx128_sk2(const u16* __restrict__ A, const u16* __restrict__ Bt,
                 u16* __restrict__ P) {
  int bid = blockIdx.x;
  int wg = (bid & 7) * 32 + (bid >> 3);
  int z = wg >> 7, rem = wg & 127;
  int by = rem >> 3, bx = rem & 7;
  g128_body(A + z * 512, Bt + z * 512, P + (size_t)z * L_SEQ * EDIM,
            EDIM, EDIM, 512, by * 256, bx * 128);
}

// ---------------- chunk-parallel WKV (bf16 k/v/r) ----------------

__global__ void k_wkv_pass1(const u16* __restrict__ k, const u16* __restrict__ v,
                            const float* __restrict__ w_,
                            float* __restrict__ sa, float* __restrict__ sb,
                            float* __restrict__ sp) {
  int id = blockIdx.x * blockDim.x + threadIdx.x;
  int e = id & 1023, c = id >> 10;
  float D = __expf(w_[e]);
  float aa = 0.f, bb = 0.f, pp = -__builtin_inff();
  const u16* kp = k + (size_t)c * WKV_T * EDIM + e;
  const u16* vp = v + (size_t)c * WKV_T * EDIM + e;
#pragma unroll 4
  for (int i = 0; i < WKV_T; ++i) {
    float kk = b2f(kp[i * EDIM]), vv = b2f(vp[i * EDIM]);
    float ww = pp - D;
    float p2 = fmaxf(ww, kk);
    float e1 = __expf(ww - p2), e2 = __expf(kk - p2);
    aa = e1 * aa + e2 * vv;
    bb = e1 * bb + e2;
    pp = p2;
  }
  sa[id] = aa; sb[id] = bb; sp[id] = pp;
}

// parallel exclusive scan: 16 lanes/channel, 8 chunks/lane, shuffle combine
__global__ __launch_bounds__(256)
void k_wkv_scan16(const float* __restrict__ w_,
                  const float* __restrict__ sa, const float* __restrict__ sb,
                  const float* __restrict__ sp,
                  float* __restrict__ oa, float* __restrict__ ob,
                  float* __restrict__ op) {
  int t = blockIdx.x * blockDim.x + threadIdx.x;
  int e = t >> 4, j = t & (SCAN_LANES - 1);
  const float NEG = -1e30f;
  float DT = __expf(w_[e]) * (float)WKV_T;
  float Ea[SCAN_CPT], Eb[SCAN_CPT], Ep[SCAN_CPT];
  float A = 0.f, B = 0.f, P = NEG;
  int base = j * SCAN_CPT;
#pragma unroll
  for (int i = 0; i < SCAN_CPT; ++i) {
    int idx = (base + i) * EDIM + e;
    Ea[i] = A; Eb[i] = B; Ep[i] = P;
    float a = sa[idx], b = sb[idx], q = sp[idx];
    float shift = P - DT;
    float pn = fmaxf(shift, q);
    float w1 = __expf(shift - pn), w2 = __expf(q - pn);
    A = w1 * A + w2 * a; B = w1 * B + w2 * b; P = pn;
  }
  float tA = A, tB = B, tP = P; int tn = SCAN_CPT;
#pragma unroll
  for (int d = 1; d < SCAN_LANES; d <<= 1) {
    float fA = __shfl_up(tA, d, SCAN_LANES);
    float fB = __shfl_up(tB, d, SCAN_LANES);
    float fP = __shfl_up(tP, d, SCAN_LANES);
    int   fn = __shfl_up(tn, d, SCAN_LANES);
    if (j >= d) {
      float shift = fP - DT * (float)tn;
      float pn = fmaxf(shift, tP);
      float w1 = __expf(shift - pn), w2 = __expf(tP - pn);
      tA = w1 * fA + w2 * tA; tB = w1 * fB + w2 * tB; tP = pn; tn += fn;
    }
  }
  float pA = __shfl_up(tA, 1, SCAN_LANES);
  float pB = __shfl_up(tB, 1, SCAN_LANES);
  float pP = __shfl_up(tP, 1, SCAN_LANES);
  if (j == 0) { pA = 0.f; pB = 0.f; pP = NEG; }
#pragma unroll
  for (int i = 0; i < SCAN_CPT; ++i) {
    float shift = pP - DT * (float)i;
    float pn = fmaxf(shift, Ep[i]);
    float w1 = __expf(shift - pn), w2 = __expf(Ep[i] - pn);
    int idx = (base + i) * EDIM + e;
    oa[idx] = w1 * pA + w2 * Ea[i];
    ob[idx] = w1 * pB + w2 * Eb[i];
    op[idx] = pn;
  }
}

// pass2 with fused sigmoid gate: rwb = bf16(sig(rpre) * wkv)
__global__ void k_wkv_pass2(const u16* __restrict__ k, const u16* __restrict__ v,
                            const float* __restrict__ u_, const float* __restrict__ w_,
                            const float* __restrict__ sa, const float* __restrict__ sb,
                            const float* __restrict__ sp,
                            const u16* __restrict__ rpre, u16* __restrict__ rwb) {
  int id = blockIdx.x * blockDim.x + threadIdx.x;
  int e = id & 1023, c = id >> 10;
  float u = u_[e];
  float D = __expf(w_[e]);
  float aa = sa[id], bb = sb[id], pp = sp[id];
  const size_t base = (size_t)c * WKV_T * EDIM + e;
  const u16* kp = k + base;
  const u16* vp = v + base;
  const u16* rp = rpre + base;
  u16* op = rwb + base;
#pragma unroll 4
  for (int i = 0; i < WKV_T; ++i) {
    float kk = b2f(kp[i * EDIM]), vv = b2f(vp[i * EDIM]);
    float ww = u + kk;
    float p = fmaxf(pp, ww);
    float e1 = __expf(pp - p), e2 = __expf(ww - p);
    float out = (e1 * aa + e2 * vv) / (e1 * bb + e2);
    op[i * EDIM] = f2b(out * sigm(b2f(rp[i * EDIM])));
    float w2s = pp - D;
    float p2 = fmaxf(w2s, kk);
    float e1b = __expf(w2s - p2), e2b = __expf(kk - p2);
    aa = e1b * aa + e2b * vv;
    bb = e1b * bb + e2b;
    pp = p2;
  }
}

// ---------------- head (fused gelu, 2 neck partials) ----------------
__global__ __launch_bounds__(256)
void k_head(const u16* __restrict__ P, const float* __restrict__ nb,
            const float* __restrict__ W,
            const int* __restrict__ s, float* __restrict__ partial) {
  const size_t LE = (size_t)L_SEQ * EDIM;
  int t = blockIdx.x, tid = threadIdx.x;
  float a0 = 0.f, a1 = 0.f, a2 = 0.f, a3 = 0.f;
  for (int e = tid; e < EDIM; e += 256) {
    size_t i = (size_t)t * EDIM + e;
    float hv = gelu1(b2f(P[i]) + b2f(P[i + LE]) + nb[e]);
    const float4 wv = *reinterpret_cast<const float4*>(W + e * 4);
    a0 += hv * wv.x; a1 += hv * wv.y; a2 += hv * wv.z; a3 += hv * wv.w;
  }
#pragma unroll
  for (int off = 32; off > 0; off >>= 1) {
    a0 += __shfl_down(a0, off, 64);
    a1 += __shfl_down(a1, off, 64);
    a2 += __shfl_down(a2, off, 64);
    a3 += __shfl_down(a3, off, 64);
  }
  __shared__ float sm[4][4];
  int w = tid >> 6, lane = tid & 63;
  if (lane == 0) { sm[w][0] = a0; sm[w][1] = a1; sm[w][2] = a2; sm[w][3] = a3; }
  __syncthreads();
  if (tid == 0) {
    float lg[4];
#pragma unroll
    for (int j = 0; j < 4; ++j) lg[j] = sm[0][j] + sm[1][j] + sm[2][j] + sm[3][j];
    float m = fmaxf(fmaxf(lg[0], lg[1]), fmaxf(lg[2], lg[3]));
    float sum = expf(lg[0] - m) + expf(lg[1] - m) + expf(lg[2] - m) + expf(lg[3] - m);
    partial[t] = 0.5f * (lg[s[t]] - m - logf(sum));
  }
}

__global__ __launch_bounds__(256)
void k_reduce(const float* __restrict__ partial, float* __restrict__ out) {
  int tid = threadIdx.x;
  float a = 0.f;
  for (int j = tid; j < L_SEQ; j += 256) a += partial[j];
#pragma unroll
  for (int off = 32; off > 0; off >>= 1) a += __shfl_down(a, off, 64);
  __shared__ float sm[4];
  if ((tid & 63) == 0) sm[tid >> 6] = a;
  __syncthreads();
  if (tid == 0) out[0] = sm[0] + sm[1] + sm[2] + sm[3];
}

// ---------------- host ----------------

extern "C" void kernel_launch(void* const* d_in, const int* in_sizes, int n_in,
                              void* d_out, int out_size, void* d_ws, size_t ws_size,
                              hipStream_t stream) {
  const int*   s        = (const int*)d_in[0];
  const float* embed    = (const float*)d_in[1];
  const float* tm_first = (const float*)d_in[2];
  const float* tm_decay = (const float*)d_in[3];
  const float* tm_mk    = (const float*)d_in[4];
  const float* tm_mv    = (const float*)d_in[5];
  const float* tm_mr    = (const float*)d_in[6];
  const float* tm_Wk    = (const float*)d_in[7];
  const float* tm_Wv    = (const float*)d_in[8];
  const float* tm_Wr    = (const float*)d_in[9];
  const float* tm_Wo    = (const float*)d_in[10];
  const float* cm_mk    = (const float*)d_in[11];
  const float* cm_mr    = (const float*)d_in[12];
  const float* cm_Wk    = (const float*)d_in[13];
  const float* cm_Wr    = (const float*)d_in[14];
  const float* cm_Wv    = (const float*)d_in[15];
  const float* neck_W   = (const float*)d_in[16];
  const float* neck_b   = (const float*)d_in[17];
  const float* head_W   = (const float*)d_in[18];

  char* ws = (char*)d_ws;
  size_t off = 0;
  auto alloc = [&](size_t bytes) { char* p = ws + off; off += (bytes + 255) & ~(size_t)255; return p; };
  const size_t LE2 = (size_t)L_SEQ * EDIM * 2;
  const size_t EE  = (size_t)EDIM * EDIM, EH = (size_t)EDIM * HDIM;

  u16*   xA    = (u16*)alloc(LE2);
  u16*   xB    = (u16*)alloc(LE2);
  u16*   kxb   = (u16*)alloc(LE2);
  u16*   vxb   = (u16*)alloc(LE2);   // also rwb
  u16*   rxb   = (u16*)alloc(LE2);
  u16*   kf    = (u16*)alloc(LE2);
  u16*   vf    = (u16*)alloc(LE2);
  u16*   rpre  = (u16*)alloc(LE2);
  u16*   kkb   = (u16*)alloc((size_t)L_SEQ * HDIM * 2);
  u16*   PA    = (u16*)alloc(2 * LE2);   // Wo / neck partials (bf16 x2)
  u16*   PR    = (u16*)alloc(2 * LE2);   // cm_Wr partials (bf16 x2)
  u16*   PB    = (u16*)alloc(4 * LE2);   // cm_Wv partials (bf16 x4)
  float* partial = (float*)alloc((size_t)L_SEQ * 4);
  float* sa  = (float*)alloc((size_t)WKV_C * EDIM * 4);
  float* sb  = (float*)alloc((size_t)WKV_C * EDIM * 4);
  float* sp  = (float*)alloc((size_t)WKV_C * EDIM * 4);
  float* sa2 = (float*)alloc((size_t)WKV_C * EDIM * 4);
  float* sb2 = (float*)alloc((size_t)WKV_C * EDIM * 4);
  float* sp2 = (float*)alloc((size_t)WKV_C * EDIM * 4);

  size_t remain = (ws_size > off) ? ws_size - off : 0;
  const size_t bigNeed = (5 * EE * NLAY + 2 * EH * NLAY + EE) * 2 + 16 * 256;
  const bool big = remain >= bigNeed;
  const int NB = big ? NLAY : 1;
  u16* wWk   = (u16*)alloc(EE * NB * 2);
  u16* wWv   = (u16*)alloc(EE * NB * 2);
  u16* wWr   = (u16*)alloc(EE * NB * 2);
  u16* wWo   = (u16*)alloc(EE * NB * 2);
  u16* wcmWr = (u16*)alloc(EE * NB * 2);
  u16* wcmWk = (u16*)alloc(EH * NB * 2);
  u16* wcmWv = (u16*)alloc(EH * NB * 2);
  u16* wneck = big ? (u16*)alloc(EE * 2) : wWk;

  const dim3 blk(256);
  const dim3 blk512(512);
  const dim3 gE4((L_SEQ * EDIM) / 1024);
  const dim3 gRB(L_SEQ / 4);               // row-block grid for f1/f2
  const dim3 gWkv((WKV_C * EDIM) / 256);
  const dim3 gScan((EDIM * SCAN_LANES) / 256);
  const size_t DLDS  = 131072;  // 128KB for 256^2
  const size_t DLDS2 = 98304;   // 96KB for 256x128

  if (big) {
    k_tconv_all<<<dim3(TC_EE + 2 * TC_EH), blk, 0, stream>>>(
        tm_Wk, tm_Wv, tm_Wr, tm_Wo, cm_Wr, neck_W, cm_Wk, cm_Wv,
        wWk, wWv, wWr, wWo, wcmWr, wneck, wcmWk, wcmWv);
  }

  for (int l = 0; l < NLAY; ++l) {
    size_t oE  = (size_t)l * EDIM;
    size_t oEE = (size_t)l * EE;
    size_t oEH = (size_t)l * EH;
    size_t wE  = big ? oEE : 0;
    size_t wH  = big ? oEH : 0;
    if (!big) {
      k_tconv<<<dim3(EDIM / 64, EDIM / 64, 1), blk, 0, stream>>>(tm_Wk + oEE, wWk, EDIM, EDIM);
      k_tconv<<<dim3(EDIM / 64, EDIM / 64, 1), blk, 0, stream>>>(tm_Wv + oEE, wWv, EDIM, EDIM);
      k_tconv<<<dim3(EDIM / 64, EDIM / 64, 1), blk, 0, stream>>>(tm_Wr + oEE, wWr, EDIM, EDIM);
      k_tconv<<<dim3(EDIM / 64, EDIM / 64, 1), blk, 0, stream>>>(tm_Wo + oEE, wWo, EDIM, EDIM);
      k_tconv<<<dim3(EDIM / 64, EDIM / 64, 1), blk, 0, stream>>>(cm_Wr + oEE, wcmWr, EDIM, EDIM);
      k_tconv<<<dim3(HDIM / 64, EDIM / 64, 1), blk, 0, stream>>>(cm_Wk + oEH, wcmWk, EDIM, HDIM);
      k_tconv<<<dim3(EDIM / 64, HDIM / 64, 1), blk, 0, stream>>>(cm_Wv + oEH, wcmWv, HDIM, EDIM);
    }
    // --- TimeMixing ---
    if (l == 0)
      k_f0<<<gE4, blk, 0, stream>>>(s, embed, tm_mk + oE, tm_mv + oE, tm_mr + oE,
                                    xA, kxb, vxb, rxb);
    else
      k_f1<<<gRB, blk, 0, stream>>>(xB, PR, PB, tm_mk + oE, tm_mv + oE, tm_mr + oE,
                                    xA, kxb, vxb, rxb);
    k_g256_3<<<dim3(192), blk512, DLDS, stream>>>(kxb, vxb, rxb,
                                                  wWk + wE, wWv + wE, wWr + wE,
                                                  kf, vf, rpre);
    k_wkv_pass1<<<gWkv, blk, 0, stream>>>(kf, vf, tm_decay + oE, sa, sb, sp);
    k_wkv_scan16<<<gScan, blk, 0, stream>>>(tm_decay + oE, sa, sb, sp, sa2, sb2, sp2);
    k_wkv_pass2<<<gWkv, blk, 0, stream>>>(kf, vf, tm_first + oE, tm_decay + oE,
                                          sa2, sb2, sp2, rpre, vxb);
    k_gx128_sk2<<<dim3(256), blk512, DLDS2, stream>>>(vxb, wWo + wE, PA);
    // --- ChannelMixing ---
    k_f2<<<gRB, blk, 0, stream>>>(xA, PA, cm_mk + oE, cm_mr + oE, xB, kxb, rxb);
    k_gx128_sk2<<<dim3(256), blk512, DLDS2, stream>>>(rxb, wcmWr + wE, PR);
    k_g256_cmk<<<dim3(256), blk512, DLDS, stream>>>(kxb, wcmWk + wH, kkb);
    k_g256_wv<<<dim3(256), blk512, DLDS, stream>>>(kkb, wcmWv + wH, PB);
  }
  // --- Neck + Head ---
  if (!big) k_tconv<<<dim3(EDIM / 64, EDIM / 64, 1), blk, 0, stream>>>(neck_W, wneck, EDIM, EDIM);
  k_f3<<<gE4, blk, 0, stream>>>(xB, PR, PB, kxb);
  k_gx128_sk2<<<dim3(256), blk512, DLDS2, stream>>>(kxb, wneck, PA);
  k_head<<<dim3(L_SEQ), blk, 0, stream>>>(PA, neck_b, head_W, s, partial);
  k_reduce<<<dim3(1), blk, 0, stream>>>(partial, (float*)d_out);

  (void)in_sizes; (void)n_in; (void)out_size;
}

// Round 17
// 1630.337 us; speedup vs baseline: 1.1137x; 1.0013x over previous
//
#include <hip/hip_runtime.h>
#include <stdint.h>

#define L_SEQ 4096
#define EDIM  1024
#define HDIM  4096
#define NLAY  8
#define WKV_C 128  // chunks
#define WKV_T 32   // tokens per chunk
#define SCAN_LANES 16
#define SCAN_CPT   (WKV_C / SCAN_LANES)  // 8

typedef unsigned short u16;
typedef __attribute__((ext_vector_type(8))) short short8;
typedef __attribute__((ext_vector_type(4))) float f32x4;
typedef __attribute__((ext_vector_type(4))) float f4v;
typedef __attribute__((ext_vector_type(4))) unsigned short us4;
typedef __attribute__((ext_vector_type(8))) unsigned short us8;

static __device__ __forceinline__ u16 f2b(float f) {
  union { float f; uint32_t u; } a; a.f = f;
  uint32_t u = a.u;
  return (u16)((u + 0x7FFFu + ((u >> 16) & 1u)) >> 16);  // RNE
}
static __device__ __forceinline__ float b2f(u16 b) {
  union { uint32_t u; float f; } a; a.u = ((uint32_t)b) << 16;
  return a.f;
}
static __device__ __forceinline__ float sigm(float v) {
  return 1.f / (1.f + __expf(-v));
}
static __device__ __forceinline__ float4 ld_bf4(const u16* __restrict__ p, size_t i) {
  us4 v = *reinterpret_cast<const us4*>(&p[i]);
  return make_float4(b2f(v.x), b2f(v.y), b2f(v.z), b2f(v.w));
}

static __device__ __forceinline__ void gld_lds16(const void* g, void* l) {
  __builtin_amdgcn_global_load_lds(
      (const __attribute__((address_space(1))) void*)g,
      (__attribute__((address_space(3))) void*)l, 16, 0, 0);
}

// ---------------- fused elementwise (x residual in bf16) ----------------

// F0: x = embed[tok], tm-mix3 (layer 0)
__global__ void k_f0(const int* __restrict__ s, const float* __restrict__ embed,
                     const float* __restrict__ mk, const float* __restrict__ mv,
                     const float* __restrict__ mr, u16* __restrict__ xA,
                     u16* __restrict__ kx, u16* __restrict__ vx, u16* __restrict__ rx) {
  int i = (blockIdx.x * blockDim.x + threadIdx.x) * 4;
  int t = i >> 10, e = i & 1023;
  int tok = (t == 0) ? 0 : s[t - 1];
  float4 xc = *reinterpret_cast<const float4*>(&embed[tok * EDIM + e]);
  float4 xs = make_float4(0.f, 0.f, 0.f, 0.f);
  if (t > 0) {
    int tokp = (t == 1) ? 0 : s[t - 2];
    xs = *reinterpret_cast<const float4*>(&embed[tokp * EDIM + e]);
  }
  us4 ox; ox.x = f2b(xc.x); ox.y = f2b(xc.y); ox.z = f2b(xc.z); ox.w = f2b(xc.w);
  *reinterpret_cast<us4*>(&xA[i]) = ox;
  float4 m; us4 o;
  m = *reinterpret_cast<const float4*>(&mk[e]);
  o.x = f2b(xc.x * m.x + xs.x * (1.f - m.x)); o.y = f2b(xc.y * m.y + xs.y * (1.f - m.y));
  o.z = f2b(xc.z * m.z + xs.z * (1.f - m.z)); o.w = f2b(xc.w * m.w + xs.w * (1.f - m.w));
  *reinterpret_cast<us4*>(&kx[i]) = o;
  m = *reinterpret_cast<const float4*>(&mv[e]);
  o.x = f2b(xc.x * m.x + xs.x * (1.f - m.x)); o.y = f2b(xc.y * m.y + xs.y * (1.f - m.y));
  o.z = f2b(xc.z * m.z + xs.z * (1.f - m.z)); o.w = f2b(xc.w * m.w + xs.w * (1.f - m.w));
  *reinterpret_cast<us4*>(&vx[i]) = o;
  m = *reinterpret_cast<const float4*>(&mr[e]);
  o.x = f2b(xc.x * m.x + xs.x * (1.f - m.x)); o.y = f2b(xc.y * m.y + xs.y * (1.f - m.y));
  o.z = f2b(xc.z * m.z + xs.z * (1.f - m.z)); o.w = f2b(xc.w * m.w + xs.w * (1.f - m.w));
  *reinterpret_cast<us4*>(&rx[i]) = o;
}

// cm-finish: x = xB + sig(PR0+PR1) * (PB0+PB1+PB2+PB3)  (all bf16)
static __device__ __forceinline__ float4 cm_finish(const u16* __restrict__ xB,
                                                   const u16* __restrict__ PR,
                                                   const u16* __restrict__ PB, int i) {
  const size_t LE = (size_t)L_SEQ * EDIM;
  float4 xm = ld_bf4(xB, i);
  float4 r0 = ld_bf4(PR, i), r1 = ld_bf4(PR, i + LE);
  float4 v0 = ld_bf4(PB, i), v1 = ld_bf4(PB, i + LE);
  float4 v2 = ld_bf4(PB, i + 2 * LE), v3 = ld_bf4(PB, i + 3 * LE);
  xm.x += sigm(r0.x + r1.x) * (v0.x + v1.x + v2.x + v3.x);
  xm.y += sigm(r0.y + r1.y) * (v0.y + v1.y + v2.y + v3.y);
  xm.z += sigm(r0.z + r1.z) * (v0.z + v1.z + v2.z + v3.z);
  xm.w += sigm(r0.w + r1.w) * (v0.w + v1.w + v2.w + v3.w);
  return xm;
}

static __device__ __forceinline__ us4 mix4(float4 xc, float4 xs, float4 m) {
  us4 o;
  o.x = f2b(xc.x * m.x + xs.x * (1.f - m.x));
  o.y = f2b(xc.y * m.y + xs.y * (1.f - m.y));
  o.z = f2b(xc.z * m.z + xs.z * (1.f - m.z));
  o.w = f2b(xc.w * m.w + xs.w * (1.f - m.w));
  return o;
}

// F1 row-block: block b owns rows 4b..4b+3; thread col = 4*tid.
__global__ __launch_bounds__(256)
void k_f1(const u16* __restrict__ xB, const u16* __restrict__ PR,
          const u16* __restrict__ PB,
          const float* __restrict__ mk, const float* __restrict__ mv,
          const float* __restrict__ mr, u16* __restrict__ xA,
          u16* __restrict__ kx, u16* __restrict__ vx, u16* __restrict__ rx) {
  int b = blockIdx.x, col = threadIdx.x * 4;
  float4 cf[5];
#pragma unroll
  for (int r = 0; r < 5; ++r) {
    int t = 4 * b + r - 1;
    cf[r] = (t < 0) ? make_float4(0.f, 0.f, 0.f, 0.f)
                    : cm_finish(xB, PR, PB, t * EDIM + col);
  }
  float4 m_k = *reinterpret_cast<const float4*>(&mk[col]);
  float4 m_v = *reinterpret_cast<const float4*>(&mv[col]);
  float4 m_r = *reinterpret_cast<const float4*>(&mr[col]);
#pragma unroll
  for (int q = 0; q < 4; ++q) {
    int i = (4 * b + q) * EDIM + col;
    float4 xc = cf[q + 1], xs = cf[q];
    us4 ox; ox.x = f2b(xc.x); ox.y = f2b(xc.y); ox.z = f2b(xc.z); ox.w = f2b(xc.w);
    *reinterpret_cast<us4*>(&xA[i]) = ox;
    *reinterpret_cast<us4*>(&kx[i]) = mix4(xc, xs, m_k);
    *reinterpret_cast<us4*>(&vx[i]) = mix4(xc, xs, m_v);
    *reinterpret_cast<us4*>(&rx[i]) = mix4(xc, xs, m_r);
  }
}

static __device__ __forceinline__ float4 tm_finish(const u16* __restrict__ xA,
                                                   const u16* __restrict__ PA, int i) {
  const size_t LE = (size_t)L_SEQ * EDIM;
  float4 xm = ld_bf4(xA, i);
  float4 a = ld_bf4(PA, i), b = ld_bf4(PA, i + LE);
  xm.x += a.x + b.x; xm.y += a.y + b.y; xm.z += a.z + b.z; xm.w += a.w + b.w;
  return xm;
}

// F2 row-block: x = xA + PA0 + PA1; cm-mix2
__global__ __launch_bounds__(256)
void k_f2(const u16* __restrict__ xA, const u16* __restrict__ PA,
          const float* __restrict__ mk, const float* __restrict__ mr,
          u16* __restrict__ xB, u16* __restrict__ kx, u16* __restrict__ rx) {
  int b = blockIdx.x, col = threadIdx.x * 4;
  float4 cf[5];
#pragma unroll
  for (int r = 0; r < 5; ++r) {
    int t = 4 * b + r - 1;
    cf[r] = (t < 0) ? make_float4(0.f, 0.f, 0.f, 0.f)
                    : tm_finish(xA, PA, t * EDIM + col);
  }
  float4 m_k = *reinterpret_cast<const float4*>(&mk[col]);
  float4 m_r = *reinterpret_cast<const float4*>(&mr[col]);
#pragma unroll
  for (int q = 0; q < 4; ++q) {
    int i = (4 * b + q) * EDIM + col;
    float4 xc = cf[q + 1], xs = cf[q];
    us4 ox; ox.x = f2b(xc.x); ox.y = f2b(xc.y); ox.z = f2b(xc.z); ox.w = f2b(xc.w);
    *reinterpret_cast<us4*>(&xB[i]) = ox;
    *reinterpret_cast<us4*>(&kx[i]) = mix4(xc, xs, m_k);
    *reinterpret_cast<us4*>(&rx[i]) = mix4(xc, xs, m_r);
  }
}

// F3: hb = bf16(cm_finish)
__global__ void k_f3(const u16* __restrict__ xB, const u16* __restrict__ PR,
                     const u16* __restrict__ PB, u16* __restrict__ hb) {
  int i = (blockIdx.x * blockDim.x + threadIdx.x) * 4;
  float4 xc = cm_finish(xB, PR, PB, i);
  us4 o;
  o.x = f2b(xc.x); o.y = f2b(xc.y); o.z = f2b(xc.z); o.w = f2b(xc.w);
  *reinterpret_cast<us4*>(&hb[i]) = o;
}

static __device__ __forceinline__ float gelu1(float v) {
  float c = 0.7978845608028654f * (v + 0.044715f * v * v * v);
  return 0.5f * v * (1.f + tanhf(c));
}

// ---------------- transpose + f32->bf16 (NT loads) ----------------
static __device__ __forceinline__
void tconv2(const float* __restrict__ s, u16* __restrict__ d, int K, int N,
            int n0, int k0) {
  __shared__ float tile[64][65];
  int tid = threadIdx.x;
  int tx = tid & 15, ty = tid >> 4;
#pragma unroll
  for (int i = 0; i < 4; ++i) {
    int kr = ty + i * 16;
    f4v v = __builtin_nontemporal_load(
        reinterpret_cast<const f4v*>(&s[(size_t)(k0 + kr) * N + n0 + tx * 4]));
    tile[kr][tx * 4 + 0] = v.x; tile[kr][tx * 4 + 1] = v.y;
    tile[kr][tx * 4 + 2] = v.z; tile[kr][tx * 4 + 3] = v.w;
  }
  __syncthreads();
  int tx8 = tid & 7, ny = tid >> 3;
#pragma unroll
  for (int h = 0; h < 2; ++h) {
    int n = ny + h * 32;
    us8 o;
#pragma unroll
    for (int c = 0; c < 8; ++c) o[c] = f2b(tile[tx8 * 8 + c][n]);
    *reinterpret_cast<us8*>(&d[(size_t)(n0 + n) * K + k0 + tx8 * 8]) = o;
  }
}

__global__ __launch_bounds__(256)
void k_tconv(const float* __restrict__ src, u16* __restrict__ dst, int K, int N) {
  tconv2(src + (size_t)blockIdx.z * K * N, dst + (size_t)blockIdx.z * K * N,
         K, N, blockIdx.x * 64, blockIdx.y * 64);
}

// ALL weights in one flat launch: 41 ExE + 8 ExH (cm_Wk) + 8 HxE (cm_Wv)
#define TC_EE  (41 * 256)
#define TC_EH  8192
__global__ __launch_bounds__(256)
void k_tconv_all(const float* __restrict__ Wk, const float* __restrict__ Wv,
                 const float* __restrict__ Wr, const float* __restrict__ Wo,
                 const float* __restrict__ cWr, const float* __restrict__ nW,
                 const float* __restrict__ cWk, const float* __restrict__ cWv,
                 u16* __restrict__ oWk, u16* __restrict__ oWv, u16* __restrict__ oWr,
                 u16* __restrict__ oWo, u16* __restrict__ ocWr, u16* __restrict__ onW,
                 u16* __restrict__ ocWk, u16* __restrict__ ocWv) {
  const size_t EE = (size_t)EDIM * EDIM, EH = (size_t)EDIM * HDIM;
  int bid = blockIdx.x;
  if (bid < TC_EE) {
    int z = bid >> 8, rem = bid & 255;
    const float* src; u16* dst;
    if (z < 8)       { src = Wk  + (size_t)z * EE;        dst = oWk  + (size_t)z * EE; }
    else if (z < 16) { src = Wv  + (size_t)(z - 8) * EE;  dst = oWv  + (size_t)(z - 8) * EE; }
    else if (z < 24) { src = Wr  + (size_t)(z - 16) * EE; dst = oWr  + (size_t)(z - 16) * EE; }
    else if (z < 32) { src = Wo  + (size_t)(z - 24) * EE; dst = oWo  + (size_t)(z - 24) * EE; }
    else if (z < 40) { src = cWr + (size_t)(z - 32) * EE; dst = ocWr + (size_t)(z - 32) * EE; }
    else             { src = nW;                          dst = onW; }
    tconv2(src, dst, EDIM, EDIM, (rem & 15) * 64, (rem >> 4) * 64);
  } else if (bid < TC_EE + TC_EH) {
    int b = bid - TC_EE;
    int z = b >> 10, rem = b & 1023;
    tconv2(cWk + (size_t)z * EH, ocWk + (size_t)z * EH, EDIM, HDIM,
           (rem & 63) * 64, (rem >> 6) * 64);
  } else {
    int b = bid - TC_EE - TC_EH;
    int z = b >> 10, rem = b & 1023;
    tconv2(cWv + (size_t)z * EH, ocWv + (size_t)z * EH, HDIM, EDIM,
           (rem & 15) * 64, (rem >> 4) * 64);
  }
}

// ========== 256x256 8-wave pipelined GEMM (ONE barrier per K-tile) ==========
// EPI: 0 = f32 store, 1 = bf16 store, 2 = bf16(relu^2)
template <int EPI>
__device__ __forceinline__
void g256_body(const u16* __restrict__ A, const u16* __restrict__ Bt,
               void* __restrict__ Cv, int N, int ldk, int klen,
               int bm, int bn) {
  extern __shared__ __align__(16) u16 lds[];
  const int tid = threadIdx.x, lane = tid & 63, w = tid >> 6;
  const int wr = w >> 2, wc = w & 3;
  const int l16 = lane & 15, lhi = lane >> 4;
  const int NT = klen >> 5;

  f32x4 acc[8][4];
#pragma unroll
  for (int i = 0; i < 8; ++i)
#pragma unroll
    for (int j = 0; j < 4; ++j)
#pragma unroll
      for (int r = 0; r < 4; ++r) acc[i][j][r] = 0.f;

  const int sd = tid * 16;
  const int sr = sd >> 6;
  const int sc = ((sd >> 4) & 3) ^ ((sr >> 1) & 3);
  const int sdst = w * 512;

  const int spn = lhi ^ ((l16 >> 1) & 3);
  const int aBase = wr * 4096 + l16 * 32 + spn * 8;
  const int bBase = 8192 + (wc >> 1) * 4096 + ((wc & 1) * 64 + l16) * 32 + spn * 8;

  auto stage_ht = [&](int kt, int ht) {
    const u16* src = (ht < 2) ? A : Bt;
    int rowbase = ((ht < 2) ? bm : bn) + (ht & 1) * 128;
    gld_lds16(src + (size_t)(rowbase + sr) * ldk + kt * 32 + sc * 8,
              &lds[(kt & 3) * 16384 + ht * 4096 + sdst]);
  };

#pragma unroll
  for (int t = 0; t < 3; ++t)
#pragma unroll
    for (int h = 0; h < 4; ++h) stage_ht(t, h);
  asm volatile("s_waitcnt vmcnt(8)" ::: "memory");
  __builtin_amdgcn_s_barrier();

  short8 a[4], b[4];
  for (int kt = 0; kt < NT; ++kt) {
    const int pb = (kt & 3) * 16384;
    __builtin_amdgcn_sched_barrier(0);
    // ---- phase 1: rows 0-63 ----
#pragma unroll
    for (int mi = 0; mi < 4; ++mi)
      a[mi] = *reinterpret_cast<const short8*>(&lds[pb + aBase + mi * 512]);
#pragma unroll
    for (int ni = 0; ni < 4; ++ni)
      b[ni] = *reinterpret_cast<const short8*>(&lds[pb + bBase + ni * 512]);
    if (kt + 3 < NT) { stage_ht(kt + 3, 0); stage_ht(kt + 3, 1); }
    asm volatile("s_waitcnt lgkmcnt(0)" ::: "memory");
    __builtin_amdgcn_sched_barrier(0);
    __builtin_amdgcn_s_setprio(1);
#pragma unroll
    for (int mi = 0; mi < 4; ++mi)
#pragma unroll
      for (int ni = 0; ni < 4; ++ni)
        acc[mi][ni] = __builtin_amdgcn_mfma_f32_16x16x32_bf16(a[mi], b[ni], acc[mi][ni], 0, 0, 0);
    __builtin_amdgcn_s_setprio(0);
    __builtin_amdgcn_sched_barrier(0);
    // ---- phase 2: rows 64-127 ----
#pragma unroll
    for (int mi = 0; mi < 4; ++mi)
      a[mi] = *reinterpret_cast<const short8*>(&lds[pb + aBase + 2048 + mi * 512]);
    if (kt + 3 < NT) { stage_ht(kt + 3, 2); stage_ht(kt + 3, 3); }
    asm volatile("s_waitcnt lgkmcnt(0)" ::: "memory");
    __builtin_amdgcn_sched_barrier(0);
    __builtin_amdgcn_s_setprio(1);
#pragma unroll
    for (int mi = 0; mi < 4; ++mi)
#pragma unroll
      for (int ni = 0; ni < 4; ++ni)
        acc[4 + mi][ni] = __builtin_amdgcn_mfma_f32_16x16x32_bf16(a[mi], b[ni], acc[4 + mi][ni], 0, 0, 0);
    __builtin_amdgcn_s_setprio(0);
    if (kt + 4 <= NT)      asm volatile("s_waitcnt vmcnt(8)" ::: "memory");
    else if (kt + 3 == NT) asm volatile("s_waitcnt vmcnt(4)" ::: "memory");
    else if (kt + 2 == NT) asm volatile("s_waitcnt vmcnt(0)" ::: "memory");
    __builtin_amdgcn_s_barrier();   // single rendezvous per K-tile
  }

#pragma unroll
  for (int q = 0; q < 8; ++q)
#pragma unroll
    for (int ni = 0; ni < 4; ++ni)
#pragma unroll
      for (int r = 0; r < 4; ++r) {
        int row = bm + wr * 128 + (q >> 2) * 64 + (q & 3) * 16 + lhi * 4 + r;
        int col = bn + wc * 64 + ni * 16 + l16;
        size_t o = (size_t)row * N + col;
        float v = acc[q][ni][r];
        if constexpr (EPI == 0) ((float*)Cv)[o] = v;
        else if constexpr (EPI == 1) ((u16*)Cv)[o] = f2b(v);
        else { v = fmaxf(v, 0.f); ((u16*)Cv)[o] = f2b(v * v); }
      }
}

// ========== 256x128 8-wave pipelined GEMM (3 LDS buffers = 72KB, 2 blocks/CU) ==========
__device__ __forceinline__
void g128_body(const u16* __restrict__ A, const u16* __restrict__ Bt,
               u16* __restrict__ Cv, int N, int ldk, int klen,
               int bm, int bn) {
  extern __shared__ __align__(16) u16 lds[];
  const int tid = threadIdx.x, lane = tid & 63, w = tid >> 6;
  const int wr = w >> 2, wc = w & 3;
  const int l16 = lane & 15, lhi = lane >> 4;
  const int NT = klen >> 5;

  f32x4 acc[8][2];
#pragma unroll
  for (int i = 0; i < 8; ++i)
#pragma unroll
    for (int j = 0; j < 2; ++j)
#pragma unroll
      for (int r = 0; r < 4; ++r) acc[i][j][r] = 0.f;

  const int sd = tid * 16;
  const int sr = sd >> 6;
  const int sc = ((sd >> 4) & 3) ^ ((sr >> 1) & 3);
  const int sdst = w * 512;

  const int spn = lhi ^ ((l16 >> 1) & 3);
  const int aBase = wr * 4096 + l16 * 32 + spn * 8;
  const int bBase = 8192 + (wc * 32 + l16) * 32 + spn * 8;

  auto stage_ht = [&](int kt, int ht, int buf) {
    const u16* src = (ht < 2) ? A : Bt;
    int rowbase = (ht < 2) ? (bm + ht * 128) : bn;
    int dsto = (ht < 2) ? ht * 4096 : 8192;
    gld_lds16(src + (size_t)(rowbase + sr) * ldk + kt * 32 + sc * 8,
              &lds[buf * 12288 + dsto + sdst]);
  };

  // prologue: tiles 0 (buf 0) and 1 (buf 1)
#pragma unroll
  for (int h = 0; h < 3; ++h) stage_ht(0, h, 0);
#pragma unroll
  for (int h = 0; h < 3; ++h) stage_ht(1, h, 1);
  asm volatile("s_waitcnt vmcnt(3)" ::: "memory");  // tile 0 arrived
  __builtin_amdgcn_s_barrier();

  int cur = 0;
  short8 a[4], b[2];
  for (int kt = 0; kt < NT; ++kt) {
    const int pb = cur * 12288;
    const int nb = (cur >= 1) ? cur - 1 : 2;  // (cur+2)%3 : holds tile kt-1, free
    __builtin_amdgcn_sched_barrier(0);
    // ---- phase 1: rows 0-63 ----
#pragma unroll
    for (int mi = 0; mi < 4; ++mi)
      a[mi] = *reinterpret_cast<const short8*>(&lds[pb + aBase + mi * 512]);
#pragma unroll
    for (int ni = 0; ni < 2; ++ni)
      b[ni] = *reinterpret_cast<const short8*>(&lds[pb + bBase + ni * 512]);
    if (kt + 2 < NT) { stage_ht(kt + 2, 0, nb); stage_ht(kt + 2, 1, nb); }
    asm volatile("s_waitcnt lgkmcnt(0)" ::: "memory");
    __builtin_amdgcn_sched_barrier(0);
    __builtin_amdgcn_s_setprio(1);
#pragma unroll
    for (int mi = 0; mi < 4; ++mi)
#pragma unroll
      for (int ni = 0; ni < 2; ++ni)
        acc[mi][ni] = __builtin_amdgcn_mfma_f32_16x16x32_bf16(a[mi], b[ni], acc[mi][ni], 0, 0, 0);
    __builtin_amdgcn_s_setprio(0);
    __builtin_amdgcn_sched_barrier(0);
    // ---- phase 2: rows 64-127 ----
#pragma unroll
    for (int mi = 0; mi < 4; ++mi)
      a[mi] = *reinterpret_cast<const short8*>(&lds[pb + aBase + 2048 + mi * 512]);
    if (kt + 2 < NT) stage_ht(kt + 2, 2, nb);
    asm volatile("s_waitcnt lgkmcnt(0)" ::: "memory");
    __builtin_amdgcn_sched_barrier(0);
    __builtin_amdgcn_s_setprio(1);
#pragma unroll
    for (int mi = 0; mi < 4; ++mi)
#pragma unroll
      for (int ni = 0; ni < 2; ++ni)
        acc[4 + mi][ni] = __builtin_amdgcn_mfma_f32_16x16x32_bf16(a[mi], b[ni], acc[4 + mi][ni], 0, 0, 0);
    __builtin_amdgcn_s_setprio(0);
    if (kt + 2 < NT)      asm volatile("s_waitcnt vmcnt(3)" ::: "memory");
    else if (kt + 1 < NT) asm volatile("s_waitcnt vmcnt(0)" ::: "memory");
    __builtin_amdgcn_s_barrier();   // single rendezvous per K-tile
    cur = (cur == 2) ? 0 : cur + 1;
  }

#pragma unroll
  for (int q = 0; q < 8; ++q)
#pragma unroll
    for (int ni = 0; ni < 2; ++ni)
#pragma unroll
      for (int r = 0; r < 4; ++r) {
        int row = bm + wr * 128 + (q >> 2) * 64 + (q & 3) * 16 + lhi * 4 + r;
        int col = bn + wc * 32 + ni * 16 + l16;
        Cv[(size_t)row * N + col] = f2b(acc[q][ni][r]);
      }
}

// ---------------- GEMM kernel wrappers ----------------

// cm_Wk: sqrelu bf16; grid 256
__global__ __launch_bounds__(512)
void k_g256_cmk(const u16* __restrict__ A, const u16* __restrict__ Bt,
                u16* __restrict__ C) {
  int bid = blockIdx.x;
  int wg = (bid & 7) * 32 + (bid >> 3);
  int lb = wg & 3, sv = wg >> 2;
  int by = (sv >> 3) * 2 + (lb & 1);
  int bx = (sv & 7) * 2 + (lb >> 1);
  g256_body<2>(A, Bt, C, HDIM, EDIM, EDIM, by * 256, bx * 256);
}

// cm_Wv: split-K x4 over H, bf16 partials; grid 256
__global__ __launch_bounds__(512)
void k_g256_wv(const u16* __restrict__ A, const u16* __restrict__ Bt,
               u16* __restrict__ P) {
  int bid = blockIdx.x;
  int wg = (bid & 7) * 32 + (bid >> 3);
  int z = wg >> 6, rem = wg & 63;
  int lb = rem & 3, sv = rem >> 2;
  int by = (sv >> 1) * 2 + (lb & 1);
  int bx = (sv & 1) * 2 + (lb >> 1);
  g256_body<1>(A + z * 1024, Bt + z * 1024, P + (size_t)z * L_SEQ * EDIM,
               EDIM, HDIM, 1024, by * 256, bx * 256);
}

// batched k/v/r GEMMs, bf16 out; grid 192
__global__ __launch_bounds__(512)
void k_g256_3(const u16* __restrict__ A0, const u16* __restrict__ A1, const u16* __restrict__ A2,
              const u16* __restrict__ B0, const u16* __restrict__ B1, const u16* __restrict__ B2,
              u16* __restrict__ C0, u16* __restrict__ C1, u16* __restrict__ C2) {
  int bid = blockIdx.x;
  int wg = (bid & 7) * 24 + (bid >> 3);
  int z = wg >> 6, rem = wg & 63;
  int lb = rem & 3, sv = rem >> 2;
  int by = (sv >> 1) * 2 + (lb & 1);
  int bx = (sv & 1) * 2 + (lb >> 1);
  const u16* A = (z == 0) ? A0 : (z == 1) ? A1 : A2;
  const u16* B = (z == 0) ? B0 : (z == 1) ? B1 : B2;
  u16*       C = (z == 0) ? C0 : (z == 1) ? C1 : C2;
  g256_body<1>(A, B, C, EDIM, EDIM, EDIM, by * 256, bx * 256);
}

// E^2 GEMM split-K x2 (Wo / cm_Wr / neck), bf16 partials; grid 256
__global__ __launch_bounds__(512)
void k_gx128_sk2(const u16* __restrict__ A, const u16* __restrict__ Bt,
                 u16* __restrict__ P) {
  int bid = blockIdx.x;
  int wg = (bid & 7) * 32 + (bid >> 3);
  int z = wg >> 7, rem = wg & 127;
  int by = rem >> 3, bx = rem & 7;
  g128_body(A + z * 512, Bt + z * 512, P + (size_t)z * L_SEQ * EDIM,
            EDIM, EDIM, 512, by * 256, bx * 128);
}

// ---------------- chunk-parallel WKV (bf16 k/v/r) ----------------

__global__ void k_wkv_pass1(const u16* __restrict__ k, const u16* __restrict__ v,
                            const float* __restrict__ w_,
                            float* __restrict__ sa, float* __restrict__ sb,
                            float* __restrict__ sp) {
  int id = blockIdx.x * blockDim.x + threadIdx.x;
  int e = id & 1023, c = id >> 10;
  float D = __expf(w_[e]);
  float aa = 0.f, bb = 0.f, pp = -__builtin_inff();
  const u16* kp = k + (size_t)c * WKV_T * EDIM + e;
  const u16* vp = v + (size_t)c * WKV_T * EDIM + e;
#pragma unroll 4
  for (int i = 0; i < WKV_T; ++i) {
    float kk = b2f(kp[i * EDIM]), vv = b2f(vp[i * EDIM]);
    float ww = pp - D;
    float p2 = fmaxf(ww, kk);
    float e1 = __expf(ww - p2), e2 = __expf(kk - p2);
    aa = e1 * aa + e2 * vv;
    bb = e1 * bb + e2;
    pp = p2;
  }
  sa[id] = aa; sb[id] = bb; sp[id] = pp;
}

// parallel exclusive scan: 16 lanes/channel, 8 chunks/lane, shuffle combine
__global__ __launch_bounds__(256)
void k_wkv_scan16(const float* __restrict__ w_,
                  const float* __restrict__ sa, const float* __restrict__ sb,
                  const float* __restrict__ sp,
                  float* __restrict__ oa, float* __restrict__ ob,
                  float* __restrict__ op) {
  int t = blockIdx.x * blockDim.x + threadIdx.x;
  int e = t >> 4, j = t & (SCAN_LANES - 1);
  const float NEG = -1e30f;
  float DT = __expf(w_[e]) * (float)WKV_T;
  float Ea[SCAN_CPT], Eb[SCAN_CPT], Ep[SCAN_CPT];
  float A = 0.f, B = 0.f, P = NEG;
  int base = j * SCAN_CPT;
#pragma unroll
  for (int i = 0; i < SCAN_CPT; ++i) {
    int idx = (base + i) * EDIM + e;
    Ea[i] = A; Eb[i] = B; Ep[i] = P;
    float a = sa[idx], b = sb[idx], q = sp[idx];
    float shift = P - DT;
    float pn = fmaxf(shift, q);
    float w1 = __expf(shift - pn), w2 = __expf(q - pn);
    A = w1 * A + w2 * a; B = w1 * B + w2 * b; P = pn;
  }
  float tA = A, tB = B, tP = P; int tn = SCAN_CPT;
#pragma unroll
  for (int d = 1; d < SCAN_LANES; d <<= 1) {
    float fA = __shfl_up(tA, d, SCAN_LANES);
    float fB = __shfl_up(tB, d, SCAN_LANES);
    float fP = __shfl_up(tP, d, SCAN_LANES);
    int   fn = __shfl_up(tn, d, SCAN_LANES);
    if (j >= d) {
      float shift = fP - DT * (float)tn;
      float pn = fmaxf(shift, tP);
      float w1 = __expf(shift - pn), w2 = __expf(tP - pn);
      tA = w1 * fA + w2 * tA; tB = w1 * fB + w2 * tB; tP = pn; tn += fn;
    }
  }
  float pA = __shfl_up(tA, 1, SCAN_LANES);
  float pB = __shfl_up(tB, 1, SCAN_LANES);
  float pP = __shfl_up(tP, 1, SCAN_LANES);
  if (j == 0) { pA = 0.f; pB = 0.f; pP = NEG; }
#pragma unroll
  for (int i = 0; i < SCAN_CPT; ++i) {
    float shift = pP - DT * (float)i;
    float pn = fmaxf(shift, Ep[i]);
    float w1 = __expf(shift - pn), w2 = __expf(Ep[i] - pn);
    int idx = (base + i) * EDIM + e;
    oa[idx] = w1 * pA + w2 * Ea[i];
    ob[idx] = w1 * pB + w2 * Eb[i];
    op[idx] = pn;
  }
}

// pass2 with fused sigmoid gate: rwb = bf16(sig(rpre) * wkv)
__global__ void k_wkv_pass2(const u16* __restrict__ k, const u16* __restrict__ v,
                            const float* __restrict__ u_, const float* __restrict__ w_,
                            const float* __restrict__ sa, const float* __restrict__ sb,
                            const float* __restrict__ sp,
                            const u16* __restrict__ rpre, u16* __restrict__ rwb) {
  int id = blockIdx.x * blockDim.x + threadIdx.x;
  int e = id & 1023, c = id >> 10;
  float u = u_[e];
  float D = __expf(w_[e]);
  float aa = sa[id], bb = sb[id], pp = sp[id];
  const size_t base = (size_t)c * WKV_T * EDIM + e;
  const u16* kp = k + base;
  const u16* vp = v + base;
  const u16* rp = rpre + base;
  u16* op = rwb + base;
#pragma unroll 4
  for (int i = 0; i < WKV_T; ++i) {
    float kk = b2f(kp[i * EDIM]), vv = b2f(vp[i * EDIM]);
    float ww = u + kk;
    float p = fmaxf(pp, ww);
    float e1 = __expf(pp - p), e2 = __expf(ww - p);
    float out = (e1 * aa + e2 * vv) / (e1 * bb + e2);
    op[i * EDIM] = f2b(out * sigm(b2f(rp[i * EDIM])));
    float w2s = pp - D;
    float p2 = fmaxf(w2s, kk);
    float e1b = __expf(w2s - p2), e2b = __expf(kk - p2);
    aa = e1b * aa + e2b * vv;
    bb = e1b * bb + e2b;
    pp = p2;
  }
}

// ---------------- head (fused gelu, 2 neck partials) ----------------
__global__ __launch_bounds__(256)
void k_head(const u16* __restrict__ P, const float* __restrict__ nb,
            const float* __restrict__ W,
            const int* __restrict__ s, float* __restrict__ partial) {
  const size_t LE = (size_t)L_SEQ * EDIM;
  int t = blockIdx.x, tid = threadIdx.x;
  float a0 = 0.f, a1 = 0.f, a2 = 0.f, a3 = 0.f;
  for (int e = tid; e < EDIM; e += 256) {
    size_t i = (size_t)t * EDIM + e;
    float hv = gelu1(b2f(P[i]) + b2f(P[i + LE]) + nb[e]);
    const float4 wv = *reinterpret_cast<const float4*>(W + e * 4);
    a0 += hv * wv.x; a1 += hv * wv.y; a2 += hv * wv.z; a3 += hv * wv.w;
  }
#pragma unroll
  for (int off = 32; off > 0; off >>= 1) {
    a0 += __shfl_down(a0, off, 64);
    a1 += __shfl_down(a1, off, 64);
    a2 += __shfl_down(a2, off, 64);
    a3 += __shfl_down(a3, off, 64);
  }
  __shared__ float sm[4][4];
  int w = tid >> 6, lane = tid & 63;
  if (lane == 0) { sm[w][0] = a0; sm[w][1] = a1; sm[w][2] = a2; sm[w][3] = a3; }
  __syncthreads();
  if (tid == 0) {
    float lg[4];
#pragma unroll
    for (int j = 0; j < 4; ++j) lg[j] = sm[0][j] + sm[1][j] + sm[2][j] + sm[3][j];
    float m = fmaxf(fmaxf(lg[0], lg[1]), fmaxf(lg[2], lg[3]));
    float sum = expf(lg[0] - m) + expf(lg[1] - m) + expf(lg[2] - m) + expf(lg[3] - m);
    partial[t] = 0.5f * (lg[s[t]] - m - logf(sum));
  }
}

__global__ __launch_bounds__(256)
void k_reduce(const float* __restrict__ partial, float* __restrict__ out) {
  int tid = threadIdx.x;
  float a = 0.f;
  for (int j = tid; j < L_SEQ; j += 256) a += partial[j];
#pragma unroll
  for (int off = 32; off > 0; off >>= 1) a += __shfl_down(a, off, 64);
  __shared__ float sm[4];
  if ((tid & 63) == 0) sm[tid >> 6] = a;
  __syncthreads();
  if (tid == 0) out[0] = sm[0] + sm[1] + sm[2] + sm[3];
}

// ---------------- host ----------------

extern "C" void kernel_launch(void* const* d_in, const int* in_sizes, int n_in,
                              void* d_out, int out_size, void* d_ws, size_t ws_size,
                              hipStream_t stream) {
  const int*   s        = (const int*)d_in[0];
  const float* embed    = (const float*)d_in[1];
  const float* tm_first = (const float*)d_in[2];
  const float* tm_decay = (const float*)d_in[3];
  const float* tm_mk    = (const float*)d_in[4];
  const float* tm_mv    = (const float*)d_in[5];
  const float* tm_mr    = (const float*)d_in[6];
  const float* tm_Wk    = (const float*)d_in[7];
  const float* tm_Wv    = (const float*)d_in[8];
  const float* tm_Wr    = (const float*)d_in[9];
  const float* tm_Wo    = (const float*)d_in[10];
  const float* cm_mk    = (const float*)d_in[11];
  const float* cm_mr    = (const float*)d_in[12];
  const float* cm_Wk    = (const float*)d_in[13];
  const float* cm_Wr    = (const float*)d_in[14];
  const float* cm_Wv    = (const float*)d_in[15];
  const float* neck_W   = (const float*)d_in[16];
  const float* neck_b   = (const float*)d_in[17];
  const float* head_W   = (const float*)d_in[18];

  char* ws = (char*)d_ws;
  size_t off = 0;
  auto alloc = [&](size_t bytes) { char* p = ws + off; off += (bytes + 255) & ~(size_t)255; return p; };
  const size_t LE2 = (size_t)L_SEQ * EDIM * 2;
  const size_t EE  = (size_t)EDIM * EDIM, EH = (size_t)EDIM * HDIM;

  u16*   xA    = (u16*)alloc(LE2);
  u16*   xB    = (u16*)alloc(LE2);
  u16*   kxb   = (u16*)alloc(LE2);
  u16*   vxb   = (u16*)alloc(LE2);   // also rwb
  u16*   rxb   = (u16*)alloc(LE2);
  u16*   kf    = (u16*)alloc(LE2);
  u16*   vf    = (u16*)alloc(LE2);
  u16*   rpre  = (u16*)alloc(LE2);
  u16*   kkb   = (u16*)alloc((size_t)L_SEQ * HDIM * 2);
  u16*   PA    = (u16*)alloc(2 * LE2);   // Wo / neck partials (bf16 x2)
  u16*   PR    = (u16*)alloc(2 * LE2);   // cm_Wr partials (bf16 x2)
  u16*   PB    = (u16*)alloc(4 * LE2);   // cm_Wv partials (bf16 x4)
  float* partial = (float*)alloc((size_t)L_SEQ * 4);
  float* sa  = (float*)alloc((size_t)WKV_C * EDIM * 4);
  float* sb  = (float*)alloc((size_t)WKV_C * EDIM * 4);
  float* sp  = (float*)alloc((size_t)WKV_C * EDIM * 4);
  float* sa2 = (float*)alloc((size_t)WKV_C * EDIM * 4);
  float* sb2 = (float*)alloc((size_t)WKV_C * EDIM * 4);
  float* sp2 = (float*)alloc((size_t)WKV_C * EDIM * 4);

  size_t remain = (ws_size > off) ? ws_size - off : 0;
  const size_t bigNeed = (5 * EE * NLAY + 2 * EH * NLAY + EE) * 2 + 16 * 256;
  const bool big = remain >= bigNeed;
  const int NB = big ? NLAY : 1;
  u16* wWk   = (u16*)alloc(EE * NB * 2);
  u16* wWv   = (u16*)alloc(EE * NB * 2);
  u16* wWr   = (u16*)alloc(EE * NB * 2);
  u16* wWo   = (u16*)alloc(EE * NB * 2);
  u16* wcmWr = (u16*)alloc(EE * NB * 2);
  u16* wcmWk = (u16*)alloc(EH * NB * 2);
  u16* wcmWv = (u16*)alloc(EH * NB * 2);
  u16* wneck = big ? (u16*)alloc(EE * 2) : wWk;

  const dim3 blk(256);
  const dim3 blk512(512);
  const dim3 gE4((L_SEQ * EDIM) / 1024);
  const dim3 gRB(L_SEQ / 4);               // row-block grid for f1/f2
  const dim3 gWkv((WKV_C * EDIM) / 256);
  const dim3 gScan((EDIM * SCAN_LANES) / 256);
  const size_t DLDS  = 131072;  // 128KB for 256^2
  const size_t DLDS2 = 73728;   // 72KB for 256x128 (3 buffers -> 2 blocks/CU)

  if (big) {
    k_tconv_all<<<dim3(TC_EE + 2 * TC_EH), blk, 0, stream>>>(
        tm_Wk, tm_Wv, tm_Wr, tm_Wo, cm_Wr, neck_W, cm_Wk, cm_Wv,
        wWk, wWv, wWr, wWo, wcmWr, wneck, wcmWk, wcmWv);
  }

  for (int l = 0; l < NLAY; ++l) {
    size_t oE  = (size_t)l * EDIM;
    size_t oEE = (size_t)l * EE;
    size_t oEH = (size_t)l * EH;
    size_t wE  = big ? oEE : 0;
    size_t wH  = big ? oEH : 0;
    if (!big) {
      k_tconv<<<dim3(EDIM / 64, EDIM / 64, 1), blk, 0, stream>>>(tm_Wk + oEE, wWk, EDIM, EDIM);
      k_tconv<<<dim3(EDIM / 64, EDIM / 64, 1), blk, 0, stream>>>(tm_Wv + oEE, wWv, EDIM, EDIM);
      k_tconv<<<dim3(EDIM / 64, EDIM / 64, 1), blk, 0, stream>>>(tm_Wr + oEE, wWr, EDIM, EDIM);
      k_tconv<<<dim3(EDIM / 64, EDIM / 64, 1), blk, 0, stream>>>(tm_Wo + oEE, wWo, EDIM, EDIM);
      k_tconv<<<dim3(EDIM / 64, EDIM / 64, 1), blk, 0, stream>>>(cm_Wr + oEE, wcmWr, EDIM, EDIM);
      k_tconv<<<dim3(HDIM / 64, EDIM / 64, 1), blk, 0, stream>>>(cm_Wk + oEH, wcmWk, EDIM, HDIM);
      k_tconv<<<dim3(EDIM / 64, HDIM / 64, 1), blk, 0, stream>>>(cm_Wv + oEH, wcmWv, HDIM, EDIM);
    }
    // --- TimeMixing ---
    if (l == 0)
      k_f0<<<gE4, blk, 0, stream>>>(s, embed, tm_mk + oE, tm_mv + oE, tm_mr + oE,
                                    xA, kxb, vxb, rxb);
    else
      k_f1<<<gRB, blk, 0, stream>>>(xB, PR, PB, tm_mk + oE, tm_mv + oE, tm_mr + oE,
                                    xA, kxb, vxb, rxb);
    k_g256_3<<<dim3(192), blk512, DLDS, stream>>>(kxb, vxb, rxb,
                                                  wWk + wE, wWv + wE, wWr + wE,
                                                  kf, vf, rpre);
    k_wkv_pass1<<<gWkv, blk, 0, stream>>>(kf, vf, tm_decay + oE, sa, sb, sp);
    k_wkv_scan16<<<gScan, blk, 0, stream>>>(tm_decay + oE, sa, sb, sp, sa2, sb2, sp2);
    k_wkv_pass2<<<gWkv, blk, 0, stream>>>(kf, vf, tm_first + oE, tm_decay + oE,
                                          sa2, sb2, sp2, rpre, vxb);
    k_gx128_sk2<<<dim3(256), blk512, DLDS2, stream>>>(vxb, wWo + wE, PA);
    // --- ChannelMixing ---
    k_f2<<<gRB, blk, 0, stream>>>(xA, PA, cm_mk + oE, cm_mr + oE, xB, kxb, rxb);
    k_gx128_sk2<<<dim3(256), blk512, DLDS2, stream>>>(rxb, wcmWr + wE, PR);
    k_g256_cmk<<<dim3(256), blk512, DLDS, stream>>>(kxb, wcmWk + wH, kkb);
    k_g256_wv<<<dim3(256), blk512, DLDS, stream>>>(kkb, wcmWv + wH, PB);
  }
  // --- Neck + Head ---
  if (!big) k_tconv<<<dim3(EDIM / 64, EDIM / 64, 1), blk, 0, stream>>>(neck_W, wneck, EDIM, EDIM);
  k_f3<<<gE4, blk, 0, stream>>>(xB, PR, PB, kxb);
  k_gx128_sk2<<<dim3(256), blk512, DLDS2, stream>>>(kxb, wneck, PA);
  k_head<<<dim3(L_SEQ), blk, 0, stream>>>(PA, neck_b, head_W, s, partial);
  k_reduce<<<dim3(1), blk, 0, stream>>>(partial, (float*)d_out);

  (void)in_sizes; (void)n_in; (void)out_size;
}